// Round 1
// baseline (1951.854 us; speedup 1.0000x reference)
//
#include <hip/hip_runtime.h>
#include <hip/hip_bf16.h>

#define AS1 __attribute__((address_space(1)))
#define AS3 __attribute__((address_space(3)))

typedef __attribute__((ext_vector_type(8))) short bf16x8;
typedef __attribute__((ext_vector_type(4))) float f32x4;

#define B_ 2
#define S_ 2048
#define D_ 4096
#define H_ 32
#define HD_ 128
#define P_ 30

__device__ __forceinline__ short f2b(float f) {
  union { __hip_bfloat16 h; short s; } u;
  u.h = __float2bfloat16(f);
  return u.s;
}
__device__ __forceinline__ float b2f(short s) {
  union { short s; __hip_bfloat16 h; } u;
  u.s = s;
  return __bfloat162float(u.h);
}
__device__ __forceinline__ void gload16(const void* g, void* l) {
  __builtin_amdgcn_global_load_lds((const AS1 void*)g, (AS3 void*)l, 16, 0, 0);
}

// ---------------- elementwise conversion ----------------
__global__ __launch_bounds__(256) void convert_f32_bf16(const float* __restrict__ in,
                                                        short* __restrict__ out) {
  size_t i = ((size_t)blockIdx.x * 256 + threadIdx.x) * 4;
  float4 v = *reinterpret_cast<const float4*>(in + i);
  short4 o;
  o.x = f2b(v.x); o.y = f2b(v.y); o.z = f2b(v.z); o.w = f2b(v.w);
  *reinterpret_cast<short4*>(out + i) = o;
}

// prefix (30 x 4096 f32) -> padded 128 x 4096 bf16 (zeros beyond row 29)
__global__ __launch_bounds__(256) void pad_prefix(const float* __restrict__ p,
                                                  short* __restrict__ pb) {
  int i = blockIdx.x * 256 + threadIdx.x;   // 128*4096 elems
  int row = i >> 12, col = i & 4095;
  pb[i] = (row < P_) ? f2b(p[row * D_ + col]) : (short)0;
}

// W (K x N) f32 -> Wt (N x K) bf16, 32x32 LDS tiles
__global__ void transpose_convert(const float* __restrict__ W, short* __restrict__ Wt,
                                  int K, int N) {
  __shared__ float t[32][33];
  int bx = blockIdx.x, by = blockIdx.y;
  int tx = threadIdx.x, ty = threadIdx.y;
#pragma unroll
  for (int i = 0; i < 4; ++i) {
    int r = ty * 4 + i;
    t[r][tx] = W[(size_t)(by * 32 + r) * N + bx * 32 + tx];
  }
  __syncthreads();
#pragma unroll
  for (int i = 0; i < 4; ++i) {
    int r = ty * 4 + i;
    Wt[(size_t)(bx * 32 + r) * K + by * 32 + tx] = f2b(t[tx][r]);
  }
}

// in-place RoPE on (B,S,H,HD) bf16; pairs (2i,2i+1), tables (S, HD/2) f32
__global__ __launch_bounds__(256) void rope_kernel(short* __restrict__ t,
                                                   const float* __restrict__ fc,
                                                   const float* __restrict__ fs) {
  size_t g = ((size_t)blockIdx.x * 256 + threadIdx.x) * 8;
  int d = (int)(g & 127);
  int s = (int)((g >> 12) & 2047);
  bf16x8 v = *reinterpret_cast<bf16x8*>(t + g);
  int i0 = d >> 1;  // multiple of 4
  float4 c = *reinterpret_cast<const float4*>(fc + (size_t)s * 64 + i0);
  float4 sn = *reinterpret_cast<const float4*>(fs + (size_t)s * 64 + i0);
  float cc[4] = {c.x, c.y, c.z, c.w};
  float ss[4] = {sn.x, sn.y, sn.z, sn.w};
  bf16x8 o;
#pragma unroll
  for (int p = 0; p < 4; ++p) {
    float t0 = b2f(v[2 * p]), t1 = b2f(v[2 * p + 1]);
    o[2 * p] = f2b(t0 * cc[p] - t1 * ss[p]);
    o[2 * p + 1] = f2b(t0 * ss[p] + t1 * cc[p]);
  }
  *reinterpret_cast<bf16x8*>(t + g) = o;
}

// ---------------- GEMM: C(MxN) = A(MxK) * Bt(NxK)^T, bf16 in, f32 acc ----------------
// m97 structure: 128x128 tile, 4 waves in 2x2, each 64x64 (4x4 frags of 16x16),
// BK=32, global_load_lds width 16, ds_read_b128 fragments.
template <typename OutT>
__global__ __launch_bounds__(256) void gemm_bt(const short* __restrict__ A,
                                               const short* __restrict__ Bt,
                                               OutT* __restrict__ C,
                                               int M, int N, int K) {
  __shared__ short As[128 * 32];
  __shared__ short Bs[128 * 32];
  const int tid = threadIdx.x;
  const int lane = tid & 63;
  const int wbase = tid & 192;            // wave*64
  const int wr = ((tid >> 7) & 1) * 64;   // wave row offset
  const int wc = ((tid >> 6) & 1) * 64;   // wave col offset
  const int lr = lane & 15;
  const int lk = (lane >> 4) * 8;
  const int bm = blockIdx.y, bn = blockIdx.x;
  f32x4 acc[4][4] = {};
  const short* Ab = A + (size_t)bm * 128 * K;
  const short* Bb = Bt + (size_t)bn * 128 * K;
  for (int kt = 0; kt < K; kt += 32) {
    __syncthreads();
#pragma unroll
    for (int i = 0; i < 2; ++i) {
      int f = i * 256 + tid;
      int row = f >> 2, col = (f & 3) * 8;
      gload16(Ab + (size_t)row * K + kt + col, &As[(i * 256 + wbase) * 8]);
      gload16(Bb + (size_t)row * K + kt + col, &Bs[(i * 256 + wbase) * 8]);
    }
    __syncthreads();
    bf16x8 af[4], bfr[4];
#pragma unroll
    for (int m = 0; m < 4; ++m)
      af[m] = *reinterpret_cast<const bf16x8*>(&As[(wr + m * 16 + lr) * 32 + lk]);
#pragma unroll
    for (int n = 0; n < 4; ++n)
      bfr[n] = *reinterpret_cast<const bf16x8*>(&Bs[(wc + n * 16 + lr) * 32 + lk]);
#pragma unroll
    for (int m = 0; m < 4; ++m)
#pragma unroll
      for (int n = 0; n < 4; ++n)
        acc[m][n] = __builtin_amdgcn_mfma_f32_16x16x32_bf16(af[m], bfr[n], acc[m][n], 0, 0, 0);
  }
  // C/D layout: col = lane&15, row = (lane>>4)*4 + reg  [m89]
  const int row0 = bm * 128 + wr + (lane >> 4) * 4;
  const int col0 = bn * 128 + wc + lr;
#pragma unroll
  for (int m = 0; m < 4; ++m)
#pragma unroll
    for (int n = 0; n < 4; ++n)
#pragma unroll
      for (int j = 0; j < 4; ++j) {
        size_t idx = (size_t)(row0 + m * 16 + j) * N + col0 + n * 16;
        if constexpr (sizeof(OutT) == 2) C[idx] = f2b(acc[m][n][j]);
        else C[idx] = acc[m][n][j];
      }
}

// ---------------- fused flash attention (causal + gated prefix) ----------------
// grid (32 qtiles, 64 b*h), block 256 = 4 waves x 16 q rows.
__global__ __launch_bounds__(256) void attn_kernel(
    const short* __restrict__ qb, const short* __restrict__ kb, const short* __restrict__ vb,
    const short* __restrict__ pkb, const short* __restrict__ pvb,
    const float* __restrict__ gate, short* __restrict__ ab) {
  __shared__ short Ks[64 * 128];      // K tile, XOR-swizzled (G4/G21)
  __shared__ short Vt[128 * 64];      // V tile transposed [d][tok], swizzled
  __shared__ short Ps[4][16 * 72];    // per-wave P tile, padded stride 72
  const int tid = threadIdx.x;
  const int wave = tid >> 6, lane = tid & 63;
  const int wbase = tid & 192;
  const int lr = lane & 15, lg = lane >> 4;
  const int qt = blockIdx.x, bh = blockIdx.y;
  const int b = bh >> 5, h = bh & 31;

  // Q fragments (rope'd) direct from global: A[r=lr][k], 4 chunks of K=32
  const short* qrow = qb + ((size_t)(b * S_ + qt * 64 + wave * 16 + lr) * H_ + h) * HD_;
  bf16x8 aq[4];
#pragma unroll
  for (int kk = 0; kk < 4; ++kk)
    aq[kk] = *reinterpret_cast<const bf16x8*>(qrow + kk * 32 + lg * 8);

  float m1[4], l1[4], m2[4], l2[4];
  f32x4 o1[8] = {}, o2[8] = {};
#pragma unroll
  for (int j = 0; j < 4; ++j) { m1[j] = m2[j] = -1e30f; l1[j] = l2[j] = 0.f; }

  auto stage = [&](const short* kbase, const short* vbase) {
    // K: 64x128 tile; linear LDS dest + inverse-swizzled global source (G21)
#pragma unroll
    for (int i = 0; i < 4; ++i) {
      int f = i * 256 + tid;
      int row = f >> 4;
      int col = ((f & 15) ^ (row & 7)) * 8;
      gload16(kbase + (size_t)row * (size_t)(H_ * HD_) + col, &Ks[(i * 256 + wbase) * 8]);
    }
    // V transposed: reg-stage + scattered ds_write, token-chunk XOR swizzle
#pragma unroll
    for (int i = 0; i < 4; ++i) {
      int f = i * 256 + tid;
      int tok = f >> 4, dc = (f & 15) * 8;
      bf16x8 v = *reinterpret_cast<const bf16x8*>(vbase + (size_t)tok * (size_t)(H_ * HD_) + dc);
#pragma unroll
      for (int e = 0; e < 8; ++e) {
        int d = dc + e;
        int s = ((d >> 3) ^ d) & 7;
        Vt[d * 64 + (tok ^ (s * 8))] = v[e];
      }
    }
  };

  // mode: 0 = full, 1 = causal diagonal, 2 = prefix (cols >= P_ masked)
  auto process = [&](int kv0, int mode, float* m, float* l, f32x4* o) {
    f32x4 sc[4] = {};
#pragma unroll
    for (int cb = 0; cb < 4; ++cb) {
      int tok = cb * 16 + lr;
#pragma unroll
      for (int kk = 0; kk < 4; ++kk) {
        int addr = (tok * 128 + kk * 32 + lg * 8) ^ ((tok & 7) * 8);
        bf16x8 bk = *reinterpret_cast<const bf16x8*>(&Ks[addr]);
        sc[cb] = __builtin_amdgcn_mfma_f32_16x16x32_bf16(aq[kk], bk, sc[cb], 0, 0, 0);
      }
    }
    const float scale = 0.08838834764831845f;  // 1/sqrt(128)
#pragma unroll
    for (int cb = 0; cb < 4; ++cb) {
      int colg = kv0 + cb * 16 + lr;
      int coll = cb * 16 + lr;
#pragma unroll
      for (int j = 0; j < 4; ++j) {
        float v = sc[cb][j] * scale;
        int rowg = qt * 64 + wave * 16 + lg * 4 + j;
        bool ok = (mode == 0) || (mode == 1 && colg <= rowg) || (mode == 2 && coll < P_);
        sc[cb][j] = ok ? v : -1e30f;
      }
    }
#pragma unroll
    for (int j = 0; j < 4; ++j) {
      float v = fmaxf(fmaxf(sc[0][j], sc[1][j]), fmaxf(sc[2][j], sc[3][j]));
      v = fmaxf(v, __shfl_xor(v, 1));
      v = fmaxf(v, __shfl_xor(v, 2));
      v = fmaxf(v, __shfl_xor(v, 4));
      v = fmaxf(v, __shfl_xor(v, 8));
      float mn = fmaxf(m[j], v);
      float alpha = __expf(m[j] - mn);
      float rs = 0.f;
#pragma unroll
      for (int cb = 0; cb < 4; ++cb) {
        float p = __expf(sc[cb][j] - mn);
        sc[cb][j] = p;
        rs += p;
      }
      rs += __shfl_xor(rs, 1);
      rs += __shfl_xor(rs, 2);
      rs += __shfl_xor(rs, 4);
      rs += __shfl_xor(rs, 8);
      l[j] = l[j] * alpha + rs;
      m[j] = mn;
#pragma unroll
      for (int nb = 0; nb < 8; ++nb) o[nb][j] *= alpha;
    }
    // P -> LDS (per-wave), then A-fragments for PV
#pragma unroll
    for (int cb = 0; cb < 4; ++cb)
#pragma unroll
      for (int j = 0; j < 4; ++j)
        Ps[wave][(lg * 4 + j) * 72 + cb * 16 + lr] = f2b(sc[cb][j]);
    bf16x8 ap[2];
#pragma unroll
    for (int kk = 0; kk < 2; ++kk)
      ap[kk] = *reinterpret_cast<const bf16x8*>(&Ps[wave][lr * 72 + kk * 32 + lg * 8]);
#pragma unroll
    for (int nb = 0; nb < 8; ++nb) {
      int d = nb * 16 + lr;
      int s = ((d >> 3) ^ d) & 7;
#pragma unroll
      for (int kk = 0; kk < 2; ++kk) {
        int t0 = (kk * 32 + lg * 8) ^ (s * 8);
        bf16x8 bv = *reinterpret_cast<const bf16x8*>(&Vt[d * 64 + t0]);
        o[nb] = __builtin_amdgcn_mfma_f32_16x16x32_bf16(ap[kk], bv, o[nb], 0, 0, 0);
      }
    }
  };

  const short* kb_bh = kb + ((size_t)b * S_ * H_ + h) * HD_;
  const short* vb_bh = vb + ((size_t)b * S_ * H_ + h) * HD_;
  for (int t = 0; t <= qt; ++t) {
    __syncthreads();
    stage(kb_bh + (size_t)t * 64 * (H_ * HD_), vb_bh + (size_t)t * 64 * (H_ * HD_));
    __syncthreads();
    process(t * 64, (t == qt) ? 1 : 0, m1, l1, o1);
  }
  __syncthreads();
  stage(pkb + h * HD_, pvb + h * HD_);  // rows 0..63 valid (buffer is 128 rows, zeros past 29)
  __syncthreads();
  process(0, 2, m2, l2, o2);

  float g = tanhf(gate[h]);
#pragma unroll
  for (int j = 0; j < 4; ++j) {
    int q = qt * 64 + wave * 16 + lg * 4 + j;
    float i1 = 1.f / l1[j], i2 = 1.f / l2[j];
    size_t base = ((size_t)(b * S_ + q) * H_ + h) * HD_;
#pragma unroll
    for (int nb = 0; nb < 8; ++nb)
      ab[base + nb * 16 + lr] = f2b(o1[nb][j] * i1 + g * o2[nb][j] * i2);
  }
}

// ---------------- launcher ----------------
extern "C" void kernel_launch(void* const* d_in, const int* in_sizes, int n_in,
                              void* d_out, int out_size, void* d_ws, size_t ws_size,
                              hipStream_t stream) {
  const float* x = (const float*)d_in[0];
  const float* fc = (const float*)d_in[1];
  const float* fs = (const float*)d_in[2];
  const float* prefix = (const float*)d_in[3];
  const float* gate = (const float*)d_in[4];
  const float* wq = (const float*)d_in[5];
  const float* wk = (const float*)d_in[6];
  const float* wv = (const float*)d_in[7];
  const float* wo = (const float*)d_in[8];
  float* out = (float*)d_out;

  char* ws = (char*)d_ws;
  const size_t SZ = (size_t)4096 * 4096 * 2;  // 32 MiB per bf16 matrix
  short* xb = (short*)(ws);                    // also reused as attention output
  short* wT = (short*)(ws + SZ);
  short* qbuf = (short*)(ws + 2 * SZ);
  short* kbuf = (short*)(ws + 3 * SZ);
  short* vbuf = (short*)(ws + 4 * SZ);
  short* pb = (short*)(ws + 5 * SZ);
  short* pkb = (short*)(ws + 5 * SZ + (1 << 20));
  short* pvb = (short*)(ws + 5 * SZ + (2 << 20));
  short* abuf = xb;  // alias: x_bf16 dead after V projection

  dim3 tcg(128, 128), tcb(32, 8);
  dim3 gg(32, 32), gp(32, 1);

  convert_f32_bf16<<<16384, 256, 0, stream>>>(x, xb);
  pad_prefix<<<2048, 256, 0, stream>>>(prefix, pb);

  transpose_convert<<<tcg, tcb, 0, stream>>>(wq, wT, 4096, 4096);
  gemm_bt<short><<<gg, 256, 0, stream>>>(xb, wT, qbuf, 4096, 4096, 4096);

  transpose_convert<<<tcg, tcb, 0, stream>>>(wk, wT, 4096, 4096);
  gemm_bt<short><<<gg, 256, 0, stream>>>(xb, wT, kbuf, 4096, 4096, 4096);
  gemm_bt<short><<<gp, 256, 0, stream>>>(pb, wT, pkb, 128, 4096, 4096);

  transpose_convert<<<tcg, tcb, 0, stream>>>(wv, wT, 4096, 4096);
  gemm_bt<short><<<gg, 256, 0, stream>>>(xb, wT, vbuf, 4096, 4096, 4096);
  gemm_bt<short><<<gp, 256, 0, stream>>>(pb, wT, pvb, 128, 4096, 4096);

  rope_kernel<<<8192, 256, 0, stream>>>(qbuf, fc, fs);
  rope_kernel<<<8192, 256, 0, stream>>>(kbuf, fc, fs);

  attn_kernel<<<dim3(32, 64), 256, 0, stream>>>(qbuf, kbuf, vbuf, pkb, pvb, gate, abuf);

  transpose_convert<<<tcg, tcb, 0, stream>>>(wo, wT, 4096, 4096);
  gemm_bt<float><<<gg, 256, 0, stream>>>(abuf, wT, out, 4096, 4096, 4096);
}

// Round 3
// 1658.141 us; speedup vs baseline: 1.1771x; 1.1771x over previous
//
#include <hip/hip_runtime.h>
#include <hip/hip_bf16.h>

#define AS1 __attribute__((address_space(1)))
#define AS3 __attribute__((address_space(3)))

typedef __attribute__((ext_vector_type(8))) short bf16x8;
typedef __attribute__((ext_vector_type(4))) float f32x4;

#define B_ 2
#define S_ 2048
#define D_ 4096
#define H_ 32
#define HD_ 128
#define P_ 30

__device__ __forceinline__ short f2b(float f) {
  union { __hip_bfloat16 h; short s; } u;
  u.h = __float2bfloat16(f);
  return u.s;
}
__device__ __forceinline__ float b2f(short s) {
  union { short s; __hip_bfloat16 h; } u;
  u.s = s;
  return __bfloat162float(u.h);
}
__device__ __forceinline__ void gload16(const void* g, void* l) {
  __builtin_amdgcn_global_load_lds((const AS1 void*)g, (AS3 void*)l, 16, 0, 0);
}

// ---------------- elementwise conversion ----------------
__global__ __launch_bounds__(256) void convert_f32_bf16(const float* __restrict__ in,
                                                        short* __restrict__ out) {
  size_t i = ((size_t)blockIdx.x * 256 + threadIdx.x) * 4;
  float4 v = *reinterpret_cast<const float4*>(in + i);
  short4 o;
  o.x = f2b(v.x); o.y = f2b(v.y); o.z = f2b(v.z); o.w = f2b(v.w);
  *reinterpret_cast<short4*>(out + i) = o;
}

// prefix (30 x 4096 f32) -> padded 128 x 4096 bf16 (zeros beyond row 29)
__global__ __launch_bounds__(256) void pad_prefix(const float* __restrict__ p,
                                                  short* __restrict__ pb) {
  int i = blockIdx.x * 256 + threadIdx.x;
  int row = i >> 12, col = i & 4095;
  pb[i] = (row < P_) ? f2b(p[row * D_ + col]) : (short)0;
}

// W (K x N) f32 -> Wt (N x K) bf16, 32x32 LDS tiles
__global__ void transpose_convert(const float* __restrict__ W, short* __restrict__ Wt,
                                  int K, int N) {
  __shared__ float t[32][33];
  int bx = blockIdx.x, by = blockIdx.y;
  int tx = threadIdx.x, ty = threadIdx.y;
#pragma unroll
  for (int i = 0; i < 4; ++i) {
    int r = ty * 4 + i;
    t[r][tx] = W[(size_t)(by * 32 + r) * N + bx * 32 + tx];
  }
  __syncthreads();
#pragma unroll
  for (int i = 0; i < 4; ++i) {
    int r = ty * 4 + i;
    Wt[(size_t)(bx * 32 + r) * K + by * 32 + tx] = f2b(t[tx][r]);
  }
}

// V (B, S, H*HD) bf16 -> V^T (B, H*HD, S) bf16, 64x64 LDS tiles
__global__ __launch_bounds__(256) void transpose_v(const short* __restrict__ src,
                                                   short* __restrict__ dst) {
  __shared__ short t[64][72];
  int b = blockIdx.z;
  int s0 = blockIdx.y * 64, c0 = blockIdx.x * 64;
  int tid = threadIdx.x;
#pragma unroll
  for (int i = 0; i < 2; ++i) {
    int g = i * 256 + tid;
    int r = g >> 3, c = (g & 7) * 8;
    *(bf16x8*)&t[r][c] = *(const bf16x8*)&src[((size_t)b * S_ + s0 + r) * D_ + c0 + c];
  }
  __syncthreads();
#pragma unroll
  for (int i = 0; i < 2; ++i) {
    int g = i * 256 + tid;
    int r = g >> 3, c = (g & 7) * 8;
    bf16x8 v;
#pragma unroll
    for (int e = 0; e < 8; ++e) v[e] = t[c + e][r];
    *(bf16x8*)&dst[((size_t)b * D_ + c0 + r) * S_ + s0 + c] = v;
  }
}

// in-place RoPE on (B,S,H,HD) bf16
__global__ __launch_bounds__(256) void rope_kernel(short* __restrict__ t,
                                                   const float* __restrict__ fc,
                                                   const float* __restrict__ fs) {
  size_t g = ((size_t)blockIdx.x * 256 + threadIdx.x) * 8;
  int d = (int)(g & 127);
  int s = (int)((g >> 12) & 2047);
  bf16x8 v = *reinterpret_cast<bf16x8*>(t + g);
  int i0 = d >> 1;
  float4 c = *reinterpret_cast<const float4*>(fc + (size_t)s * 64 + i0);
  float4 sn = *reinterpret_cast<const float4*>(fs + (size_t)s * 64 + i0);
  float cc[4] = {c.x, c.y, c.z, c.w};
  float ss[4] = {sn.x, sn.y, sn.z, sn.w};
  bf16x8 o;
#pragma unroll
  for (int p = 0; p < 4; ++p) {
    float t0 = b2f(v[2 * p]), t1 = b2f(v[2 * p + 1]);
    o[2 * p] = f2b(t0 * cc[p] - t1 * ss[p]);
    o[2 * p + 1] = f2b(t0 * ss[p] + t1 * cc[p]);
  }
  *reinterpret_cast<bf16x8*>(t + g) = o;
}

// ---------------- GEMM (m97 structure, unchanged) ----------------
template <typename OutT>
__global__ __launch_bounds__(256) void gemm_bt(const short* __restrict__ A,
                                               const short* __restrict__ Bt,
                                               OutT* __restrict__ C,
                                               int M, int N, int K) {
  __shared__ short As[128 * 32];
  __shared__ short Bs[128 * 32];
  const int tid = threadIdx.x;
  const int lane = tid & 63;
  const int wbase = tid & 192;
  const int wr = ((tid >> 7) & 1) * 64;
  const int wc = ((tid >> 6) & 1) * 64;
  const int lr = lane & 15;
  const int lk = (lane >> 4) * 8;
  const int bm = blockIdx.y, bn = blockIdx.x;
  f32x4 acc[4][4] = {};
  const short* Ab = A + (size_t)bm * 128 * K;
  const short* Bb = Bt + (size_t)bn * 128 * K;
  for (int kt = 0; kt < K; kt += 32) {
    __syncthreads();
#pragma unroll
    for (int i = 0; i < 2; ++i) {
      int f = i * 256 + tid;
      int row = f >> 2, col = (f & 3) * 8;
      gload16(Ab + (size_t)row * K + kt + col, &As[(i * 256 + wbase) * 8]);
      gload16(Bb + (size_t)row * K + kt + col, &Bs[(i * 256 + wbase) * 8]);
    }
    __syncthreads();
    bf16x8 af[4], bfr[4];
#pragma unroll
    for (int m = 0; m < 4; ++m)
      af[m] = *reinterpret_cast<const bf16x8*>(&As[(wr + m * 16 + lr) * 32 + lk]);
#pragma unroll
    for (int n = 0; n < 4; ++n)
      bfr[n] = *reinterpret_cast<const bf16x8*>(&Bs[(wc + n * 16 + lr) * 32 + lk]);
#pragma unroll
    for (int m = 0; m < 4; ++m)
#pragma unroll
      for (int n = 0; n < 4; ++n)
        acc[m][n] = __builtin_amdgcn_mfma_f32_16x16x32_bf16(af[m], bfr[n], acc[m][n], 0, 0, 0);
  }
  const int row0 = bm * 128 + wr + (lane >> 4) * 4;
  const int col0 = bn * 128 + wc + lr;
#pragma unroll
  for (int m = 0; m < 4; ++m)
#pragma unroll
    for (int n = 0; n < 4; ++n)
#pragma unroll
      for (int j = 0; j < 4; ++j) {
        size_t idx = (size_t)(row0 + m * 16 + j) * N + col0 + n * 16;
        if constexpr (sizeof(OutT) == 2) C[idx] = f2b(acc[m][n][j]);
        else C[idx] = acc[m][n][j];
      }
}

// ---------------- causal flash attention, 128 q-rows/block ----------------
// grid (16, 64). 4 waves x 32 rows. KVBLK=64. K and V^T double-buffered in LDS,
// both staged linearly via global_load_lds with a 16B-granule XOR swizzle
// applied on the global SOURCE address (G21) and on every LDS read (involution).
// K tile: [tok=64][d=128]; V tile: [d=128][tok=64] (from pre-transposed vT).
__global__ __launch_bounds__(256) void attn_kernel(
    const short* __restrict__ qb, const short* __restrict__ kb, const short* __restrict__ vt,
    short* __restrict__ ab) {
  __shared__ short Ks[2][64 * 128];
  __shared__ short Vs[2][128 * 64];
  __shared__ short Ps[4][32 * 64];
  const int tid = threadIdx.x;
  const int wave = tid >> 6, lane = tid & 63;
  const int wbase = tid & 192;
  const int lr = lane & 15, lg = lane >> 4;
  const int qt = (int)gridDim.x - 1 - (int)blockIdx.x;  // heavy blocks first
  const int bh = blockIdx.y;
  const int b = bh >> 5, h = bh & 31;

  // Q fragments: rows qt*128 + wave*32 + rb*16 + lr
  bf16x8 aq[2][4];
#pragma unroll
  for (int rb = 0; rb < 2; ++rb) {
    const short* qrow = qb + ((size_t)(b * S_ + qt * 128 + wave * 32 + rb * 16 + lr) * H_ + h) * HD_;
#pragma unroll
    for (int kk = 0; kk < 4; ++kk)
      aq[rb][kk] = *reinterpret_cast<const bf16x8*>(qrow + kk * 32 + lg * 8);
  }

  float m[2][4], l[2][4];
  f32x4 o[2][8] = {};
#pragma unroll
  for (int rb = 0; rb < 2; ++rb)
#pragma unroll
    for (int j = 0; j < 4; ++j) { m[rb][j] = -1e30f; l[rb][j] = 0.f; }

  const short* kb_bh = kb + ((size_t)b * S_ * H_ + h) * HD_;
  const short* vt_bh = vt + ((size_t)(b * H_ + h)) * HD_ * S_;

  auto stageK = [&](int t, int buf) {
#pragma unroll
    for (int i = 0; i < 4; ++i) {
      int g = i * 256 + tid;
      int row = g >> 4;                       // tok
      int col = ((g & 15) ^ (row & 7)) * 8;   // inverse-swizzled source granule
      gload16(kb_bh + (size_t)(t * 64 + row) * (H_ * HD_) + col,
              &Ks[buf][(i * 256 + wbase) * 8]);
    }
  };
  auto stageV = [&](int t, int buf) {
#pragma unroll
    for (int i = 0; i < 4; ++i) {
      int g = i * 256 + tid;
      int row = g >> 3;                       // d
      int col = ((g & 7) ^ (row & 7)) * 8;    // inverse-swizzled source granule (tok)
      gload16(vt_bh + (size_t)row * S_ + t * 64 + col,
              &Vs[buf][(i * 256 + wbase) * 8]);
    }
  };

  auto process = [&](int t, bool diag) {
    const int buf = t & 1;
    f32x4 sc[2][4] = {};
#pragma unroll
    for (int cb = 0; cb < 4; ++cb) {
      int tok = cb * 16 + lr;
#pragma unroll
      for (int kk = 0; kk < 4; ++kk) {
        int addr = tok * 128 + (((kk * 4 + lg) ^ (tok & 7)) * 8);
        bf16x8 bk = *reinterpret_cast<const bf16x8*>(&Ks[buf][addr]);
        sc[0][cb] = __builtin_amdgcn_mfma_f32_16x16x32_bf16(aq[0][kk], bk, sc[0][cb], 0, 0, 0);
        sc[1][cb] = __builtin_amdgcn_mfma_f32_16x16x32_bf16(aq[1][kk], bk, sc[1][cb], 0, 0, 0);
      }
    }
    const float scale = 0.08838834764831845f;
#pragma unroll
    for (int rb = 0; rb < 2; ++rb) {
#pragma unroll
      for (int cb = 0; cb < 4; ++cb) {
        int colg = t * 64 + cb * 16 + lr;
#pragma unroll
        for (int j = 0; j < 4; ++j) {
          float v = sc[rb][cb][j] * scale;
          int rowg = qt * 128 + wave * 32 + rb * 16 + lg * 4 + j;
          sc[rb][cb][j] = (!diag || colg <= rowg) ? v : -1e30f;
        }
      }
#pragma unroll
      for (int j = 0; j < 4; ++j) {
        float v = fmaxf(fmaxf(sc[rb][0][j], sc[rb][1][j]), fmaxf(sc[rb][2][j], sc[rb][3][j]));
        v = fmaxf(v, __shfl_xor(v, 1));
        v = fmaxf(v, __shfl_xor(v, 2));
        v = fmaxf(v, __shfl_xor(v, 4));
        v = fmaxf(v, __shfl_xor(v, 8));
        float mn = fmaxf(m[rb][j], v);
        float alpha = __expf(m[rb][j] - mn);
        float rs = 0.f;
#pragma unroll
        for (int cb = 0; cb < 4; ++cb) {
          float p = __expf(sc[rb][cb][j] - mn);
          sc[rb][cb][j] = p;
          rs += p;
        }
        rs += __shfl_xor(rs, 1);
        rs += __shfl_xor(rs, 2);
        rs += __shfl_xor(rs, 4);
        rs += __shfl_xor(rs, 8);
        l[rb][j] = l[rb][j] * alpha + rs;
        m[rb][j] = mn;
#pragma unroll
        for (int nb = 0; nb < 8; ++nb) o[rb][nb][j] *= alpha;
      }
      // store P rows, XOR-swizzled 8-short granules, row stride 64
#pragma unroll
      for (int cb = 0; cb < 4; ++cb)
#pragma unroll
        for (int j = 0; j < 4; ++j) {
          int row = rb * 16 + lg * 4 + j, col = cb * 16 + lr;
          Ps[wave][row * 64 + (((col >> 3) ^ (row & 7)) * 8) + (col & 7)] = f2b(sc[rb][cb][j]);
        }
    }
    // PV: A = P (LDS, swizzled), B = V^T rows (LDS, swizzled)
#pragma unroll
    for (int kk = 0; kk < 2; ++kk) {
      bf16x8 ap[2];
#pragma unroll
      for (int rb = 0; rb < 2; ++rb) {
        int row = rb * 16 + lr;
        ap[rb] = *reinterpret_cast<const bf16x8*>(
            &Ps[wave][row * 64 + (((kk * 4 + lg) ^ (lr & 7)) * 8)]);
      }
#pragma unroll
      for (int nb = 0; nb < 8; ++nb) {
        int d = nb * 16 + lr;
        bf16x8 bv = *reinterpret_cast<const bf16x8*>(
            &Vs[buf][d * 64 + (((kk * 4 + lg) ^ (lr & 7)) * 8)]);
        o[0][nb] = __builtin_amdgcn_mfma_f32_16x16x32_bf16(ap[0], bv, o[0][nb], 0, 0, 0);
        o[1][nb] = __builtin_amdgcn_mfma_f32_16x16x32_bf16(ap[1], bv, o[1][nb], 0, 0, 0);
      }
    }
  };

  const int nt = 2 * (qt + 1);
  stageK(0, 0);
  stageV(0, 0);
  __syncthreads();
  for (int t = 0; t < nt; ++t) {
    if (t + 1 < nt) {
      stageK(t + 1, (t + 1) & 1);
      stageV(t + 1, (t + 1) & 1);
    }
    process(t, t >= 2 * qt);
    __syncthreads();
  }

#pragma unroll
  for (int rb = 0; rb < 2; ++rb)
#pragma unroll
    for (int j = 0; j < 4; ++j) {
      int q = qt * 128 + wave * 32 + rb * 16 + lg * 4 + j;
      float inv = 1.f / l[rb][j];
      size_t base = ((size_t)(b * S_ + q) * H_ + h) * HD_;
#pragma unroll
      for (int nb = 0; nb < 8; ++nb)
        ab[base + nb * 16 + lr] = f2b(o[rb][nb][j] * inv);
    }
}

// ---------------- gated prefix attention (adds into ab) ----------------
__global__ __launch_bounds__(256) void prefix_kernel(
    const short* __restrict__ qb, const short* __restrict__ pkb, const short* __restrict__ pvb,
    const float* __restrict__ gate, short* __restrict__ ab) {
  __shared__ short pkl[P_ * 128];
  __shared__ short pvl[P_ * 128];
  const int tid = threadIdx.x;
  const int qt = blockIdx.x, bh = blockIdx.y;
  const int b = bh >> 5, h = bh & 31;
  for (int i = tid; i < P_ * 16; i += 256) {
    int row = i >> 4, c = (i & 15) * 8;
    *(bf16x8*)&pkl[row * 128 + c] = *(const bf16x8*)&pkb[(size_t)row * 4096 + h * 128 + c];
    *(bf16x8*)&pvl[row * 128 + c] = *(const bf16x8*)&pvb[(size_t)row * 4096 + h * 128 + c];
  }
  __syncthreads();
  const int r = tid >> 2, p = tid & 3;
  const int q = qt * 64 + r;
  const short* qrow = qb + ((size_t)(b * S_ + q) * H_ + h) * HD_ + p * 32;
  float qv[32];
#pragma unroll
  for (int i = 0; i < 4; ++i) {
    bf16x8 v = *(const bf16x8*)(qrow + i * 8);
#pragma unroll
    for (int e = 0; e < 8; ++e) qv[i * 8 + e] = b2f(v[e]);
  }
  const float scale = 0.08838834764831845f;
  float s[P_];
  float mx = -1e30f;
#pragma unroll
  for (int j = 0; j < P_; ++j) {
    float dot = 0.f;
#pragma unroll
    for (int i = 0; i < 4; ++i) {
      bf16x8 kv = *(const bf16x8*)&pkl[j * 128 + p * 32 + i * 8];
#pragma unroll
      for (int e = 0; e < 8; ++e) dot += qv[i * 8 + e] * b2f(kv[e]);
    }
    dot += __shfl_xor(dot, 1);
    dot += __shfl_xor(dot, 2);
    s[j] = dot * scale;
    mx = fmaxf(mx, s[j]);
  }
  float sum = 0.f;
#pragma unroll
  for (int j = 0; j < P_; ++j) { s[j] = __expf(s[j] - mx); sum += s[j]; }
  float o[32] = {};
#pragma unroll
  for (int j = 0; j < P_; ++j) {
#pragma unroll
    for (int i = 0; i < 4; ++i) {
      bf16x8 vv = *(const bf16x8*)&pvl[j * 128 + p * 32 + i * 8];
#pragma unroll
      for (int e = 0; e < 8; ++e) o[i * 8 + e] += s[j] * b2f(vv[e]);
    }
  }
  float g = tanhf(gate[h]) / sum;
  short* arow = ab + ((size_t)(b * S_ + q) * H_ + h) * HD_ + p * 32;
#pragma unroll
  for (int i = 0; i < 4; ++i) {
    bf16x8 av = *(bf16x8*)(arow + i * 8);
#pragma unroll
    for (int e = 0; e < 8; ++e) av[e] = f2b(b2f(av[e]) + g * o[i * 8 + e]);
    *(bf16x8*)(arow + i * 8) = av;
  }
}

// ---------------- launcher ----------------
extern "C" void kernel_launch(void* const* d_in, const int* in_sizes, int n_in,
                              void* d_out, int out_size, void* d_ws, size_t ws_size,
                              hipStream_t stream) {
  const float* x = (const float*)d_in[0];
  const float* fc = (const float*)d_in[1];
  const float* fs = (const float*)d_in[2];
  const float* prefix = (const float*)d_in[3];
  const float* gate = (const float*)d_in[4];
  const float* wq = (const float*)d_in[5];
  const float* wk = (const float*)d_in[6];
  const float* wv = (const float*)d_in[7];
  const float* wo = (const float*)d_in[8];
  float* out = (float*)d_out;

  char* ws = (char*)d_ws;
  const size_t SZ = (size_t)4096 * 4096 * 2;
  short* xb = (short*)(ws);
  short* wT = (short*)(ws + SZ);     // weight^T slot; reused as V^T after pv GEMM
  short* qbuf = (short*)(ws + 2 * SZ);
  short* kbuf = (short*)(ws + 3 * SZ);
  short* vbuf = (short*)(ws + 4 * SZ);
  short* pb = (short*)(ws + 5 * SZ);
  short* pkb = (short*)(ws + 5 * SZ + (1 << 20));
  short* pvb = (short*)(ws + 5 * SZ + (2 << 20));
  short* abuf = xb;  // alias: x_bf16 dead after V projection
  short* vT = wT;    // alias: w^T slot free between pv GEMM and wo transpose

  dim3 tcg(128, 128), tcb(32, 8);
  dim3 gg(32, 32), gp(32, 1);

  convert_f32_bf16<<<16384, 256, 0, stream>>>(x, xb);
  pad_prefix<<<2048, 256, 0, stream>>>(prefix, pb);

  transpose_convert<<<tcg, tcb, 0, stream>>>(wq, wT, 4096, 4096);
  gemm_bt<short><<<gg, 256, 0, stream>>>(xb, wT, qbuf, 4096, 4096, 4096);

  transpose_convert<<<tcg, tcb, 0, stream>>>(wk, wT, 4096, 4096);
  gemm_bt<short><<<gg, 256, 0, stream>>>(xb, wT, kbuf, 4096, 4096, 4096);
  gemm_bt<short><<<gp, 256, 0, stream>>>(pb, wT, pkb, 128, 4096, 4096);

  transpose_convert<<<tcg, tcb, 0, stream>>>(wv, wT, 4096, 4096);
  gemm_bt<short><<<gg, 256, 0, stream>>>(xb, wT, vbuf, 4096, 4096, 4096);
  gemm_bt<short><<<gp, 256, 0, stream>>>(pb, wT, pvb, 128, 4096, 4096);

  transpose_v<<<dim3(64, 32, 2), 256, 0, stream>>>(vbuf, vT);

  rope_kernel<<<8192, 256, 0, stream>>>(qbuf, fc, fs);
  rope_kernel<<<8192, 256, 0, stream>>>(kbuf, fc, fs);

  attn_kernel<<<dim3(16, 64), 256, 0, stream>>>(qbuf, kbuf, vT, abuf);
  prefix_kernel<<<dim3(32, 64), 256, 0, stream>>>(qbuf, pkb, pvb, gate, abuf);

  transpose_convert<<<tcg, tcb, 0, stream>>>(wo, wT, 4096, 4096);
  gemm_bt<float><<<gg, 256, 0, stream>>>(abuf, wT, out, 4096, 4096, 4096);
}

// Round 4
// 1599.251 us; speedup vs baseline: 1.2205x; 1.0368x over previous
//
#include <hip/hip_runtime.h>
#include <hip/hip_bf16.h>

#define AS1 __attribute__((address_space(1)))
#define AS3 __attribute__((address_space(3)))

typedef __attribute__((ext_vector_type(8))) short bf16x8;
typedef __attribute__((ext_vector_type(4))) float f32x4;

#define B_ 2
#define S_ 2048
#define D_ 4096
#define H_ 32
#define HD_ 128
#define P_ 30

__device__ __forceinline__ short f2b(float f) {
  union { __hip_bfloat16 h; short s; } u;
  u.h = __float2bfloat16(f);
  return u.s;
}
__device__ __forceinline__ float b2f(short s) {
  union { short s; __hip_bfloat16 h; } u;
  u.s = s;
  return __bfloat162float(u.h);
}
__device__ __forceinline__ void gload16(const void* g, void* l) {
  __builtin_amdgcn_global_load_lds((const AS1 void*)g, (AS3 void*)l, 16, 0, 0);
}

// ---------------- elementwise conversion ----------------
__global__ __launch_bounds__(256) void convert_f32_bf16(const float* __restrict__ in,
                                                        short* __restrict__ out) {
  size_t i = ((size_t)blockIdx.x * 256 + threadIdx.x) * 4;
  float4 v = *reinterpret_cast<const float4*>(in + i);
  short4 o;
  o.x = f2b(v.x); o.y = f2b(v.y); o.z = f2b(v.z); o.w = f2b(v.w);
  *reinterpret_cast<short4*>(out + i) = o;
}

// prefix (30 x 4096 f32) -> padded 128 x 4096 bf16 (zeros beyond row 29)
__global__ __launch_bounds__(256) void pad_prefix(const float* __restrict__ p,
                                                  short* __restrict__ pb) {
  int i = blockIdx.x * 256 + threadIdx.x;
  int row = i >> 12, col = i & 4095;
  pb[i] = (row < P_) ? f2b(p[row * D_ + col]) : (short)0;
}

// W (K x N) f32 -> Wt (N x K) bf16, 32x32 LDS tiles
__global__ void transpose_convert(const float* __restrict__ W, short* __restrict__ Wt,
                                  int K, int N) {
  __shared__ float t[32][33];
  int bx = blockIdx.x, by = blockIdx.y;
  int tx = threadIdx.x, ty = threadIdx.y;
#pragma unroll
  for (int i = 0; i < 4; ++i) {
    int r = ty * 4 + i;
    t[r][tx] = W[(size_t)(by * 32 + r) * N + bx * 32 + tx];
  }
  __syncthreads();
#pragma unroll
  for (int i = 0; i < 4; ++i) {
    int r = ty * 4 + i;
    Wt[(size_t)(bx * 32 + r) * K + by * 32 + tx] = f2b(t[tx][r]);
  }
}

// in-place RoPE on (B,S,H,HD) bf16
__global__ __launch_bounds__(256) void rope_kernel(short* __restrict__ t,
                                                   const float* __restrict__ fc,
                                                   const float* __restrict__ fs) {
  size_t g = ((size_t)blockIdx.x * 256 + threadIdx.x) * 8;
  int d = (int)(g & 127);
  int s = (int)((g >> 12) & 2047);
  bf16x8 v = *reinterpret_cast<bf16x8*>(t + g);
  int i0 = d >> 1;
  float4 c = *reinterpret_cast<const float4*>(fc + (size_t)s * 64 + i0);
  float4 sn = *reinterpret_cast<const float4*>(fs + (size_t)s * 64 + i0);
  float cc[4] = {c.x, c.y, c.z, c.w};
  float ss[4] = {sn.x, sn.y, sn.z, sn.w};
  bf16x8 o;
#pragma unroll
  for (int p = 0; p < 4; ++p) {
    float t0 = b2f(v[2 * p]), t1 = b2f(v[2 * p + 1]);
    o[2 * p] = f2b(t0 * cc[p] - t1 * ss[p]);
    o[2 * p + 1] = f2b(t0 * ss[p] + t1 * cc[p]);
  }
  *reinterpret_cast<bf16x8*>(t + g) = o;
}

// ---------------- GEMM (m97 structure) ----------------
// OM: 0 = f32 out, 1 = bf16 out, 2 = bf16 transposed-out (V^T: (b, col, s) layout)
template <int OM>
__global__ __launch_bounds__(256) void gemm_bt(const short* __restrict__ A,
                                               const short* __restrict__ Bt,
                                               void* __restrict__ Cv,
                                               int M, int N, int K) {
  __shared__ short As[128 * 32];
  __shared__ short Bs[128 * 32];
  const int tid = threadIdx.x;
  const int lane = tid & 63;
  const int wbase = tid & 192;
  const int wr = ((tid >> 7) & 1) * 64;
  const int wc = ((tid >> 6) & 1) * 64;
  const int lr = lane & 15;
  const int lk = (lane >> 4) * 8;
  // XCD-aware bijective swizzle (grid blocks % 8 == 0)
  int lin = blockIdx.y * gridDim.x + blockIdx.x;
  int nwg = gridDim.x * gridDim.y;
  int cpx = nwg >> 3;
  int swz = (lin & 7) * cpx + (lin >> 3);
  const int bm = swz / gridDim.x, bn = swz % gridDim.x;
  f32x4 acc[4][4] = {};
  const short* Ab = A + (size_t)bm * 128 * K;
  const short* Bb = Bt + (size_t)bn * 128 * K;
  for (int kt = 0; kt < K; kt += 32) {
    __syncthreads();
#pragma unroll
    for (int i = 0; i < 2; ++i) {
      int f = i * 256 + tid;
      int row = f >> 2, col = (f & 3) * 8;
      gload16(Ab + (size_t)row * K + kt + col, &As[(i * 256 + wbase) * 8]);
      gload16(Bb + (size_t)row * K + kt + col, &Bs[(i * 256 + wbase) * 8]);
    }
    __syncthreads();
    bf16x8 af[4], bfr[4];
#pragma unroll
    for (int m = 0; m < 4; ++m)
      af[m] = *reinterpret_cast<const bf16x8*>(&As[(wr + m * 16 + lr) * 32 + lk]);
#pragma unroll
    for (int n = 0; n < 4; ++n)
      bfr[n] = *reinterpret_cast<const bf16x8*>(&Bs[(wc + n * 16 + lr) * 32 + lk]);
#pragma unroll
    for (int m = 0; m < 4; ++m)
#pragma unroll
      for (int n = 0; n < 4; ++n)
        acc[m][n] = __builtin_amdgcn_mfma_f32_16x16x32_bf16(af[m], bfr[n], acc[m][n], 0, 0, 0);
  }
  const int row0 = bm * 128 + wr + (lane >> 4) * 4;
  const int col0 = bn * 128 + wc + lr;
  if constexpr (OM == 2) {
    // write C^T into (b, col, s) layout, packed 4 bf16 per store
    const int b = row0 >> 11;
    const int s0 = row0 & 2047;
    short* C = (short*)Cv;
#pragma unroll
    for (int m = 0; m < 4; ++m)
#pragma unroll
      for (int n = 0; n < 4; ++n) {
        short4 pk;
        pk.x = f2b(acc[m][n][0]); pk.y = f2b(acc[m][n][1]);
        pk.z = f2b(acc[m][n][2]); pk.w = f2b(acc[m][n][3]);
        size_t idx = ((size_t)(b * 4096 + col0 + n * 16)) * 2048 + s0 + m * 16;
        *reinterpret_cast<short4*>(&C[idx]) = pk;
      }
  } else {
#pragma unroll
    for (int m = 0; m < 4; ++m)
#pragma unroll
      for (int n = 0; n < 4; ++n)
#pragma unroll
        for (int j = 0; j < 4; ++j) {
          size_t idx = (size_t)(row0 + m * 16 + j) * N + col0 + n * 16;
          if constexpr (OM == 1) ((short*)Cv)[idx] = f2b(acc[m][n][j]);
          else ((float*)Cv)[idx] = acc[m][n][j];
        }
  }
}

// ---------------- causal flash attention, 128 q-rows/block ----------------
// Swapped QK^T: S^T = mfma(A=K, B=Q) -> lane holds q-row = lane&15, tokens = lg*4+j.
// Softmax row-reduce: in-register over 16 + shfl_xor(16,32). P-store: packed b64.
__global__ __launch_bounds__(256) void attn_kernel(
    const short* __restrict__ qb, const short* __restrict__ kb, const short* __restrict__ vt,
    short* __restrict__ ab) {
  __shared__ short Ks[2][64 * 128];
  __shared__ short Vs[2][128 * 64];
  __shared__ short Ps[4][32 * 64];
  const int tid = threadIdx.x;
  const int wave = tid >> 6, lane = tid & 63;
  const int wbase = tid & 192;
  const int lr = lane & 15, lg = lane >> 4;
  const int qt = (int)gridDim.x - 1 - (int)blockIdx.x;  // heavy blocks first
  const int bh = blockIdx.y;
  const int b = bh >> 5, h = bh & 31;

  bf16x8 aq[2][4];
#pragma unroll
  for (int rb = 0; rb < 2; ++rb) {
    const short* qrow = qb + ((size_t)(b * S_ + qt * 128 + wave * 32 + rb * 16 + lr) * H_ + h) * HD_;
#pragma unroll
    for (int kk = 0; kk < 4; ++kk)
      aq[rb][kk] = *reinterpret_cast<const bf16x8*>(qrow + kk * 32 + lg * 8);
  }

  float m[2], l[2];
  f32x4 o[2][8] = {};
#pragma unroll
  for (int rb = 0; rb < 2; ++rb) { m[rb] = -1e30f; l[rb] = 0.f; }

  const short* kb_bh = kb + ((size_t)b * S_ * H_ + h) * HD_;
  const short* vt_bh = vt + ((size_t)(b * H_ + h)) * HD_ * S_;

  auto stageK = [&](int t, int buf) {
#pragma unroll
    for (int i = 0; i < 4; ++i) {
      int g = i * 256 + tid;
      int row = g >> 4;
      int col = ((g & 15) ^ (row & 7)) * 8;
      gload16(kb_bh + (size_t)(t * 64 + row) * (H_ * HD_) + col,
              &Ks[buf][(i * 256 + wbase) * 8]);
    }
  };
  auto stageV = [&](int t, int buf) {
#pragma unroll
    for (int i = 0; i < 4; ++i) {
      int g = i * 256 + tid;
      int row = g >> 3;
      int col = ((g & 7) ^ (row & 7)) * 8;
      gload16(vt_bh + (size_t)row * S_ + t * 64 + col,
              &Vs[buf][(i * 256 + wbase) * 8]);
    }
  };

  auto process = [&](int t, bool diag) {
    const int buf = t & 1;
    f32x4 sc[2][4] = {};
    __builtin_amdgcn_s_setprio(1);
#pragma unroll
    for (int cb = 0; cb < 4; ++cb) {
      int tok = cb * 16 + lr;
#pragma unroll
      for (int kk = 0; kk < 4; ++kk) {
        int addr = tok * 128 + (((kk * 4 + lg) ^ (tok & 7)) * 8);
        bf16x8 bk = *reinterpret_cast<const bf16x8*>(&Ks[buf][addr]);
        // swapped: A = K-frag, B = Q-frag
        sc[0][cb] = __builtin_amdgcn_mfma_f32_16x16x32_bf16(bk, aq[0][kk], sc[0][cb], 0, 0, 0);
        sc[1][cb] = __builtin_amdgcn_mfma_f32_16x16x32_bf16(bk, aq[1][kk], sc[1][cb], 0, 0, 0);
      }
    }
    __builtin_amdgcn_s_setprio(0);
    const float scale = 0.08838834764831845f;
    // lane holds: q = rb*16 + lr (row), token = cb*16 + lg*4 + j
    float alpha[2];
#pragma unroll
    for (int rb = 0; rb < 2; ++rb) {
      const int rowg = qt * 128 + wave * 32 + rb * 16 + lr;
#pragma unroll
      for (int cb = 0; cb < 4; ++cb)
#pragma unroll
        for (int j = 0; j < 4; ++j) {
          int colg = t * 64 + cb * 16 + lg * 4 + j;
          float v = sc[rb][cb][j] * scale;
          sc[rb][cb][j] = (!diag || colg <= rowg) ? v : -1e30f;
        }
      float mx = sc[rb][0][0];
#pragma unroll
      for (int cb = 0; cb < 4; ++cb)
#pragma unroll
        for (int j = 0; j < 4; ++j) mx = fmaxf(mx, sc[rb][cb][j]);
      mx = fmaxf(mx, __shfl_xor(mx, 16));
      mx = fmaxf(mx, __shfl_xor(mx, 32));
      float mn = fmaxf(m[rb], mx);
      alpha[rb] = __expf(m[rb] - mn);
      m[rb] = mn;
      float rs = 0.f;
      const int row = rb * 16 + lr;
#pragma unroll
      for (int cb = 0; cb < 4; ++cb) {
        short4 pk;
        float p0 = __expf(sc[rb][cb][0] - mn);
        float p1 = __expf(sc[rb][cb][1] - mn);
        float p2 = __expf(sc[rb][cb][2] - mn);
        float p3 = __expf(sc[rb][cb][3] - mn);
        rs += (p0 + p1) + (p2 + p3);
        pk.x = f2b(p0); pk.y = f2b(p1); pk.z = f2b(p2); pk.w = f2b(p3);
        int gran = (cb * 2 + (lg >> 1)) ^ (lr & 7);
        *reinterpret_cast<short4*>(&Ps[wave][row * 64 + gran * 8 + (lg & 1) * 4]) = pk;
      }
      rs += __shfl_xor(rs, 16);
      rs += __shfl_xor(rs, 32);
      l[rb] = l[rb] * alpha[rb] + rs;
    }
    // rescale o: alpha for q-row lg*4+j lives at lane lg*4+j
#pragma unroll
    for (int rb = 0; rb < 2; ++rb) {
      f32x4 av;
#pragma unroll
      for (int j = 0; j < 4; ++j) av[j] = __shfl(alpha[rb], lg * 4 + j);
#pragma unroll
      for (int nb = 0; nb < 8; ++nb)
#pragma unroll
        for (int j = 0; j < 4; ++j) o[rb][nb][j] *= av[j];
    }
    // PV: A = P (LDS), B = V^T rows (LDS)
#pragma unroll
    for (int kk = 0; kk < 2; ++kk) {
      bf16x8 ap[2];
#pragma unroll
      for (int rb = 0; rb < 2; ++rb) {
        int row = rb * 16 + lr;
        ap[rb] = *reinterpret_cast<const bf16x8*>(
            &Ps[wave][row * 64 + (((kk * 4 + lg) ^ (lr & 7)) * 8)]);
      }
      __builtin_amdgcn_s_setprio(1);
#pragma unroll
      for (int nb = 0; nb < 8; ++nb) {
        int d = nb * 16 + lr;
        bf16x8 bv = *reinterpret_cast<const bf16x8*>(
            &Vs[buf][d * 64 + (((kk * 4 + lg) ^ (lr & 7)) * 8)]);
        o[0][nb] = __builtin_amdgcn_mfma_f32_16x16x32_bf16(ap[0], bv, o[0][nb], 0, 0, 0);
        o[1][nb] = __builtin_amdgcn_mfma_f32_16x16x32_bf16(ap[1], bv, o[1][nb], 0, 0, 0);
      }
      __builtin_amdgcn_s_setprio(0);
    }
  };

  const int nt = 2 * (qt + 1);
  stageK(0, 0);
  stageV(0, 0);
  __syncthreads();
  for (int t = 0; t < nt; ++t) {
    if (t + 1 < nt) {
      stageK(t + 1, (t + 1) & 1);
      stageV(t + 1, (t + 1) & 1);
    }
    process(t, t >= 2 * qt);
    __syncthreads();
  }

#pragma unroll
  for (int rb = 0; rb < 2; ++rb) {
    f32x4 lv;
#pragma unroll
    for (int j = 0; j < 4; ++j) lv[j] = __shfl(l[rb], lg * 4 + j);
#pragma unroll
    for (int j = 0; j < 4; ++j) {
      int q = qt * 128 + wave * 32 + rb * 16 + lg * 4 + j;
      float inv = 1.f / lv[j];
      size_t base = ((size_t)(b * S_ + q) * H_ + h) * HD_;
#pragma unroll
      for (int nb = 0; nb < 8; ++nb)
        ab[base + nb * 16 + lr] = f2b(o[rb][nb][j] * inv);
    }
  }
}

// ---------------- gated prefix attention (adds into ab) ----------------
__global__ __launch_bounds__(256) void prefix_kernel(
    const short* __restrict__ qb, const short* __restrict__ pkb, const short* __restrict__ pvb,
    const float* __restrict__ gate, short* __restrict__ ab) {
  __shared__ short pkl[P_ * 128];
  __shared__ short pvl[P_ * 128];
  const int tid = threadIdx.x;
  const int qt = blockIdx.x, bh = blockIdx.y;
  const int b = bh >> 5, h = bh & 31;
  for (int i = tid; i < P_ * 16; i += 256) {
    int row = i >> 4, c = (i & 15) * 8;
    *(bf16x8*)&pkl[row * 128 + c] = *(const bf16x8*)&pkb[(size_t)row * 4096 + h * 128 + c];
    *(bf16x8*)&pvl[row * 128 + c] = *(const bf16x8*)&pvb[(size_t)row * 4096 + h * 128 + c];
  }
  __syncthreads();
  const int r = tid >> 2, p = tid & 3;
  const int q = qt * 64 + r;
  const short* qrow = qb + ((size_t)(b * S_ + q) * H_ + h) * HD_ + p * 32;
  float qv[32];
#pragma unroll
  for (int i = 0; i < 4; ++i) {
    bf16x8 v = *(const bf16x8*)(qrow + i * 8);
#pragma unroll
    for (int e = 0; e < 8; ++e) qv[i * 8 + e] = b2f(v[e]);
  }
  const float scale = 0.08838834764831845f;
  float s[P_];
  float mx = -1e30f;
#pragma unroll
  for (int j = 0; j < P_; ++j) {
    float dot = 0.f;
#pragma unroll
    for (int i = 0; i < 4; ++i) {
      bf16x8 kv = *(const bf16x8*)&pkl[j * 128 + p * 32 + i * 8];
#pragma unroll
      for (int e = 0; e < 8; ++e) dot += qv[i * 8 + e] * b2f(kv[e]);
    }
    dot += __shfl_xor(dot, 1);
    dot += __shfl_xor(dot, 2);
    s[j] = dot * scale;
    mx = fmaxf(mx, s[j]);
  }
  float sum = 0.f;
#pragma unroll
  for (int j = 0; j < P_; ++j) { s[j] = __expf(s[j] - mx); sum += s[j]; }
  float o[32] = {};
#pragma unroll
  for (int j = 0; j < P_; ++j) {
#pragma unroll
    for (int i = 0; i < 4; ++i) {
      bf16x8 vv = *(const bf16x8*)&pvl[j * 128 + p * 32 + i * 8];
#pragma unroll
      for (int e = 0; e < 8; ++e) o[i * 8 + e] += s[j] * b2f(vv[e]);
    }
  }
  float g = tanhf(gate[h]) / sum;
  short* arow = ab + ((size_t)(b * S_ + q) * H_ + h) * HD_ + p * 32;
#pragma unroll
  for (int i = 0; i < 4; ++i) {
    bf16x8 av = *(bf16x8*)(arow + i * 8);
#pragma unroll
    for (int e = 0; e < 8; ++e) av[e] = f2b(b2f(av[e]) + g * o[i * 8 + e]);
    *(bf16x8*)(arow + i * 8) = av;
  }
}

// ---------------- launcher ----------------
extern "C" void kernel_launch(void* const* d_in, const int* in_sizes, int n_in,
                              void* d_out, int out_size, void* d_ws, size_t ws_size,
                              hipStream_t stream) {
  const float* x = (const float*)d_in[0];
  const float* fc = (const float*)d_in[1];
  const float* fs = (const float*)d_in[2];
  const float* prefix = (const float*)d_in[3];
  const float* gate = (const float*)d_in[4];
  const float* wq = (const float*)d_in[5];
  const float* wk = (const float*)d_in[6];
  const float* wv = (const float*)d_in[7];
  const float* wo = (const float*)d_in[8];
  float* out = (float*)d_out;

  char* ws = (char*)d_ws;
  const size_t SZ = (size_t)4096 * 4096 * 2;
  short* xb = (short*)(ws);
  short* wT = (short*)(ws + SZ);
  short* qbuf = (short*)(ws + 2 * SZ);
  short* kbuf = (short*)(ws + 3 * SZ);
  short* vT = (short*)(ws + 4 * SZ);   // V^T written directly by gemm_bt<2>
  short* pb = (short*)(ws + 5 * SZ);
  short* pkb = (short*)(ws + 5 * SZ + (1 << 20));
  short* pvb = (short*)(ws + 5 * SZ + (2 << 20));
  short* abuf = xb;  // alias: x_bf16 dead after V projection

  dim3 tcg(128, 128), tcb(32, 8);
  dim3 gg(32, 32), gp(32, 1);

  convert_f32_bf16<<<16384, 256, 0, stream>>>(x, xb);
  pad_prefix<<<2048, 256, 0, stream>>>(prefix, pb);

  transpose_convert<<<tcg, tcb, 0, stream>>>(wq, wT, 4096, 4096);
  gemm_bt<1><<<gg, 256, 0, stream>>>(xb, wT, qbuf, 4096, 4096, 4096);

  transpose_convert<<<tcg, tcb, 0, stream>>>(wk, wT, 4096, 4096);
  gemm_bt<1><<<gg, 256, 0, stream>>>(xb, wT, kbuf, 4096, 4096, 4096);
  gemm_bt<1><<<gp, 256, 0, stream>>>(pb, wT, pkb, 128, 4096, 4096);

  transpose_convert<<<tcg, tcb, 0, stream>>>(wv, wT, 4096, 4096);
  gemm_bt<2><<<gg, 256, 0, stream>>>(xb, wT, vT, 4096, 4096, 4096);
  gemm_bt<1><<<gp, 256, 0, stream>>>(pb, wT, pvb, 128, 4096, 4096);

  rope_kernel<<<8192, 256, 0, stream>>>(qbuf, fc, fs);
  rope_kernel<<<8192, 256, 0, stream>>>(kbuf, fc, fs);

  attn_kernel<<<dim3(16, 64), 256, 0, stream>>>(qbuf, kbuf, vT, abuf);
  prefix_kernel<<<dim3(32, 64), 256, 0, stream>>>(qbuf, pkb, pvb, gate, abuf);

  transpose_convert<<<tcg, tcb, 0, stream>>>(wo, wT, 4096, 4096);
  gemm_bt<0><<<gg, 256, 0, stream>>>(abuf, wT, out, 4096, 4096, 4096);
}

// Round 5
// 1269.755 us; speedup vs baseline: 1.5372x; 1.2595x over previous
//
#include <hip/hip_runtime.h>
#include <hip/hip_bf16.h>

#define AS1 __attribute__((address_space(1)))
#define AS3 __attribute__((address_space(3)))

typedef __attribute__((ext_vector_type(8))) short bf16x8;
typedef __attribute__((ext_vector_type(4))) float f32x4;

#define B_ 2
#define S_ 2048
#define D_ 4096
#define H_ 32
#define HD_ 128
#define P_ 30

__device__ __forceinline__ short f2b(float f) {
  union { __hip_bfloat16 h; short s; } u;
  u.h = __float2bfloat16(f);
  return u.s;
}
__device__ __forceinline__ float b2f(short s) {
  union { short s; __hip_bfloat16 h; } u;
  u.s = s;
  return __bfloat162float(u.h);
}
__device__ __forceinline__ void gload16(const void* g, void* l) {
  __builtin_amdgcn_global_load_lds((const AS1 void*)g, (AS3 void*)l, 16, 0, 0);
}

// ---------------- elementwise conversion ----------------
__global__ __launch_bounds__(256) void convert_f32_bf16(const float* __restrict__ in,
                                                        short* __restrict__ out) {
  size_t i = ((size_t)blockIdx.x * 256 + threadIdx.x) * 4;
  float4 v = *reinterpret_cast<const float4*>(in + i);
  short4 o;
  o.x = f2b(v.x); o.y = f2b(v.y); o.z = f2b(v.z); o.w = f2b(v.w);
  *reinterpret_cast<short4*>(out + i) = o;
}

// prefix (30 x 4096 f32) -> padded 128 x 4096 bf16 (zeros beyond row 29)
__global__ __launch_bounds__(256) void pad_prefix(const float* __restrict__ p,
                                                  short* __restrict__ pb) {
  int i = blockIdx.x * 256 + threadIdx.x;
  int row = i >> 12, col = i & 4095;
  pb[i] = (row < P_) ? f2b(p[row * D_ + col]) : (short)0;
}

// W (K x N) f32 -> Wt (N x K) bf16, 32x32 LDS tiles
__global__ void transpose_convert(const float* __restrict__ W, short* __restrict__ Wt,
                                  int K, int N) {
  __shared__ float t[32][33];
  int bx = blockIdx.x, by = blockIdx.y;
  int tx = threadIdx.x, ty = threadIdx.y;
#pragma unroll
  for (int i = 0; i < 4; ++i) {
    int r = ty * 4 + i;
    t[r][tx] = W[(size_t)(by * 32 + r) * N + bx * 32 + tx];
  }
  __syncthreads();
#pragma unroll
  for (int i = 0; i < 4; ++i) {
    int r = ty * 4 + i;
    Wt[(size_t)(bx * 32 + r) * K + by * 32 + tx] = f2b(t[tx][r]);
  }
}

// in-place RoPE on (B,S,H,HD) bf16
__global__ __launch_bounds__(256) void rope_kernel(short* __restrict__ t,
                                                   const float* __restrict__ fc,
                                                   const float* __restrict__ fs) {
  size_t g = ((size_t)blockIdx.x * 256 + threadIdx.x) * 8;
  int d = (int)(g & 127);
  int s = (int)((g >> 12) & 2047);
  bf16x8 v = *reinterpret_cast<bf16x8*>(t + g);
  int i0 = d >> 1;
  float4 c = *reinterpret_cast<const float4*>(fc + (size_t)s * 64 + i0);
  float4 sn = *reinterpret_cast<const float4*>(fs + (size_t)s * 64 + i0);
  float cc[4] = {c.x, c.y, c.z, c.w};
  float ss[4] = {sn.x, sn.y, sn.z, sn.w};
  bf16x8 o;
#pragma unroll
  for (int p = 0; p < 4; ++p) {
    float t0 = b2f(v[2 * p]), t1 = b2f(v[2 * p + 1]);
    o[2 * p] = f2b(t0 * cc[p] - t1 * ss[p]);
    o[2 * p + 1] = f2b(t0 * ss[p] + t1 * cc[p]);
  }
  *reinterpret_cast<bf16x8*>(t + g) = o;
}

// ---------------- small GEMM (m97 structure) for prefix projections ----------------
template <int OM>
__global__ __launch_bounds__(256) void gemm_bt(const short* __restrict__ A,
                                               const short* __restrict__ Bt,
                                               void* __restrict__ Cv,
                                               int M, int N, int K) {
  __shared__ short As[128 * 32];
  __shared__ short Bs[128 * 32];
  const int tid = threadIdx.x;
  const int lane = tid & 63;
  const int wbase = tid & 192;
  const int wr = ((tid >> 7) & 1) * 64;
  const int wc = ((tid >> 6) & 1) * 64;
  const int lr = lane & 15;
  const int lk = (lane >> 4) * 8;
  int lin = blockIdx.y * gridDim.x + blockIdx.x;
  int nwg = gridDim.x * gridDim.y;
  int cpx = nwg >> 3;
  int swz = (lin & 7) * cpx + (lin >> 3);
  const int bm = swz / gridDim.x, bn = swz % gridDim.x;
  f32x4 acc[4][4] = {};
  const short* Ab = A + (size_t)bm * 128 * K;
  const short* Bb = Bt + (size_t)bn * 128 * K;
  for (int kt = 0; kt < K; kt += 32) {
    __syncthreads();
#pragma unroll
    for (int i = 0; i < 2; ++i) {
      int f = i * 256 + tid;
      int row = f >> 2, col = (f & 3) * 8;
      gload16(Ab + (size_t)row * K + kt + col, &As[(i * 256 + wbase) * 8]);
      gload16(Bb + (size_t)row * K + kt + col, &Bs[(i * 256 + wbase) * 8]);
    }
    __syncthreads();
    bf16x8 af[4], bfr[4];
#pragma unroll
    for (int m = 0; m < 4; ++m)
      af[m] = *reinterpret_cast<const bf16x8*>(&As[(wr + m * 16 + lr) * 32 + lk]);
#pragma unroll
    for (int n = 0; n < 4; ++n)
      bfr[n] = *reinterpret_cast<const bf16x8*>(&Bs[(wc + n * 16 + lr) * 32 + lk]);
#pragma unroll
    for (int m = 0; m < 4; ++m)
#pragma unroll
      for (int n = 0; n < 4; ++n)
        acc[m][n] = __builtin_amdgcn_mfma_f32_16x16x32_bf16(af[m], bfr[n], acc[m][n], 0, 0, 0);
  }
  const int row0 = bm * 128 + wr + (lane >> 4) * 4;
  const int col0 = bn * 128 + wc + lr;
#pragma unroll
  for (int m = 0; m < 4; ++m)
#pragma unroll
    for (int n = 0; n < 4; ++n)
#pragma unroll
      for (int j = 0; j < 4; ++j) {
        size_t idx = (size_t)(row0 + m * 16 + j) * N + col0 + n * 16;
        if constexpr (OM == 1) ((short*)Cv)[idx] = f2b(acc[m][n][j]);
        else ((float*)Cv)[idx] = acc[m][n][j];
      }
}

// ---------------- 256x256 8-wave GEMM, 4-phase counted-vmcnt pipeline ----------------
// C(MxN) = A(MxK) * Bt(NxK)^T, bf16 in, f32 acc. BK=64, 2-slot LDS dbuf (128 KB).
// Per K-tile: 4 phases (mh x kh), 16 MFMA each. Staging: tile t+1's B + A-bottom
// during t (into unread slot); tile t+2's A-top at ph3/ph4 into current slot
// (regions consumed at ph1/ph2; ph2's post-lgkmcnt barrier orders the handoff).
// vmcnt(2) once per tile keeps the 2 newest (t+2) loads in flight.
// OM: 0 = f32 out, 1 = bf16 out, 2 = bf16 transposed-out (V^T (b, col, s))
#define PHASE(mh, kh, STAGE, TAIL)                                              \
  {                                                                             \
    bf16x8 af[4], bfr[4];                                                       \
    const int pg = (((kh)*4 + lg) ^ (lr & 7)) * 8;                              \
    _Pragma("unroll") for (int mm = 0; mm < 4; ++mm)                            \
      af[mm] = *(const bf16x8*)&As[slot][(wr + (mh)*64 + mm*16 + lr)*64 + pg];  \
    _Pragma("unroll") for (int nn = 0; nn < 4; ++nn)                            \
      bfr[nn] = *(const bf16x8*)&Bs[slot][(wc + nn*16 + lr)*64 + pg];           \
    STAGE;                                                                      \
    __builtin_amdgcn_s_barrier();                                               \
    asm volatile("s_waitcnt lgkmcnt(0)" ::: "memory");                          \
    __builtin_amdgcn_sched_barrier(0);                                          \
    __builtin_amdgcn_s_setprio(1);                                              \
    _Pragma("unroll") for (int mm = 0; mm < 4; ++mm)                            \
      _Pragma("unroll") for (int nn = 0; nn < 4; ++nn)                          \
        acc[(mh)*4 + mm][nn] = __builtin_amdgcn_mfma_f32_16x16x32_bf16(         \
            af[mm], bfr[nn], acc[(mh)*4 + mm][nn], 0, 0, 0);                    \
    __builtin_amdgcn_s_setprio(0);                                              \
    TAIL;                                                                       \
    __builtin_amdgcn_s_barrier();                                               \
  }

template <int OM>
__global__ __launch_bounds__(512, 2) void gemm256(const short* __restrict__ A,
                                                  const short* __restrict__ Bt,
                                                  void* __restrict__ Cv,
                                                  int M, int N, int K) {
  __shared__ short As[2][256 * 64];
  __shared__ short Bs[2][256 * 64];
  const int tid = threadIdx.x;
  const int w = tid >> 6;
  const int lane = tid & 63;
  const int lr = lane & 15, lg = lane >> 4;
  const int wr = (w >> 2) * 128;   // wave row (2 rows of waves)
  const int wc = (w & 3) * 64;     // wave col (4 cols of waves)
  int lin = blockIdx.y * gridDim.x + blockIdx.x;
  int nwg = gridDim.x * gridDim.y;
  int cpx = nwg >> 3;
  int swz = (lin & 7) * cpx + (lin >> 3);
  const int bm = swz / gridDim.x, bn = swz % gridDim.x;

  const short* Ab = A + (size_t)bm * 256 * K;
  const short* Bb = Bt + (size_t)bn * 256 * K;
  const int NT = K >> 6;

  f32x4 acc[8][4] = {};

  // stage one row-octet (8 rows x 64 cols) with granule XOR pre-swizzle on source
  auto stA = [&](int slot_, int r0, int kt) {
    int row = r0 + (lane >> 3);
    int gsrc = (lane & 7) ^ ((lane >> 3) & 7);
    gload16(Ab + (size_t)row * K + kt + gsrc * 8, &As[slot_][r0 * 64]);
  };
  auto stB = [&](int slot_, int r0, int kt) {
    int row = r0 + (lane >> 3);
    int gsrc = (lane & 7) ^ ((lane >> 3) & 7);
    gload16(Bb + (size_t)row * K + kt + gsrc * 8, &Bs[slot_][r0 * 64]);
  };

  const int q2 = w * 2, q4 = w * 4;
  const int rt0 = (q2 < 8 ? 0 : 64) + q2 * 8;           // A-top octet 0 (rows 0-63 / 128-191)
  const int rt1 = (q2 + 1 < 8 ? 0 : 64) + (q2 + 1) * 8; // A-top octet 1

  // prologue: fully stage tiles 0 and 1
  {
#pragma unroll
    for (int i = 0; i < 4; ++i) stB(0, (q4 + i) * 8, 0);
    stA(0, rt0, 0); stA(0, 64 + rt0, 0);
    stA(0, rt1, 0); stA(0, 64 + rt1, 0);
#pragma unroll
    for (int i = 0; i < 4; ++i) stB(1, (q4 + i) * 8, 64);
    stA(1, rt0, 64); stA(1, 64 + rt0, 64);
    stA(1, rt1, 64); stA(1, 64 + rt1, 64);
  }
  asm volatile("s_waitcnt vmcnt(8)" ::: "memory");
  __builtin_amdgcn_s_barrier();

  for (int t = 0; t < NT; ++t) {
    const int slot = t & 1;
    const int ns = slot ^ 1;
    const int kt1 = (t + 1) << 6, kt2 = (t + 2) << 6;
    const bool s6 = (t >= 1) && (t + 1 < NT);
    const bool s2 = (t + 2 < NT);

    PHASE(0, 0,
          { if (s6) { stB(ns, (q4 + 0) * 8, kt1); stB(ns, (q4 + 1) * 8, kt1); } },
          {});
    PHASE(0, 1,
          { if (s6) { stB(ns, (q4 + 2) * 8, kt1); stB(ns, (q4 + 3) * 8, kt1);
                      stA(ns, 64 + rt0, kt1);     stA(ns, 64 + rt1, kt1); } },
          {});
    PHASE(1, 0,
          { if (s2) stA(slot, rt0, kt2); },
          {});
    PHASE(1, 1,
          { if (s2) stA(slot, rt1, kt2); },
          { if (s2) asm volatile("s_waitcnt vmcnt(2)" ::: "memory");
            else    asm volatile("s_waitcnt vmcnt(0)" ::: "memory"); });
  }

  const int row0 = bm * 256 + wr + lg * 4;
  const int col0 = bn * 256 + wc + lr;
  if constexpr (OM == 2) {
    short* C = (short*)Cv;
#pragma unroll
    for (int mf = 0; mf < 8; ++mf)
#pragma unroll
      for (int n = 0; n < 4; ++n) {
        int r0 = row0 + mf * 16;
        int bb = r0 >> 11, s0 = r0 & 2047;
        short4 pk;
        pk.x = f2b(acc[mf][n][0]); pk.y = f2b(acc[mf][n][1]);
        pk.z = f2b(acc[mf][n][2]); pk.w = f2b(acc[mf][n][3]);
        size_t idx = ((size_t)(bb * 4096 + col0 + n * 16)) * 2048 + s0;
        *reinterpret_cast<short4*>(&C[idx]) = pk;
      }
  } else {
#pragma unroll
    for (int mf = 0; mf < 8; ++mf)
#pragma unroll
      for (int n = 0; n < 4; ++n)
#pragma unroll
        for (int j = 0; j < 4; ++j) {
          size_t idx = (size_t)(row0 + mf * 16 + j) * N + col0 + n * 16;
          if constexpr (OM == 1) ((short*)Cv)[idx] = f2b(acc[mf][n][j]);
          else ((float*)Cv)[idx] = acc[mf][n][j];
        }
  }
}

// ---------------- causal flash attention, 128 q-rows/block ----------------
__global__ __launch_bounds__(256) void attn_kernel(
    const short* __restrict__ qb, const short* __restrict__ kb, const short* __restrict__ vt,
    short* __restrict__ ab) {
  __shared__ short Ks[2][64 * 128];
  __shared__ short Vs[2][128 * 64];
  __shared__ short Ps[4][32 * 64];
  const int tid = threadIdx.x;
  const int wave = tid >> 6, lane = tid & 63;
  const int wbase = tid & 192;
  const int lr = lane & 15, lg = lane >> 4;
  const int qt = (int)gridDim.x - 1 - (int)blockIdx.x;
  const int bh = blockIdx.y;
  const int b = bh >> 5, h = bh & 31;

  bf16x8 aq[2][4];
#pragma unroll
  for (int rb = 0; rb < 2; ++rb) {
    const short* qrow = qb + ((size_t)(b * S_ + qt * 128 + wave * 32 + rb * 16 + lr) * H_ + h) * HD_;
#pragma unroll
    for (int kk = 0; kk < 4; ++kk)
      aq[rb][kk] = *reinterpret_cast<const bf16x8*>(qrow + kk * 32 + lg * 8);
  }

  float m[2], l[2];
  f32x4 o[2][8] = {};
#pragma unroll
  for (int rb = 0; rb < 2; ++rb) { m[rb] = -1e30f; l[rb] = 0.f; }

  const short* kb_bh = kb + ((size_t)b * S_ * H_ + h) * HD_;
  const short* vt_bh = vt + ((size_t)(b * H_ + h)) * HD_ * S_;

  auto stageK = [&](int t, int buf) {
#pragma unroll
    for (int i = 0; i < 4; ++i) {
      int g = i * 256 + tid;
      int row = g >> 4;
      int col = ((g & 15) ^ (row & 7)) * 8;
      gload16(kb_bh + (size_t)(t * 64 + row) * (H_ * HD_) + col,
              &Ks[buf][(i * 256 + wbase) * 8]);
    }
  };
  auto stageV = [&](int t, int buf) {
#pragma unroll
    for (int i = 0; i < 4; ++i) {
      int g = i * 256 + tid;
      int row = g >> 3;
      int col = ((g & 7) ^ (row & 7)) * 8;
      gload16(vt_bh + (size_t)row * S_ + t * 64 + col,
              &Vs[buf][(i * 256 + wbase) * 8]);
    }
  };

  auto process = [&](int t, bool diag) {
    const int buf = t & 1;
    f32x4 sc[2][4] = {};
    __builtin_amdgcn_s_setprio(1);
#pragma unroll
    for (int cb = 0; cb < 4; ++cb) {
      int tok = cb * 16 + lr;
#pragma unroll
      for (int kk = 0; kk < 4; ++kk) {
        int addr = tok * 128 + (((kk * 4 + lg) ^ (tok & 7)) * 8);
        bf16x8 bk = *reinterpret_cast<const bf16x8*>(&Ks[buf][addr]);
        sc[0][cb] = __builtin_amdgcn_mfma_f32_16x16x32_bf16(bk, aq[0][kk], sc[0][cb], 0, 0, 0);
        sc[1][cb] = __builtin_amdgcn_mfma_f32_16x16x32_bf16(bk, aq[1][kk], sc[1][cb], 0, 0, 0);
      }
    }
    __builtin_amdgcn_s_setprio(0);
    const float scale = 0.08838834764831845f;
    float alpha[2];
#pragma unroll
    for (int rb = 0; rb < 2; ++rb) {
      const int rowg = qt * 128 + wave * 32 + rb * 16 + lr;
#pragma unroll
      for (int cb = 0; cb < 4; ++cb)
#pragma unroll
        for (int j = 0; j < 4; ++j) {
          int colg = t * 64 + cb * 16 + lg * 4 + j;
          float v = sc[rb][cb][j] * scale;
          sc[rb][cb][j] = (!diag || colg <= rowg) ? v : -1e30f;
        }
      float mx = sc[rb][0][0];
#pragma unroll
      for (int cb = 0; cb < 4; ++cb)
#pragma unroll
        for (int j = 0; j < 4; ++j) mx = fmaxf(mx, sc[rb][cb][j]);
      mx = fmaxf(mx, __shfl_xor(mx, 16));
      mx = fmaxf(mx, __shfl_xor(mx, 32));
      float mn = fmaxf(m[rb], mx);
      alpha[rb] = __expf(m[rb] - mn);
      m[rb] = mn;
      float rs = 0.f;
      const int row = rb * 16 + lr;
#pragma unroll
      for (int cb = 0; cb < 4; ++cb) {
        short4 pk;
        float p0 = __expf(sc[rb][cb][0] - mn);
        float p1 = __expf(sc[rb][cb][1] - mn);
        float p2 = __expf(sc[rb][cb][2] - mn);
        float p3 = __expf(sc[rb][cb][3] - mn);
        rs += (p0 + p1) + (p2 + p3);
        pk.x = f2b(p0); pk.y = f2b(p1); pk.z = f2b(p2); pk.w = f2b(p3);
        int gran = (cb * 2 + (lg >> 1)) ^ (lr & 7);
        *reinterpret_cast<short4*>(&Ps[wave][row * 64 + gran * 8 + (lg & 1) * 4]) = pk;
      }
      rs += __shfl_xor(rs, 16);
      rs += __shfl_xor(rs, 32);
      l[rb] = l[rb] * alpha[rb] + rs;
    }
#pragma unroll
    for (int rb = 0; rb < 2; ++rb) {
      f32x4 av;
#pragma unroll
      for (int j = 0; j < 4; ++j) av[j] = __shfl(alpha[rb], lg * 4 + j);
#pragma unroll
      for (int nb = 0; nb < 8; ++nb)
#pragma unroll
        for (int j = 0; j < 4; ++j) o[rb][nb][j] *= av[j];
    }
#pragma unroll
    for (int kk = 0; kk < 2; ++kk) {
      bf16x8 ap[2];
#pragma unroll
      for (int rb = 0; rb < 2; ++rb) {
        int row = rb * 16 + lr;
        ap[rb] = *reinterpret_cast<const bf16x8*>(
            &Ps[wave][row * 64 + (((kk * 4 + lg) ^ (lr & 7)) * 8)]);
      }
      __builtin_amdgcn_s_setprio(1);
#pragma unroll
      for (int nb = 0; nb < 8; ++nb) {
        int d = nb * 16 + lr;
        bf16x8 bv = *reinterpret_cast<const bf16x8*>(
            &Vs[buf][d * 64 + (((kk * 4 + lg) ^ (lr & 7)) * 8)]);
        o[0][nb] = __builtin_amdgcn_mfma_f32_16x16x32_bf16(ap[0], bv, o[0][nb], 0, 0, 0);
        o[1][nb] = __builtin_amdgcn_mfma_f32_16x16x32_bf16(ap[1], bv, o[1][nb], 0, 0, 0);
      }
      __builtin_amdgcn_s_setprio(0);
    }
  };

  const int nt = 2 * (qt + 1);
  stageK(0, 0);
  stageV(0, 0);
  __syncthreads();
  for (int t = 0; t < nt; ++t) {
    if (t + 1 < nt) {
      stageK(t + 1, (t + 1) & 1);
      stageV(t + 1, (t + 1) & 1);
    }
    process(t, t >= 2 * qt);
    __syncthreads();
  }

#pragma unroll
  for (int rb = 0; rb < 2; ++rb) {
    f32x4 lv;
#pragma unroll
    for (int j = 0; j < 4; ++j) lv[j] = __shfl(l[rb], lg * 4 + j);
#pragma unroll
    for (int j = 0; j < 4; ++j) {
      int q = qt * 128 + wave * 32 + rb * 16 + lg * 4 + j;
      float inv = 1.f / lv[j];
      size_t base = ((size_t)(b * S_ + q) * H_ + h) * HD_;
#pragma unroll
      for (int nb = 0; nb < 8; ++nb)
        ab[base + nb * 16 + lr] = f2b(o[rb][nb][j] * inv);
    }
  }
}

// ---------------- gated prefix attention (adds into ab) ----------------
__global__ __launch_bounds__(256) void prefix_kernel(
    const short* __restrict__ qb, const short* __restrict__ pkb, const short* __restrict__ pvb,
    const float* __restrict__ gate, short* __restrict__ ab) {
  __shared__ short pkl[P_ * 128];
  __shared__ short pvl[P_ * 128];
  const int tid = threadIdx.x;
  const int qt = blockIdx.x, bh = blockIdx.y;
  const int b = bh >> 5, h = bh & 31;
  for (int i = tid; i < P_ * 16; i += 256) {
    int row = i >> 4, c = (i & 15) * 8;
    *(bf16x8*)&pkl[row * 128 + c] = *(const bf16x8*)&pkb[(size_t)row * 4096 + h * 128 + c];
    *(bf16x8*)&pvl[row * 128 + c] = *(const bf16x8*)&pvb[(size_t)row * 4096 + h * 128 + c];
  }
  __syncthreads();
  const int r = tid >> 2, p = tid & 3;
  const int q = qt * 64 + r;
  const short* qrow = qb + ((size_t)(b * S_ + q) * H_ + h) * HD_ + p * 32;
  float qv[32];
#pragma unroll
  for (int i = 0; i < 4; ++i) {
    bf16x8 v = *(const bf16x8*)(qrow + i * 8);
#pragma unroll
    for (int e = 0; e < 8; ++e) qv[i * 8 + e] = b2f(v[e]);
  }
  const float scale = 0.08838834764831845f;
  float s[P_];
  float mx = -1e30f;
#pragma unroll
  for (int j = 0; j < P_; ++j) {
    float dot = 0.f;
#pragma unroll
    for (int i = 0; i < 4; ++i) {
      bf16x8 kv = *(const bf16x8*)&pkl[j * 128 + p * 32 + i * 8];
#pragma unroll
      for (int e = 0; e < 8; ++e) dot += qv[i * 8 + e] * b2f(kv[e]);
    }
    dot += __shfl_xor(dot, 1);
    dot += __shfl_xor(dot, 2);
    s[j] = dot * scale;
    mx = fmaxf(mx, s[j]);
  }
  float sum = 0.f;
#pragma unroll
  for (int j = 0; j < P_; ++j) { s[j] = __expf(s[j] - mx); sum += s[j]; }
  float o[32] = {};
#pragma unroll
  for (int j = 0; j < P_; ++j) {
#pragma unroll
    for (int i = 0; i < 4; ++i) {
      bf16x8 vv = *(const bf16x8*)&pvl[j * 128 + p * 32 + i * 8];
#pragma unroll
      for (int e = 0; e < 8; ++e) o[i * 8 + e] += s[j] * b2f(vv[e]);
    }
  }
  float g = tanhf(gate[h]) / sum;
  short* arow = ab + ((size_t)(b * S_ + q) * H_ + h) * HD_ + p * 32;
#pragma unroll
  for (int i = 0; i < 4; ++i) {
    bf16x8 av = *(bf16x8*)(arow + i * 8);
#pragma unroll
    for (int e = 0; e < 8; ++e) av[e] = f2b(b2f(av[e]) + g * o[i * 8 + e]);
    *(bf16x8*)(arow + i * 8) = av;
  }
}

// ---------------- launcher ----------------
extern "C" void kernel_launch(void* const* d_in, const int* in_sizes, int n_in,
                              void* d_out, int out_size, void* d_ws, size_t ws_size,
                              hipStream_t stream) {
  const float* x = (const float*)d_in[0];
  const float* fc = (const float*)d_in[1];
  const float* fs = (const float*)d_in[2];
  const float* prefix = (const float*)d_in[3];
  const float* gate = (const float*)d_in[4];
  const float* wq = (const float*)d_in[5];
  const float* wk = (const float*)d_in[6];
  const float* wv = (const float*)d_in[7];
  const float* wo = (const float*)d_in[8];
  float* out = (float*)d_out;

  char* ws = (char*)d_ws;
  const size_t SZ = (size_t)4096 * 4096 * 2;
  short* xb = (short*)(ws);
  short* wT = (short*)(ws + SZ);
  short* qbuf = (short*)(ws + 2 * SZ);
  short* kbuf = (short*)(ws + 3 * SZ);
  short* vT = (short*)(ws + 4 * SZ);   // V^T written directly by gemm256<2>
  short* pb = (short*)(ws + 5 * SZ);
  short* pkb = (short*)(ws + 5 * SZ + (1 << 20));
  short* pvb = (short*)(ws + 5 * SZ + (2 << 20));
  short* abuf = xb;  // alias: x_bf16 dead after V projection

  dim3 tcg(128, 128), tcb(32, 8);
  dim3 gg(16, 16), gp(32, 1);

  convert_f32_bf16<<<16384, 256, 0, stream>>>(x, xb);
  pad_prefix<<<2048, 256, 0, stream>>>(prefix, pb);

  transpose_convert<<<tcg, tcb, 0, stream>>>(wq, wT, 4096, 4096);
  gemm256<1><<<gg, 512, 0, stream>>>(xb, wT, qbuf, 4096, 4096, 4096);

  transpose_convert<<<tcg, tcb, 0, stream>>>(wk, wT, 4096, 4096);
  gemm256<1><<<gg, 512, 0, stream>>>(xb, wT, kbuf, 4096, 4096, 4096);
  gemm_bt<1><<<gp, 256, 0, stream>>>(pb, wT, pkb, 128, 4096, 4096);

  transpose_convert<<<tcg, tcb, 0, stream>>>(wv, wT, 4096, 4096);
  gemm256<2><<<gg, 512, 0, stream>>>(xb, wT, vT, 4096, 4096, 4096);
  gemm_bt<1><<<gp, 256, 0, stream>>>(pb, wT, pvb, 128, 4096, 4096);

  rope_kernel<<<8192, 256, 0, stream>>>(qbuf, fc, fs);
  rope_kernel<<<8192, 256, 0, stream>>>(kbuf, fc, fs);

  attn_kernel<<<dim3(16, 64), 256, 0, stream>>>(qbuf, kbuf, vT, abuf);
  prefix_kernel<<<dim3(32, 64), 256, 0, stream>>>(qbuf, pkb, pvb, gate, abuf);

  transpose_convert<<<tcg, tcb, 0, stream>>>(wo, wT, 4096, 4096);
  gemm256<0><<<gg, 512, 0, stream>>>(abuf, wT, out, 4096, 4096, 4096);
}

// Round 6
// 1106.005 us; speedup vs baseline: 1.7648x; 1.1481x over previous
//
#include <hip/hip_runtime.h>
#include <hip/hip_bf16.h>

#define AS1 __attribute__((address_space(1)))
#define AS3 __attribute__((address_space(3)))

typedef __attribute__((ext_vector_type(8))) short bf16x8;
typedef __attribute__((ext_vector_type(4))) float f32x4;

#define B_ 2
#define S_ 2048
#define D_ 4096
#define H_ 32
#define HD_ 128
#define P_ 30

__device__ __forceinline__ short f2b(float f) {
  union { __hip_bfloat16 h; short s; } u;
  u.h = __float2bfloat16(f);
  return u.s;
}
__device__ __forceinline__ float b2f(short s) {
  union { short s; __hip_bfloat16 h; } u;
  u.s = s;
  return __bfloat162float(u.h);
}
__device__ __forceinline__ void gload16(const void* g, void* l) {
  __builtin_amdgcn_global_load_lds((const AS1 void*)g, (AS3 void*)l, 16, 0, 0);
}

// ---------------- elementwise conversion ----------------
__global__ __launch_bounds__(256) void convert_f32_bf16(const float* __restrict__ in,
                                                        short* __restrict__ out) {
  size_t i = ((size_t)blockIdx.x * 256 + threadIdx.x) * 4;
  float4 v = *reinterpret_cast<const float4*>(in + i);
  short4 o;
  o.x = f2b(v.x); o.y = f2b(v.y); o.z = f2b(v.z); o.w = f2b(v.w);
  *reinterpret_cast<short4*>(out + i) = o;
}

// prefix (30 x 4096 f32) -> padded 128 x 4096 bf16 (zeros beyond row 29)
__global__ __launch_bounds__(256) void pad_prefix(const float* __restrict__ p,
                                                  short* __restrict__ pb) {
  int i = blockIdx.x * 256 + threadIdx.x;
  int row = i >> 12, col = i & 4095;
  pb[i] = (row < P_) ? f2b(p[row * D_ + col]) : (short)0;
}

// W (K x N) f32 -> Wt (N x K) bf16, 32x32 LDS tiles
__global__ void transpose_convert(const float* __restrict__ W, short* __restrict__ Wt,
                                  int K, int N) {
  __shared__ float t[32][33];
  int bx = blockIdx.x, by = blockIdx.y;
  int tx = threadIdx.x, ty = threadIdx.y;
#pragma unroll
  for (int i = 0; i < 4; ++i) {
    int r = ty * 4 + i;
    t[r][tx] = W[(size_t)(by * 32 + r) * N + bx * 32 + tx];
  }
  __syncthreads();
#pragma unroll
  for (int i = 0; i < 4; ++i) {
    int r = ty * 4 + i;
    Wt[(size_t)(bx * 32 + r) * K + by * 32 + tx] = f2b(t[tx][r]);
  }
}

// in-place RoPE on (B,S,H,HD) bf16
__global__ __launch_bounds__(256) void rope_kernel(short* __restrict__ t,
                                                   const float* __restrict__ fc,
                                                   const float* __restrict__ fs) {
  size_t g = ((size_t)blockIdx.x * 256 + threadIdx.x) * 8;
  int d = (int)(g & 127);
  int s = (int)((g >> 12) & 2047);
  bf16x8 v = *reinterpret_cast<bf16x8*>(t + g);
  int i0 = d >> 1;
  float4 c = *reinterpret_cast<const float4*>(fc + (size_t)s * 64 + i0);
  float4 sn = *reinterpret_cast<const float4*>(fs + (size_t)s * 64 + i0);
  float cc[4] = {c.x, c.y, c.z, c.w};
  float ss[4] = {sn.x, sn.y, sn.z, sn.w};
  bf16x8 o;
#pragma unroll
  for (int p = 0; p < 4; ++p) {
    float t0 = b2f(v[2 * p]), t1 = b2f(v[2 * p + 1]);
    o[2 * p] = f2b(t0 * cc[p] - t1 * ss[p]);
    o[2 * p + 1] = f2b(t0 * ss[p] + t1 * cc[p]);
  }
  *reinterpret_cast<bf16x8*>(t + g) = o;
}

// ---------------- small GEMM (m97 structure) for prefix projections ----------------
template <int OM>
__global__ __launch_bounds__(256) void gemm_bt(const short* __restrict__ A,
                                               const short* __restrict__ Bt,
                                               void* __restrict__ Cv,
                                               int M, int N, int K) {
  __shared__ short As[128 * 32];
  __shared__ short Bs[128 * 32];
  const int tid = threadIdx.x;
  const int lane = tid & 63;
  const int wbase = tid & 192;
  const int wr = ((tid >> 7) & 1) * 64;
  const int wc = ((tid >> 6) & 1) * 64;
  const int lr = lane & 15;
  const int lk = (lane >> 4) * 8;
  int lin = blockIdx.y * gridDim.x + blockIdx.x;
  int nwg = gridDim.x * gridDim.y;
  int cpx = nwg >> 3;
  int swz = (lin & 7) * cpx + (lin >> 3);
  const int bm = swz / gridDim.x, bn = swz % gridDim.x;
  f32x4 acc[4][4] = {};
  const short* Ab = A + (size_t)bm * 128 * K;
  const short* Bb = Bt + (size_t)bn * 128 * K;
  for (int kt = 0; kt < K; kt += 32) {
    __syncthreads();
#pragma unroll
    for (int i = 0; i < 2; ++i) {
      int f = i * 256 + tid;
      int row = f >> 2, col = (f & 3) * 8;
      gload16(Ab + (size_t)row * K + kt + col, &As[(i * 256 + wbase) * 8]);
      gload16(Bb + (size_t)row * K + kt + col, &Bs[(i * 256 + wbase) * 8]);
    }
    __syncthreads();
    bf16x8 af[4], bfr[4];
#pragma unroll
    for (int m = 0; m < 4; ++m)
      af[m] = *reinterpret_cast<const bf16x8*>(&As[(wr + m * 16 + lr) * 32 + lk]);
#pragma unroll
    for (int n = 0; n < 4; ++n)
      bfr[n] = *reinterpret_cast<const bf16x8*>(&Bs[(wc + n * 16 + lr) * 32 + lk]);
#pragma unroll
    for (int m = 0; m < 4; ++m)
#pragma unroll
      for (int n = 0; n < 4; ++n)
        acc[m][n] = __builtin_amdgcn_mfma_f32_16x16x32_bf16(af[m], bfr[n], acc[m][n], 0, 0, 0);
  }
  const int row0 = bm * 128 + wr + (lane >> 4) * 4;
  const int col0 = bn * 128 + wc + lr;
#pragma unroll
  for (int m = 0; m < 4; ++m)
#pragma unroll
    for (int n = 0; n < 4; ++n)
#pragma unroll
      for (int j = 0; j < 4; ++j) {
        size_t idx = (size_t)(row0 + m * 16 + j) * N + col0 + n * 16;
        if constexpr (OM == 1) ((short*)Cv)[idx] = f2b(acc[m][n][j]);
        else ((float*)Cv)[idx] = acc[m][n][j];
      }
}

// ---------------- 256x256 8-wave GEMM, 4-phase counted-vmcnt pipeline ----------------
#define PHASE(mh, kh, STAGE, TAIL)                                              \
  {                                                                             \
    bf16x8 af[4], bfr[4];                                                       \
    const int pg = (((kh)*4 + lg) ^ (lr & 7)) * 8;                              \
    _Pragma("unroll") for (int mm = 0; mm < 4; ++mm)                            \
      af[mm] = *(const bf16x8*)&As[slot][(wr + (mh)*64 + mm*16 + lr)*64 + pg];  \
    _Pragma("unroll") for (int nn = 0; nn < 4; ++nn)                            \
      bfr[nn] = *(const bf16x8*)&Bs[slot][(wc + nn*16 + lr)*64 + pg];           \
    STAGE;                                                                      \
    __builtin_amdgcn_s_barrier();                                               \
    asm volatile("s_waitcnt lgkmcnt(0)" ::: "memory");                          \
    __builtin_amdgcn_sched_barrier(0);                                          \
    __builtin_amdgcn_s_setprio(1);                                              \
    _Pragma("unroll") for (int mm = 0; mm < 4; ++mm)                            \
      _Pragma("unroll") for (int nn = 0; nn < 4; ++nn)                          \
        acc[(mh)*4 + mm][nn] = __builtin_amdgcn_mfma_f32_16x16x32_bf16(         \
            af[mm], bfr[nn], acc[(mh)*4 + mm][nn], 0, 0, 0);                    \
    __builtin_amdgcn_s_setprio(0);                                              \
    TAIL;                                                                       \
    __builtin_amdgcn_s_barrier();                                               \
  }

template <int OM>
__global__ __launch_bounds__(512, 2) void gemm256(const short* __restrict__ A,
                                                  const short* __restrict__ Bt,
                                                  void* __restrict__ Cv,
                                                  int M, int N, int K) {
  __shared__ short As[2][256 * 64];
  __shared__ short Bs[2][256 * 64];
  const int tid = threadIdx.x;
  const int w = tid >> 6;
  const int lane = tid & 63;
  const int lr = lane & 15, lg = lane >> 4;
  const int wr = (w >> 2) * 128;
  const int wc = (w & 3) * 64;
  int lin = blockIdx.y * gridDim.x + blockIdx.x;
  int nwg = gridDim.x * gridDim.y;
  int cpx = nwg >> 3;
  int swz = (lin & 7) * cpx + (lin >> 3);
  const int bm = swz / gridDim.x, bn = swz % gridDim.x;

  const short* Ab = A + (size_t)bm * 256 * K;
  const short* Bb = Bt + (size_t)bn * 256 * K;
  const int NT = K >> 6;

  f32x4 acc[8][4] = {};

  auto stA = [&](int slot_, int r0, int kt) {
    int row = r0 + (lane >> 3);
    int gsrc = (lane & 7) ^ ((lane >> 3) & 7);
    gload16(Ab + (size_t)row * K + kt + gsrc * 8, &As[slot_][r0 * 64]);
  };
  auto stB = [&](int slot_, int r0, int kt) {
    int row = r0 + (lane >> 3);
    int gsrc = (lane & 7) ^ ((lane >> 3) & 7);
    gload16(Bb + (size_t)row * K + kt + gsrc * 8, &Bs[slot_][r0 * 64]);
  };

  const int q2 = w * 2, q4 = w * 4;
  const int rt0 = (q2 < 8 ? 0 : 64) + q2 * 8;
  const int rt1 = (q2 + 1 < 8 ? 0 : 64) + (q2 + 1) * 8;

  {
#pragma unroll
    for (int i = 0; i < 4; ++i) stB(0, (q4 + i) * 8, 0);
    stA(0, rt0, 0); stA(0, 64 + rt0, 0);
    stA(0, rt1, 0); stA(0, 64 + rt1, 0);
#pragma unroll
    for (int i = 0; i < 4; ++i) stB(1, (q4 + i) * 8, 64);
    stA(1, rt0, 64); stA(1, 64 + rt0, 64);
    stA(1, rt1, 64); stA(1, 64 + rt1, 64);
  }
  asm volatile("s_waitcnt vmcnt(8)" ::: "memory");
  __builtin_amdgcn_s_barrier();

  for (int t = 0; t < NT; ++t) {
    const int slot = t & 1;
    const int ns = slot ^ 1;
    const int kt1 = (t + 1) << 6, kt2 = (t + 2) << 6;
    const bool s6 = (t >= 1) && (t + 1 < NT);
    const bool s2 = (t + 2 < NT);

    PHASE(0, 0,
          { if (s6) { stB(ns, (q4 + 0) * 8, kt1); stB(ns, (q4 + 1) * 8, kt1); } },
          {});
    PHASE(0, 1,
          { if (s6) { stB(ns, (q4 + 2) * 8, kt1); stB(ns, (q4 + 3) * 8, kt1);
                      stA(ns, 64 + rt0, kt1);     stA(ns, 64 + rt1, kt1); } },
          {});
    PHASE(1, 0,
          { if (s2) stA(slot, rt0, kt2); },
          {});
    PHASE(1, 1,
          { if (s2) stA(slot, rt1, kt2); },
          { if (s2) asm volatile("s_waitcnt vmcnt(2)" ::: "memory");
            else    asm volatile("s_waitcnt vmcnt(0)" ::: "memory"); });
  }

  const int row0 = bm * 256 + wr + lg * 4;
  const int col0 = bn * 256 + wc + lr;
  if constexpr (OM == 2) {
    short* C = (short*)Cv;
#pragma unroll
    for (int mf = 0; mf < 8; ++mf)
#pragma unroll
      for (int n = 0; n < 4; ++n) {
        int r0 = row0 + mf * 16;
        int bb = r0 >> 11, s0 = r0 & 2047;
        short4 pk;
        pk.x = f2b(acc[mf][n][0]); pk.y = f2b(acc[mf][n][1]);
        pk.z = f2b(acc[mf][n][2]); pk.w = f2b(acc[mf][n][3]);
        size_t idx = ((size_t)(bb * 4096 + col0 + n * 16)) * 2048 + s0;
        *reinterpret_cast<short4*>(&C[idx]) = pk;
      }
  } else {
#pragma unroll
    for (int mf = 0; mf < 8; ++mf)
#pragma unroll
      for (int n = 0; n < 4; ++n)
#pragma unroll
        for (int j = 0; j < 4; ++j) {
          size_t idx = (size_t)(row0 + mf * 16 + j) * N + col0 + n * 16;
          if constexpr (OM == 1) ((short*)Cv)[idx] = f2b(acc[mf][n][j]);
          else ((float*)Cv)[idx] = acc[mf][n][j];
        }
  }
}

// ---------------- causal flash attention, 128 q-rows/block, 8 waves x 16 rows ----------------
__global__ __launch_bounds__(512, 4) void attn_kernel(
    const short* __restrict__ qb, const short* __restrict__ kb, const short* __restrict__ vt,
    short* __restrict__ ab) {
  __shared__ short Ks[2][64 * 128];
  __shared__ short Vs[2][128 * 64];
  __shared__ short Ps[8][16 * 64];
  const int tid = threadIdx.x;
  const int wave = tid >> 6, lane = tid & 63;
  const int lr = lane & 15, lg = lane >> 4;
  const int qt = (int)gridDim.x - 1 - (int)blockIdx.x;
  const int bh = blockIdx.y;
  const int b = bh >> 5, h = bh & 31;

  // Q fragments: wave handles rows qt*128 + wave*16 + lr
  bf16x8 aq[4];
  {
    const short* qrow = qb + ((size_t)(b * S_ + qt * 128 + wave * 16 + lr) * H_ + h) * HD_;
#pragma unroll
    for (int kk = 0; kk < 4; ++kk)
      aq[kk] = *reinterpret_cast<const bf16x8*>(qrow + kk * 32 + lg * 8);
  }

  float m = -1e30f, l = 0.f;
  f32x4 o[8] = {};

  const short* kb_bh = kb + ((size_t)b * S_ * H_ + h) * HD_;
  const short* vt_bh = vt + ((size_t)(b * H_ + h)) * HD_ * S_;

  auto stageK = [&](int t, int buf) {
#pragma unroll
    for (int c = 0; c < 2; ++c) {
      int f = c * 512 + tid;
      int row = f >> 4;
      int col = ((f & 15) ^ (row & 7)) * 8;
      gload16(kb_bh + (size_t)(t * 64 + row) * (H_ * HD_) + col,
              &Ks[buf][(c * 512 + (tid & 448)) * 8]);
    }
  };
  auto stageV = [&](int t, int buf) {
#pragma unroll
    for (int c = 0; c < 2; ++c) {
      int f = c * 512 + tid;
      int row = f >> 3;
      int col = ((f & 7) ^ (row & 7)) * 8;
      gload16(vt_bh + (size_t)row * S_ + t * 64 + col,
              &Vs[buf][(c * 512 + (tid & 448)) * 8]);
    }
  };

  auto process = [&](int t, bool diag) {
    const int buf = t & 1;
    f32x4 sc[4] = {};
    __builtin_amdgcn_s_setprio(1);
#pragma unroll
    for (int cb = 0; cb < 4; ++cb) {
      int tok = cb * 16 + lr;
#pragma unroll
      for (int kk = 0; kk < 4; ++kk) {
        int addr = tok * 128 + (((kk * 4 + lg) ^ (tok & 7)) * 8);
        bf16x8 bk = *reinterpret_cast<const bf16x8*>(&Ks[buf][addr]);
        sc[cb] = __builtin_amdgcn_mfma_f32_16x16x32_bf16(bk, aq[kk], sc[cb], 0, 0, 0);
      }
    }
    __builtin_amdgcn_s_setprio(0);
    const float scale = 0.08838834764831845f;
    const int rowg = qt * 128 + wave * 16 + lr;
#pragma unroll
    for (int cb = 0; cb < 4; ++cb)
#pragma unroll
      for (int j = 0; j < 4; ++j) {
        int colg = t * 64 + cb * 16 + lg * 4 + j;
        float v = sc[cb][j] * scale;
        sc[cb][j] = (!diag || colg <= rowg) ? v : -1e30f;
      }
    float mx = sc[0][0];
#pragma unroll
    for (int cb = 0; cb < 4; ++cb)
#pragma unroll
      for (int j = 0; j < 4; ++j) mx = fmaxf(mx, sc[cb][j]);
    mx = fmaxf(mx, __shfl_xor(mx, 16));
    mx = fmaxf(mx, __shfl_xor(mx, 32));
    float mn = fmaxf(m, mx);
    float alpha = __expf(m - mn);
    m = mn;
    float rs = 0.f;
#pragma unroll
    for (int cb = 0; cb < 4; ++cb) {
      short4 pk;
      float p0 = __expf(sc[cb][0] - mn);
      float p1 = __expf(sc[cb][1] - mn);
      float p2 = __expf(sc[cb][2] - mn);
      float p3 = __expf(sc[cb][3] - mn);
      rs += (p0 + p1) + (p2 + p3);
      pk.x = f2b(p0); pk.y = f2b(p1); pk.z = f2b(p2); pk.w = f2b(p3);
      int gran = (cb * 2 + (lg >> 1)) ^ (lr & 7);
      *reinterpret_cast<short4*>(&Ps[wave][lr * 64 + gran * 8 + (lg & 1) * 4]) = pk;
    }
    rs += __shfl_xor(rs, 16);
    rs += __shfl_xor(rs, 32);
    l = l * alpha + rs;
    // rescale o: alpha for q-row lg*4+j lives at lane lg*4+j
    f32x4 av;
#pragma unroll
    for (int j = 0; j < 4; ++j) av[j] = __shfl(alpha, lg * 4 + j);
#pragma unroll
    for (int nb = 0; nb < 8; ++nb)
#pragma unroll
      for (int j = 0; j < 4; ++j) o[nb][j] *= av[j];
    // PV
#pragma unroll
    for (int kk = 0; kk < 2; ++kk) {
      bf16x8 ap = *reinterpret_cast<const bf16x8*>(
          &Ps[wave][lr * 64 + (((kk * 4 + lg) ^ (lr & 7)) * 8)]);
      __builtin_amdgcn_s_setprio(1);
#pragma unroll
      for (int nb = 0; nb < 8; ++nb) {
        int d = nb * 16 + lr;
        bf16x8 bv = *reinterpret_cast<const bf16x8*>(
            &Vs[buf][d * 64 + (((kk * 4 + lg) ^ (lr & 7)) * 8)]);
        o[nb] = __builtin_amdgcn_mfma_f32_16x16x32_bf16(ap, bv, o[nb], 0, 0, 0);
      }
      __builtin_amdgcn_s_setprio(0);
    }
  };

  const int nt = 2 * (qt + 1);
  stageK(0, 0);
  stageV(0, 0);
  __syncthreads();
  for (int t = 0; t < nt; ++t) {
    if (t + 1 < nt) {
      stageK(t + 1, (t + 1) & 1);
      stageV(t + 1, (t + 1) & 1);
    }
    process(t, t >= 2 * qt);
    __syncthreads();
  }

  {
    f32x4 lv;
#pragma unroll
    for (int j = 0; j < 4; ++j) lv[j] = __shfl(l, lg * 4 + j);
#pragma unroll
    for (int j = 0; j < 4; ++j) {
      int q = qt * 128 + wave * 16 + lg * 4 + j;
      float inv = 1.f / lv[j];
      size_t base = ((size_t)(b * S_ + q) * H_ + h) * HD_;
#pragma unroll
      for (int nb = 0; nb < 8; ++nb)
        ab[base + nb * 16 + lr] = f2b(o[nb][j] * inv);
    }
  }
}

// ---------------- gated prefix attention (adds into ab) ----------------
__global__ __launch_bounds__(256) void prefix_kernel(
    const short* __restrict__ qb, const short* __restrict__ pkb, const short* __restrict__ pvb,
    const float* __restrict__ gate, short* __restrict__ ab) {
  __shared__ short pkl[P_ * 128];
  __shared__ short pvl[P_ * 128];
  const int tid = threadIdx.x;
  const int qt = blockIdx.x, bh = blockIdx.y;
  const int b = bh >> 5, h = bh & 31;
  for (int i = tid; i < P_ * 16; i += 256) {
    int row = i >> 4, c = (i & 15) * 8;
    *(bf16x8*)&pkl[row * 128 + c] = *(const bf16x8*)&pkb[(size_t)row * 4096 + h * 128 + c];
    *(bf16x8*)&pvl[row * 128 + c] = *(const bf16x8*)&pvb[(size_t)row * 4096 + h * 128 + c];
  }
  __syncthreads();
  const int r = tid >> 2, p = tid & 3;
  const int q = qt * 64 + r;
  const short* qrow = qb + ((size_t)(b * S_ + q) * H_ + h) * HD_ + p * 32;
  float qv[32];
#pragma unroll
  for (int i = 0; i < 4; ++i) {
    bf16x8 v = *(const bf16x8*)(qrow + i * 8);
#pragma unroll
    for (int e = 0; e < 8; ++e) qv[i * 8 + e] = b2f(v[e]);
  }
  const float scale = 0.08838834764831845f;
  float s[P_];
  float mx = -1e30f;
#pragma unroll
  for (int j = 0; j < P_; ++j) {
    float dot = 0.f;
#pragma unroll
    for (int i = 0; i < 4; ++i) {
      bf16x8 kv = *(const bf16x8*)&pkl[j * 128 + p * 32 + i * 8];
#pragma unroll
      for (int e = 0; e < 8; ++e) dot += qv[i * 8 + e] * b2f(kv[e]);
    }
    dot += __shfl_xor(dot, 1);
    dot += __shfl_xor(dot, 2);
    s[j] = dot * scale;
    mx = fmaxf(mx, s[j]);
  }
  float sum = 0.f;
#pragma unroll
  for (int j = 0; j < P_; ++j) { s[j] = __expf(s[j] - mx); sum += s[j]; }
  float o[32] = {};
#pragma unroll
  for (int j = 0; j < P_; ++j) {
#pragma unroll
    for (int i = 0; i < 4; ++i) {
      bf16x8 vv = *(const bf16x8*)&pvl[j * 128 + p * 32 + i * 8];
#pragma unroll
      for (int e = 0; e < 8; ++e) o[i * 8 + e] += s[j] * b2f(vv[e]);
    }
  }
  float g = tanhf(gate[h]) / sum;
  short* arow = ab + ((size_t)(b * S_ + q) * H_ + h) * HD_ + p * 32;
#pragma unroll
  for (int i = 0; i < 4; ++i) {
    bf16x8 av = *(bf16x8*)(arow + i * 8);
#pragma unroll
    for (int e = 0; e < 8; ++e) av[e] = f2b(b2f(av[e]) + g * o[i * 8 + e]);
    *(bf16x8*)(arow + i * 8) = av;
  }
}

// ---------------- launcher ----------------
extern "C" void kernel_launch(void* const* d_in, const int* in_sizes, int n_in,
                              void* d_out, int out_size, void* d_ws, size_t ws_size,
                              hipStream_t stream) {
  const float* x = (const float*)d_in[0];
  const float* fc = (const float*)d_in[1];
  const float* fs = (const float*)d_in[2];
  const float* prefix = (const float*)d_in[3];
  const float* gate = (const float*)d_in[4];
  const float* wq = (const float*)d_in[5];
  const float* wk = (const float*)d_in[6];
  const float* wv = (const float*)d_in[7];
  const float* wo = (const float*)d_in[8];
  float* out = (float*)d_out;

  char* ws = (char*)d_ws;
  const size_t SZ = (size_t)4096 * 4096 * 2;
  short* xb = (short*)(ws);
  short* wT = (short*)(ws + SZ);
  short* qbuf = (short*)(ws + 2 * SZ);
  short* kbuf = (short*)(ws + 3 * SZ);
  short* vT = (short*)(ws + 4 * SZ);
  short* pb = (short*)(ws + 5 * SZ);
  short* pkb = (short*)(ws + 5 * SZ + (1 << 20));
  short* pvb = (short*)(ws + 5 * SZ + (2 << 20));
  short* abuf = xb;  // alias: x_bf16 dead after V projection

  dim3 tcg(128, 128), tcb(32, 8);
  dim3 gg(16, 16), gp(32, 1);

  convert_f32_bf16<<<16384, 256, 0, stream>>>(x, xb);
  pad_prefix<<<2048, 256, 0, stream>>>(prefix, pb);

  transpose_convert<<<tcg, tcb, 0, stream>>>(wq, wT, 4096, 4096);
  gemm256<1><<<gg, 512, 0, stream>>>(xb, wT, qbuf, 4096, 4096, 4096);

  transpose_convert<<<tcg, tcb, 0, stream>>>(wk, wT, 4096, 4096);
  gemm256<1><<<gg, 512, 0, stream>>>(xb, wT, kbuf, 4096, 4096, 4096);
  gemm_bt<1><<<gp, 256, 0, stream>>>(pb, wT, pkb, 128, 4096, 4096);

  transpose_convert<<<tcg, tcb, 0, stream>>>(wv, wT, 4096, 4096);
  gemm256<2><<<gg, 512, 0, stream>>>(xb, wT, vT, 4096, 4096, 4096);
  gemm_bt<1><<<gp, 256, 0, stream>>>(pb, wT, pvb, 128, 4096, 4096);

  rope_kernel<<<8192, 256, 0, stream>>>(qbuf, fc, fs);
  rope_kernel<<<8192, 256, 0, stream>>>(kbuf, fc, fs);

  attn_kernel<<<dim3(16, 64), 512, 0, stream>>>(qbuf, kbuf, vT, abuf);
  prefix_kernel<<<dim3(32, 64), 256, 0, stream>>>(qbuf, pkb, pvb, gate, abuf);

  transpose_convert<<<tcg, tcb, 0, stream>>>(wo, wT, 4096, 4096);
  gemm256<0><<<gg, 512, 0, stream>>>(abuf, wT, out, 4096, 4096, 4096);
}

// Round 7
// 1105.970 us; speedup vs baseline: 1.7648x; 1.0000x over previous
//
#include <hip/hip_runtime.h>
#include <hip/hip_bf16.h>

#define AS1 __attribute__((address_space(1)))
#define AS3 __attribute__((address_space(3)))

typedef __attribute__((ext_vector_type(8))) short bf16x8;
typedef __attribute__((ext_vector_type(4))) float f32x4;

#define B_ 2
#define S_ 2048
#define D_ 4096
#define H_ 32
#define HD_ 128
#define P_ 30

__device__ __forceinline__ short f2b(float f) {
  union { __hip_bfloat16 h; short s; } u;
  u.h = __float2bfloat16(f);
  return u.s;
}
__device__ __forceinline__ float b2f(short s) {
  union { short s; __hip_bfloat16 h; } u;
  u.s = s;
  return __bfloat162float(u.h);
}
__device__ __forceinline__ void gload16(const void* g, void* l) {
  __builtin_amdgcn_global_load_lds((const AS1 void*)g, (AS3 void*)l, 16, 0, 0);
}

// ---------------- elementwise conversion ----------------
__global__ __launch_bounds__(256) void convert_f32_bf16(const float* __restrict__ in,
                                                        short* __restrict__ out) {
  size_t i = ((size_t)blockIdx.x * 256 + threadIdx.x) * 4;
  float4 v = *reinterpret_cast<const float4*>(in + i);
  short4 o;
  o.x = f2b(v.x); o.y = f2b(v.y); o.z = f2b(v.z); o.w = f2b(v.w);
  *reinterpret_cast<short4*>(out + i) = o;
}

// prefix (30 x 4096 f32) -> padded 128 x 4096 bf16 (zeros beyond row 29)
__global__ __launch_bounds__(256) void pad_prefix(const float* __restrict__ p,
                                                  short* __restrict__ pb) {
  int i = blockIdx.x * 256 + threadIdx.x;
  int row = i >> 12, col = i & 4095;
  pb[i] = (row < P_) ? f2b(p[row * D_ + col]) : (short)0;
}

// W (K x N) f32 -> Wt (N x K) bf16, 32x32 LDS tiles
__global__ void transpose_convert(const float* __restrict__ W, short* __restrict__ Wt,
                                  int K, int N) {
  __shared__ float t[32][33];
  int bx = blockIdx.x, by = blockIdx.y;
  int tx = threadIdx.x, ty = threadIdx.y;
#pragma unroll
  for (int i = 0; i < 4; ++i) {
    int r = ty * 4 + i;
    t[r][tx] = W[(size_t)(by * 32 + r) * N + bx * 32 + tx];
  }
  __syncthreads();
#pragma unroll
  for (int i = 0; i < 4; ++i) {
    int r = ty * 4 + i;
    Wt[(size_t)(bx * 32 + r) * K + by * 32 + tx] = f2b(t[tx][r]);
  }
}

// in-place RoPE on (B,S,H,HD) bf16
__global__ __launch_bounds__(256) void rope_kernel(short* __restrict__ t,
                                                   const float* __restrict__ fc,
                                                   const float* __restrict__ fs) {
  size_t g = ((size_t)blockIdx.x * 256 + threadIdx.x) * 8;
  int d = (int)(g & 127);
  int s = (int)((g >> 12) & 2047);
  bf16x8 v = *reinterpret_cast<bf16x8*>(t + g);
  int i0 = d >> 1;
  float4 c = *reinterpret_cast<const float4*>(fc + (size_t)s * 64 + i0);
  float4 sn = *reinterpret_cast<const float4*>(fs + (size_t)s * 64 + i0);
  float cc[4] = {c.x, c.y, c.z, c.w};
  float ss[4] = {sn.x, sn.y, sn.z, sn.w};
  bf16x8 o;
#pragma unroll
  for (int p = 0; p < 4; ++p) {
    float t0 = b2f(v[2 * p]), t1 = b2f(v[2 * p + 1]);
    o[2 * p] = f2b(t0 * cc[p] - t1 * ss[p]);
    o[2 * p + 1] = f2b(t0 * ss[p] + t1 * cc[p]);
  }
  *reinterpret_cast<bf16x8*>(t + g) = o;
}

// ---------------- small GEMM (m97 structure) for prefix projections ----------------
template <int OM>
__global__ __launch_bounds__(256) void gemm_bt(const short* __restrict__ A,
                                               const short* __restrict__ Bt,
                                               void* __restrict__ Cv,
                                               int M, int N, int K) {
  __shared__ short As[128 * 32];
  __shared__ short Bs[128 * 32];
  const int tid = threadIdx.x;
  const int lane = tid & 63;
  const int wbase = tid & 192;
  const int wr = ((tid >> 7) & 1) * 64;
  const int wc = ((tid >> 6) & 1) * 64;
  const int lr = lane & 15;
  const int lk = (lane >> 4) * 8;
  int lin = blockIdx.y * gridDim.x + blockIdx.x;
  int nwg = gridDim.x * gridDim.y;
  int cpx = nwg >> 3;
  int swz = (lin & 7) * cpx + (lin >> 3);
  const int bm = swz / gridDim.x, bn = swz % gridDim.x;
  f32x4 acc[4][4] = {};
  const short* Ab = A + (size_t)bm * 128 * K;
  const short* Bb = Bt + (size_t)bn * 128 * K;
  for (int kt = 0; kt < K; kt += 32) {
    __syncthreads();
#pragma unroll
    for (int i = 0; i < 2; ++i) {
      int f = i * 256 + tid;
      int row = f >> 2, col = (f & 3) * 8;
      gload16(Ab + (size_t)row * K + kt + col, &As[(i * 256 + wbase) * 8]);
      gload16(Bb + (size_t)row * K + kt + col, &Bs[(i * 256 + wbase) * 8]);
    }
    __syncthreads();
    bf16x8 af[4], bfr[4];
#pragma unroll
    for (int m = 0; m < 4; ++m)
      af[m] = *reinterpret_cast<const bf16x8*>(&As[(wr + m * 16 + lr) * 32 + lk]);
#pragma unroll
    for (int n = 0; n < 4; ++n)
      bfr[n] = *reinterpret_cast<const bf16x8*>(&Bs[(wc + n * 16 + lr) * 32 + lk]);
#pragma unroll
    for (int m = 0; m < 4; ++m)
#pragma unroll
      for (int n = 0; n < 4; ++n)
        acc[m][n] = __builtin_amdgcn_mfma_f32_16x16x32_bf16(af[m], bfr[n], acc[m][n], 0, 0, 0);
  }
  const int row0 = bm * 128 + wr + (lane >> 4) * 4;
  const int col0 = bn * 128 + wc + lr;
#pragma unroll
  for (int m = 0; m < 4; ++m)
#pragma unroll
    for (int n = 0; n < 4; ++n)
#pragma unroll
      for (int j = 0; j < 4; ++j) {
        size_t idx = (size_t)(row0 + m * 16 + j) * N + col0 + n * 16;
        if constexpr (OM == 1) ((short*)Cv)[idx] = f2b(acc[m][n][j]);
        else ((float*)Cv)[idx] = acc[m][n][j];
      }
}

// ---------------- 256x256 8-wave GEMM, 4-phase counted-vmcnt pipeline ----------------
#define PHASE(mh, kh, STAGE, TAIL)                                              \
  {                                                                             \
    bf16x8 af[4], bfr[4];                                                       \
    const int pg = (((kh)*4 + lg) ^ (lr & 7)) * 8;                              \
    _Pragma("unroll") for (int mm = 0; mm < 4; ++mm)                            \
      af[mm] = *(const bf16x8*)&As[slot][(wr + (mh)*64 + mm*16 + lr)*64 + pg];  \
    _Pragma("unroll") for (int nn = 0; nn < 4; ++nn)                            \
      bfr[nn] = *(const bf16x8*)&Bs[slot][(wc + nn*16 + lr)*64 + pg];           \
    STAGE;                                                                      \
    __builtin_amdgcn_s_barrier();                                               \
    asm volatile("s_waitcnt lgkmcnt(0)" ::: "memory");                          \
    __builtin_amdgcn_sched_barrier(0);                                          \
    __builtin_amdgcn_s_setprio(1);                                              \
    _Pragma("unroll") for (int mm = 0; mm < 4; ++mm)                            \
      _Pragma("unroll") for (int nn = 0; nn < 4; ++nn)                          \
        acc[(mh)*4 + mm][nn] = __builtin_amdgcn_mfma_f32_16x16x32_bf16(         \
            af[mm], bfr[nn], acc[(mh)*4 + mm][nn], 0, 0, 0);                    \
    __builtin_amdgcn_s_setprio(0);                                              \
    TAIL;                                                                       \
    __builtin_amdgcn_s_barrier();                                               \
  }

template <int OM>
__global__ __launch_bounds__(512, 2) void gemm256(const short* __restrict__ A,
                                                  const short* __restrict__ Bt,
                                                  void* __restrict__ Cv,
                                                  int M, int N, int K) {
  __shared__ short As[2][256 * 64];
  __shared__ short Bs[2][256 * 64];
  const int tid = threadIdx.x;
  const int w = tid >> 6;
  const int lane = tid & 63;
  const int lr = lane & 15, lg = lane >> 4;
  const int wr = (w >> 2) * 128;
  const int wc = (w & 3) * 64;
  int lin = blockIdx.y * gridDim.x + blockIdx.x;
  int nwg = gridDim.x * gridDim.y;
  int cpx = nwg >> 3;
  int swz = (lin & 7) * cpx + (lin >> 3);
  const int bm = swz / gridDim.x, bn = swz % gridDim.x;

  const short* Ab = A + (size_t)bm * 256 * K;
  const short* Bb = Bt + (size_t)bn * 256 * K;
  const int NT = K >> 6;

  f32x4 acc[8][4] = {};

  auto stA = [&](int slot_, int r0, int kt) {
    int row = r0 + (lane >> 3);
    int gsrc = (lane & 7) ^ ((lane >> 3) & 7);
    gload16(Ab + (size_t)row * K + kt + gsrc * 8, &As[slot_][r0 * 64]);
  };
  auto stB = [&](int slot_, int r0, int kt) {
    int row = r0 + (lane >> 3);
    int gsrc = (lane & 7) ^ ((lane >> 3) & 7);
    gload16(Bb + (size_t)row * K + kt + gsrc * 8, &Bs[slot_][r0 * 64]);
  };

  const int q2 = w * 2, q4 = w * 4;
  const int rt0 = (q2 < 8 ? 0 : 64) + q2 * 8;
  const int rt1 = (q2 + 1 < 8 ? 0 : 64) + (q2 + 1) * 8;

  {
#pragma unroll
    for (int i = 0; i < 4; ++i) stB(0, (q4 + i) * 8, 0);
    stA(0, rt0, 0); stA(0, 64 + rt0, 0);
    stA(0, rt1, 0); stA(0, 64 + rt1, 0);
#pragma unroll
    for (int i = 0; i < 4; ++i) stB(1, (q4 + i) * 8, 64);
    stA(1, rt0, 64); stA(1, 64 + rt0, 64);
    stA(1, rt1, 64); stA(1, 64 + rt1, 64);
  }
  asm volatile("s_waitcnt vmcnt(8)" ::: "memory");
  __builtin_amdgcn_s_barrier();

  for (int t = 0; t < NT; ++t) {
    const int slot = t & 1;
    const int ns = slot ^ 1;
    const int kt1 = (t + 1) << 6, kt2 = (t + 2) << 6;
    const bool s6 = (t >= 1) && (t + 1 < NT);
    const bool s2 = (t + 2 < NT);

    PHASE(0, 0,
          { if (s6) { stB(ns, (q4 + 0) * 8, kt1); stB(ns, (q4 + 1) * 8, kt1); } },
          {});
    PHASE(0, 1,
          { if (s6) { stB(ns, (q4 + 2) * 8, kt1); stB(ns, (q4 + 3) * 8, kt1);
                      stA(ns, 64 + rt0, kt1);     stA(ns, 64 + rt1, kt1); } },
          {});
    PHASE(1, 0,
          { if (s2) stA(slot, rt0, kt2); },
          {});
    PHASE(1, 1,
          { if (s2) stA(slot, rt1, kt2); },
          { if (s2) asm volatile("s_waitcnt vmcnt(2)" ::: "memory");
            else    asm volatile("s_waitcnt vmcnt(0)" ::: "memory"); });
  }

  const int row0 = bm * 256 + wr + lg * 4;
  const int col0 = bn * 256 + wc + lr;
  if constexpr (OM == 2) {
    short* C = (short*)Cv;
#pragma unroll
    for (int mf = 0; mf < 8; ++mf)
#pragma unroll
      for (int n = 0; n < 4; ++n) {
        int r0 = row0 + mf * 16;
        int bb = r0 >> 11, s0 = r0 & 2047;
        short4 pk;
        pk.x = f2b(acc[mf][n][0]); pk.y = f2b(acc[mf][n][1]);
        pk.z = f2b(acc[mf][n][2]); pk.w = f2b(acc[mf][n][3]);
        size_t idx = ((size_t)(bb * 4096 + col0 + n * 16)) * 2048 + s0;
        *reinterpret_cast<short4*>(&C[idx]) = pk;
      }
  } else {
#pragma unroll
    for (int mf = 0; mf < 8; ++mf)
#pragma unroll
      for (int n = 0; n < 4; ++n)
#pragma unroll
        for (int j = 0; j < 4; ++j) {
          size_t idx = (size_t)(row0 + mf * 16 + j) * N + col0 + n * 16;
          if constexpr (OM == 1) ((short*)Cv)[idx] = f2b(acc[mf][n][j]);
          else ((float*)Cv)[idx] = acc[mf][n][j];
        }
  }
}

// ---------------- causal flash attention, 128 q-rows/block, 8 waves x 16 rows ----------------
// K double-buffered (global_load_lds); V single LDS buffer with T14 async reg-staging
// (load V(t+1)->regs at start of tile t, ds_write after post-process barrier).
// LDS = 32K(K) + 16K(V) + 16K(P) = 64 KB -> 2 blocks/CU (16 waves/CU).
__global__ __launch_bounds__(512, 4) void attn_kernel(
    const short* __restrict__ qb, const short* __restrict__ kb, const short* __restrict__ vt,
    short* __restrict__ ab) {
  __shared__ short Ks[2][64 * 128];
  __shared__ short Vs[128 * 64];
  __shared__ short Ps[8][16 * 64];
  const int tid = threadIdx.x;
  const int wave = tid >> 6, lane = tid & 63;
  const int lr = lane & 15, lg = lane >> 4;
  const int qt = (int)gridDim.x - 1 - (int)blockIdx.x;
  const int bh = blockIdx.y;
  const int b = bh >> 5, h = bh & 31;

  bf16x8 aq[4];
  {
    const short* qrow = qb + ((size_t)(b * S_ + qt * 128 + wave * 16 + lr) * H_ + h) * HD_;
#pragma unroll
    for (int kk = 0; kk < 4; ++kk)
      aq[kk] = *reinterpret_cast<const bf16x8*>(qrow + kk * 32 + lg * 8);
  }

  float m = -1e30f, l = 0.f;
  f32x4 o[8] = {};

  const short* kb_bh = kb + ((size_t)b * S_ * H_ + h) * HD_;
  const short* vt_bh = vt + ((size_t)(b * H_ + h)) * HD_ * S_;

  auto stageK = [&](int t, int buf) {
#pragma unroll
    for (int c = 0; c < 2; ++c) {
      int f = c * 512 + tid;
      int row = f >> 4;
      int col = ((f & 15) ^ (row & 7)) * 8;
      gload16(kb_bh + (size_t)(t * 64 + row) * (H_ * HD_) + col,
              &Ks[buf][(c * 512 + (tid & 448)) * 8]);
    }
  };
  // V: load linear global -> regs (async under compute)
  auto loadV = [&](int t, bf16x8 vr[2]) {
#pragma unroll
    for (int c = 0; c < 2; ++c) {
      int f = c * 512 + tid;
      int row = f >> 3;
      vr[c] = *reinterpret_cast<const bf16x8*>(vt_bh + (size_t)row * S_ + t * 64 + (f & 7) * 8);
    }
  };
  // regs -> LDS with write-side XOR swizzle (matches read swizzle involution)
  auto writeV = [&](const bf16x8 vr[2]) {
#pragma unroll
    for (int c = 0; c < 2; ++c) {
      int f = c * 512 + tid;
      int row = f >> 3;
      int gran = (f & 7) ^ (row & 7);
      *reinterpret_cast<bf16x8*>(&Vs[row * 64 + gran * 8]) = vr[c];
    }
  };

  auto process = [&](int t, bool diag) {
    const int buf = t & 1;
    f32x4 sc[4] = {};
    __builtin_amdgcn_s_setprio(1);
#pragma unroll
    for (int cb = 0; cb < 4; ++cb) {
      int tok = cb * 16 + lr;
#pragma unroll
      for (int kk = 0; kk < 4; ++kk) {
        int addr = tok * 128 + (((kk * 4 + lg) ^ (tok & 7)) * 8);
        bf16x8 bk = *reinterpret_cast<const bf16x8*>(&Ks[buf][addr]);
        sc[cb] = __builtin_amdgcn_mfma_f32_16x16x32_bf16(bk, aq[kk], sc[cb], 0, 0, 0);
      }
    }
    __builtin_amdgcn_s_setprio(0);
    const float scale = 0.08838834764831845f;
    const int rowg = qt * 128 + wave * 16 + lr;
#pragma unroll
    for (int cb = 0; cb < 4; ++cb)
#pragma unroll
      for (int j = 0; j < 4; ++j) {
        int colg = t * 64 + cb * 16 + lg * 4 + j;
        float v = sc[cb][j] * scale;
        sc[cb][j] = (!diag || colg <= rowg) ? v : -1e30f;
      }
    float mx = sc[0][0];
#pragma unroll
    for (int cb = 0; cb < 4; ++cb)
#pragma unroll
      for (int j = 0; j < 4; ++j) mx = fmaxf(mx, sc[cb][j]);
    mx = fmaxf(mx, __shfl_xor(mx, 16));
    mx = fmaxf(mx, __shfl_xor(mx, 32));
    float mn = fmaxf(m, mx);
    float alpha = __expf(m - mn);
    m = mn;
    float rs = 0.f;
#pragma unroll
    for (int cb = 0; cb < 4; ++cb) {
      short4 pk;
      float p0 = __expf(sc[cb][0] - mn);
      float p1 = __expf(sc[cb][1] - mn);
      float p2 = __expf(sc[cb][2] - mn);
      float p3 = __expf(sc[cb][3] - mn);
      rs += (p0 + p1) + (p2 + p3);
      pk.x = f2b(p0); pk.y = f2b(p1); pk.z = f2b(p2); pk.w = f2b(p3);
      int gran = (cb * 2 + (lg >> 1)) ^ (lr & 7);
      *reinterpret_cast<short4*>(&Ps[wave][lr * 64 + gran * 8 + (lg & 1) * 4]) = pk;
    }
    rs += __shfl_xor(rs, 16);
    rs += __shfl_xor(rs, 32);
    l = l * alpha + rs;
    f32x4 av;
#pragma unroll
    for (int j = 0; j < 4; ++j) av[j] = __shfl(alpha, lg * 4 + j);
#pragma unroll
    for (int nb = 0; nb < 8; ++nb)
#pragma unroll
      for (int j = 0; j < 4; ++j) o[nb][j] *= av[j];
#pragma unroll
    for (int kk = 0; kk < 2; ++kk) {
      bf16x8 ap = *reinterpret_cast<const bf16x8*>(
          &Ps[wave][lr * 64 + (((kk * 4 + lg) ^ (lr & 7)) * 8)]);
      __builtin_amdgcn_s_setprio(1);
#pragma unroll
      for (int nb = 0; nb < 8; ++nb) {
        int d = nb * 16 + lr;
        bf16x8 bv = *reinterpret_cast<const bf16x8*>(
            &Vs[d * 64 + (((kk * 4 + lg) ^ (lr & 7)) * 8)]);
        o[nb] = __builtin_amdgcn_mfma_f32_16x16x32_bf16(ap, bv, o[nb], 0, 0, 0);
      }
      __builtin_amdgcn_s_setprio(0);
    }
  };

  const int nt = 2 * (qt + 1);
  bf16x8 vr[2];
  stageK(0, 0);
  loadV(0, vr);
  __syncthreads();   // drains K(0) gload_lds; vr ready via dep-wait
  writeV(vr);
  __syncthreads();
  for (int t = 0; t < nt; ++t) {
    const bool more = (t + 1 < nt);
    if (more) {
      loadV(t + 1, vr);             // async: hidden under process(t)
      stageK(t + 1, (t + 1) & 1);   // into other K slot
    }
    process(t, t >= 2 * qt);
    __syncthreads();                 // all waves done reading Vs/Ks; drains t+1 loads
    if (more) writeV(vr);
    __syncthreads();                 // Vs(t+1) visible
  }

  {
    f32x4 lv;
#pragma unroll
    for (int j = 0; j < 4; ++j) lv[j] = __shfl(l, lg * 4 + j);
#pragma unroll
    for (int j = 0; j < 4; ++j) {
      int q = qt * 128 + wave * 16 + lg * 4 + j;
      float inv = 1.f / lv[j];
      size_t base = ((size_t)(b * S_ + q) * H_ + h) * HD_;
#pragma unroll
      for (int nb = 0; nb < 8; ++nb)
        ab[base + nb * 16 + lr] = f2b(o[nb][j] * inv);
    }
  }
}

// ---------------- gated prefix attention (adds into ab) ----------------
__global__ __launch_bounds__(256) void prefix_kernel(
    const short* __restrict__ qb, const short* __restrict__ pkb, const short* __restrict__ pvb,
    const float* __restrict__ gate, short* __restrict__ ab) {
  __shared__ short pkl[P_ * 128];
  __shared__ short pvl[P_ * 128];
  const int tid = threadIdx.x;
  const int qt = blockIdx.x, bh = blockIdx.y;
  const int b = bh >> 5, h = bh & 31;
  for (int i = tid; i < P_ * 16; i += 256) {
    int row = i >> 4, c = (i & 15) * 8;
    *(bf16x8*)&pkl[row * 128 + c] = *(const bf16x8*)&pkb[(size_t)row * 4096 + h * 128 + c];
    *(bf16x8*)&pvl[row * 128 + c] = *(const bf16x8*)&pvb[(size_t)row * 4096 + h * 128 + c];
  }
  __syncthreads();
  const int r = tid >> 2, p = tid & 3;
  const int q = qt * 64 + r;
  const short* qrow = qb + ((size_t)(b * S_ + q) * H_ + h) * HD_ + p * 32;
  float qv[32];
#pragma unroll
  for (int i = 0; i < 4; ++i) {
    bf16x8 v = *(const bf16x8*)(qrow + i * 8);
#pragma unroll
    for (int e = 0; e < 8; ++e) qv[i * 8 + e] = b2f(v[e]);
  }
  const float scale = 0.08838834764831845f;
  float s[P_];
  float mx = -1e30f;
#pragma unroll
  for (int j = 0; j < P_; ++j) {
    float dot = 0.f;
#pragma unroll
    for (int i = 0; i < 4; ++i) {
      bf16x8 kv = *(const bf16x8*)&pkl[j * 128 + p * 32 + i * 8];
#pragma unroll
      for (int e = 0; e < 8; ++e) dot += qv[i * 8 + e] * b2f(kv[e]);
    }
    dot += __shfl_xor(dot, 1);
    dot += __shfl_xor(dot, 2);
    s[j] = dot * scale;
    mx = fmaxf(mx, s[j]);
  }
  float sum = 0.f;
#pragma unroll
  for (int j = 0; j < P_; ++j) { s[j] = __expf(s[j] - mx); sum += s[j]; }
  float o[32] = {};
#pragma unroll
  for (int j = 0; j < P_; ++j) {
#pragma unroll
    for (int i = 0; i < 4; ++i) {
      bf16x8 vv = *(const bf16x8*)&pvl[j * 128 + p * 32 + i * 8];
#pragma unroll
      for (int e = 0; e < 8; ++e) o[i * 8 + e] += s[j] * b2f(vv[e]);
    }
  }
  float g = tanhf(gate[h]) / sum;
  short* arow = ab + ((size_t)(b * S_ + q) * H_ + h) * HD_ + p * 32;
#pragma unroll
  for (int i = 0; i < 4; ++i) {
    bf16x8 av = *(bf16x8*)(arow + i * 8);
#pragma unroll
    for (int e = 0; e < 8; ++e) av[e] = f2b(b2f(av[e]) + g * o[i * 8 + e]);
    *(bf16x8*)(arow + i * 8) = av;
  }
}

// ---------------- launcher ----------------
extern "C" void kernel_launch(void* const* d_in, const int* in_sizes, int n_in,
                              void* d_out, int out_size, void* d_ws, size_t ws_size,
                              hipStream_t stream) {
  const float* x = (const float*)d_in[0];
  const float* fc = (const float*)d_in[1];
  const float* fs = (const float*)d_in[2];
  const float* prefix = (const float*)d_in[3];
  const float* gate = (const float*)d_in[4];
  const float* wq = (const float*)d_in[5];
  const float* wk = (const float*)d_in[6];
  const float* wv = (const float*)d_in[7];
  const float* wo = (const float*)d_in[8];
  float* out = (float*)d_out;

  char* ws = (char*)d_ws;
  const size_t SZ = (size_t)4096 * 4096 * 2;
  short* xb = (short*)(ws);
  short* wT = (short*)(ws + SZ);
  short* qbuf = (short*)(ws + 2 * SZ);
  short* kbuf = (short*)(ws + 3 * SZ);
  short* vT = (short*)(ws + 4 * SZ);
  short* pb = (short*)(ws + 5 * SZ);
  short* pkb = (short*)(ws + 5 * SZ + (1 << 20));
  short* pvb = (short*)(ws + 5 * SZ + (2 << 20));
  short* abuf = xb;  // alias: x_bf16 dead after V projection

  dim3 tcg(128, 128), tcb(32, 8);
  dim3 gg(16, 16), gp(32, 1);

  convert_f32_bf16<<<16384, 256, 0, stream>>>(x, xb);
  pad_prefix<<<2048, 256, 0, stream>>>(prefix, pb);

  transpose_convert<<<tcg, tcb, 0, stream>>>(wq, wT, 4096, 4096);
  gemm256<1><<<gg, 512, 0, stream>>>(xb, wT, qbuf, 4096, 4096, 4096);

  transpose_convert<<<tcg, tcb, 0, stream>>>(wk, wT, 4096, 4096);
  gemm256<1><<<gg, 512, 0, stream>>>(xb, wT, kbuf, 4096, 4096, 4096);
  gemm_bt<1><<<gp, 256, 0, stream>>>(pb, wT, pkb, 128, 4096, 4096);

  transpose_convert<<<tcg, tcb, 0, stream>>>(wv, wT, 4096, 4096);
  gemm256<2><<<gg, 512, 0, stream>>>(xb, wT, vT, 4096, 4096, 4096);
  gemm_bt<1><<<gp, 256, 0, stream>>>(pb, wT, pvb, 128, 4096, 4096);

  rope_kernel<<<8192, 256, 0, stream>>>(qbuf, fc, fs);
  rope_kernel<<<8192, 256, 0, stream>>>(kbuf, fc, fs);

  attn_kernel<<<dim3(16, 64), 512, 0, stream>>>(qbuf, kbuf, vT, abuf);
  prefix_kernel<<<dim3(32, 64), 256, 0, stream>>>(qbuf, pkb, pvb, gate, abuf);

  transpose_convert<<<tcg, tcb, 0, stream>>>(wo, wT, 4096, 4096);
  gemm256<0><<<gg, 512, 0, stream>>>(abuf, wT, out, 4096, 4096, 4096);
}

// Round 8
// 1097.814 us; speedup vs baseline: 1.7779x; 1.0074x over previous
//
#include <hip/hip_runtime.h>
#include <hip/hip_bf16.h>

#define AS1 __attribute__((address_space(1)))
#define AS3 __attribute__((address_space(3)))

typedef __attribute__((ext_vector_type(8))) short bf16x8;
typedef __attribute__((ext_vector_type(4))) float f32x4;

#define B_ 2
#define S_ 2048
#define D_ 4096
#define H_ 32
#define HD_ 128
#define P_ 30

__device__ __forceinline__ short f2b(float f) {
  union { __hip_bfloat16 h; short s; } u;
  u.h = __float2bfloat16(f);
  return u.s;
}
__device__ __forceinline__ float b2f(short s) {
  union { short s; __hip_bfloat16 h; } u;
  u.s = s;
  return __bfloat162float(u.h);
}
__device__ __forceinline__ void gload16(const void* g, void* l) {
  __builtin_amdgcn_global_load_lds((const AS1 void*)g, (AS3 void*)l, 16, 0, 0);
}

// ---------------- elementwise conversion ----------------
__global__ __launch_bounds__(256) void convert_f32_bf16(const float* __restrict__ in,
                                                        short* __restrict__ out) {
  size_t i = ((size_t)blockIdx.x * 256 + threadIdx.x) * 4;
  float4 v = *reinterpret_cast<const float4*>(in + i);
  short4 o;
  o.x = f2b(v.x); o.y = f2b(v.y); o.z = f2b(v.z); o.w = f2b(v.w);
  *reinterpret_cast<short4*>(out + i) = o;
}

// prefix (30 x 4096 f32) -> padded 128 x 4096 bf16 (zeros beyond row 29)
__global__ __launch_bounds__(256) void pad_prefix(const float* __restrict__ p,
                                                  short* __restrict__ pb) {
  int i = blockIdx.x * 256 + threadIdx.x;
  int row = i >> 12, col = i & 4095;
  pb[i] = (row < P_) ? f2b(p[row * D_ + col]) : (short)0;
}

// W (K x N) f32 -> Wt (N x K) bf16, 32x32 LDS tiles
__global__ void transpose_convert(const float* __restrict__ W, short* __restrict__ Wt,
                                  int K, int N) {
  __shared__ float t[32][33];
  int bx = blockIdx.x, by = blockIdx.y;
  int tx = threadIdx.x, ty = threadIdx.y;
#pragma unroll
  for (int i = 0; i < 4; ++i) {
    int r = ty * 4 + i;
    t[r][tx] = W[(size_t)(by * 32 + r) * N + bx * 32 + tx];
  }
  __syncthreads();
#pragma unroll
  for (int i = 0; i < 4; ++i) {
    int r = ty * 4 + i;
    Wt[(size_t)(bx * 32 + r) * K + by * 32 + tx] = f2b(t[tx][r]);
  }
}

// in-place RoPE on (B,S,H,HD) bf16
__global__ __launch_bounds__(256) void rope_kernel(short* __restrict__ t,
                                                   const float* __restrict__ fc,
                                                   const float* __restrict__ fs) {
  size_t g = ((size_t)blockIdx.x * 256 + threadIdx.x) * 8;
  int d = (int)(g & 127);
  int s = (int)((g >> 12) & 2047);
  bf16x8 v = *reinterpret_cast<bf16x8*>(t + g);
  int i0 = d >> 1;
  float4 c = *reinterpret_cast<const float4*>(fc + (size_t)s * 64 + i0);
  float4 sn = *reinterpret_cast<const float4*>(fs + (size_t)s * 64 + i0);
  float cc[4] = {c.x, c.y, c.z, c.w};
  float ss[4] = {sn.x, sn.y, sn.z, sn.w};
  bf16x8 o;
#pragma unroll
  for (int p = 0; p < 4; ++p) {
    float t0 = b2f(v[2 * p]), t1 = b2f(v[2 * p + 1]);
    o[2 * p] = f2b(t0 * cc[p] - t1 * ss[p]);
    o[2 * p + 1] = f2b(t0 * ss[p] + t1 * cc[p]);
  }
  *reinterpret_cast<bf16x8*>(t + g) = o;
}

// ---------------- small GEMM (m97 structure) for prefix projections ----------------
template <int OM>
__global__ __launch_bounds__(256) void gemm_bt(const short* __restrict__ A,
                                               const short* __restrict__ Bt,
                                               void* __restrict__ Cv,
                                               int M, int N, int K) {
  __shared__ short As[128 * 32];
  __shared__ short Bs[128 * 32];
  const int tid = threadIdx.x;
  const int lane = tid & 63;
  const int wbase = tid & 192;
  const int wr = ((tid >> 7) & 1) * 64;
  const int wc = ((tid >> 6) & 1) * 64;
  const int lr = lane & 15;
  const int lk = (lane >> 4) * 8;
  int lin = blockIdx.y * gridDim.x + blockIdx.x;
  int nwg = gridDim.x * gridDim.y;
  int cpx = nwg >> 3;
  int swz = (lin & 7) * cpx + (lin >> 3);
  const int bm = swz / gridDim.x, bn = swz % gridDim.x;
  f32x4 acc[4][4] = {};
  const short* Ab = A + (size_t)bm * 128 * K;
  const short* Bb = Bt + (size_t)bn * 128 * K;
  for (int kt = 0; kt < K; kt += 32) {
    __syncthreads();
#pragma unroll
    for (int i = 0; i < 2; ++i) {
      int f = i * 256 + tid;
      int row = f >> 2, col = (f & 3) * 8;
      gload16(Ab + (size_t)row * K + kt + col, &As[(i * 256 + wbase) * 8]);
      gload16(Bb + (size_t)row * K + kt + col, &Bs[(i * 256 + wbase) * 8]);
    }
    __syncthreads();
    bf16x8 af[4], bfr[4];
#pragma unroll
    for (int m = 0; m < 4; ++m)
      af[m] = *reinterpret_cast<const bf16x8*>(&As[(wr + m * 16 + lr) * 32 + lk]);
#pragma unroll
    for (int n = 0; n < 4; ++n)
      bfr[n] = *reinterpret_cast<const bf16x8*>(&Bs[(wc + n * 16 + lr) * 32 + lk]);
#pragma unroll
    for (int m = 0; m < 4; ++m)
#pragma unroll
      for (int n = 0; n < 4; ++n)
        acc[m][n] = __builtin_amdgcn_mfma_f32_16x16x32_bf16(af[m], bfr[n], acc[m][n], 0, 0, 0);
  }
  const int row0 = bm * 128 + wr + (lane >> 4) * 4;
  const int col0 = bn * 128 + wc + lr;
#pragma unroll
  for (int m = 0; m < 4; ++m)
#pragma unroll
    for (int n = 0; n < 4; ++n)
#pragma unroll
      for (int j = 0; j < 4; ++j) {
        size_t idx = (size_t)(row0 + m * 16 + j) * N + col0 + n * 16;
        if constexpr (OM == 1) ((short*)Cv)[idx] = f2b(acc[m][n][j]);
        else ((float*)Cv)[idx] = acc[m][n][j];
      }
}

// ---------------- 256x256 8-wave GEMM, 4-phase counted-vmcnt pipeline ----------------
#define PHASE(mh, kh, STAGE, TAIL)                                              \
  {                                                                             \
    bf16x8 af[4], bfr[4];                                                       \
    const int pg = (((kh)*4 + lg) ^ (lr & 7)) * 8;                              \
    _Pragma("unroll") for (int mm = 0; mm < 4; ++mm)                            \
      af[mm] = *(const bf16x8*)&As[slot][(wr + (mh)*64 + mm*16 + lr)*64 + pg];  \
    _Pragma("unroll") for (int nn = 0; nn < 4; ++nn)                            \
      bfr[nn] = *(const bf16x8*)&Bs[slot][(wc + nn*16 + lr)*64 + pg];           \
    STAGE;                                                                      \
    __builtin_amdgcn_s_barrier();                                               \
    asm volatile("s_waitcnt lgkmcnt(0)" ::: "memory");                          \
    __builtin_amdgcn_sched_barrier(0);                                          \
    __builtin_amdgcn_s_setprio(1);                                              \
    _Pragma("unroll") for (int mm = 0; mm < 4; ++mm)                            \
      _Pragma("unroll") for (int nn = 0; nn < 4; ++nn)                          \
        acc[(mh)*4 + mm][nn] = __builtin_amdgcn_mfma_f32_16x16x32_bf16(         \
            af[mm], bfr[nn], acc[(mh)*4 + mm][nn], 0, 0, 0);                    \
    __builtin_amdgcn_s_setprio(0);                                              \
    TAIL;                                                                       \
    __builtin_amdgcn_s_barrier();                                               \
  }

template <int OM>
__global__ __launch_bounds__(512, 2) void gemm256(const short* __restrict__ A,
                                                  const short* __restrict__ Bt,
                                                  void* __restrict__ Cv,
                                                  int M, int N, int K) {
  __shared__ short As[2][256 * 64];
  __shared__ short Bs[2][256 * 64];
  const int tid = threadIdx.x;
  const int w = tid >> 6;
  const int lane = tid & 63;
  const int lr = lane & 15, lg = lane >> 4;
  const int wr = (w >> 2) * 128;
  const int wc = (w & 3) * 64;
  int lin = blockIdx.y * gridDim.x + blockIdx.x;
  int nwg = gridDim.x * gridDim.y;
  int cpx = nwg >> 3;
  int swz = (lin & 7) * cpx + (lin >> 3);
  const int bm = swz / gridDim.x, bn = swz % gridDim.x;

  const short* Ab = A + (size_t)bm * 256 * K;
  const short* Bb = Bt + (size_t)bn * 256 * K;
  const int NT = K >> 6;

  f32x4 acc[8][4] = {};

  auto stA = [&](int slot_, int r0, int kt) {
    int row = r0 + (lane >> 3);
    int gsrc = (lane & 7) ^ ((lane >> 3) & 7);
    gload16(Ab + (size_t)row * K + kt + gsrc * 8, &As[slot_][r0 * 64]);
  };
  auto stB = [&](int slot_, int r0, int kt) {
    int row = r0 + (lane >> 3);
    int gsrc = (lane & 7) ^ ((lane >> 3) & 7);
    gload16(Bb + (size_t)row * K + kt + gsrc * 8, &Bs[slot_][r0 * 64]);
  };

  const int q2 = w * 2, q4 = w * 4;
  const int rt0 = (q2 < 8 ? 0 : 64) + q2 * 8;
  const int rt1 = (q2 + 1 < 8 ? 0 : 64) + (q2 + 1) * 8;

  {
#pragma unroll
    for (int i = 0; i < 4; ++i) stB(0, (q4 + i) * 8, 0);
    stA(0, rt0, 0); stA(0, 64 + rt0, 0);
    stA(0, rt1, 0); stA(0, 64 + rt1, 0);
#pragma unroll
    for (int i = 0; i < 4; ++i) stB(1, (q4 + i) * 8, 64);
    stA(1, rt0, 64); stA(1, 64 + rt0, 64);
    stA(1, rt1, 64); stA(1, 64 + rt1, 64);
  }
  asm volatile("s_waitcnt vmcnt(8)" ::: "memory");
  __builtin_amdgcn_s_barrier();

  for (int t = 0; t < NT; ++t) {
    const int slot = t & 1;
    const int ns = slot ^ 1;
    const int kt1 = (t + 1) << 6, kt2 = (t + 2) << 6;
    const bool s6 = (t >= 1) && (t + 1 < NT);
    const bool s2 = (t + 2 < NT);

    PHASE(0, 0,
          { if (s6) { stB(ns, (q4 + 0) * 8, kt1); stB(ns, (q4 + 1) * 8, kt1); } },
          {});
    PHASE(0, 1,
          { if (s6) { stB(ns, (q4 + 2) * 8, kt1); stB(ns, (q4 + 3) * 8, kt1);
                      stA(ns, 64 + rt0, kt1);     stA(ns, 64 + rt1, kt1); } },
          {});
    PHASE(1, 0,
          { if (s2) stA(slot, rt0, kt2); },
          {});
    PHASE(1, 1,
          { if (s2) stA(slot, rt1, kt2); },
          { if (s2) asm volatile("s_waitcnt vmcnt(2)" ::: "memory");
            else    asm volatile("s_waitcnt vmcnt(0)" ::: "memory"); });
  }

  const int row0 = bm * 256 + wr + lg * 4;
  const int col0 = bn * 256 + wc + lr;
  if constexpr (OM == 2) {
    short* C = (short*)Cv;
#pragma unroll
    for (int mf = 0; mf < 8; ++mf)
#pragma unroll
      for (int n = 0; n < 4; ++n) {
        int r0 = row0 + mf * 16;
        int bb = r0 >> 11, s0 = r0 & 2047;
        short4 pk;
        pk.x = f2b(acc[mf][n][0]); pk.y = f2b(acc[mf][n][1]);
        pk.z = f2b(acc[mf][n][2]); pk.w = f2b(acc[mf][n][3]);
        size_t idx = ((size_t)(bb * 4096 + col0 + n * 16)) * 2048 + s0;
        *reinterpret_cast<short4*>(&C[idx]) = pk;
      }
  } else {
#pragma unroll
    for (int mf = 0; mf < 8; ++mf)
#pragma unroll
      for (int n = 0; n < 4; ++n)
#pragma unroll
        for (int j = 0; j < 4; ++j) {
          size_t idx = (size_t)(row0 + mf * 16 + j) * N + col0 + n * 16;
          if constexpr (OM == 1) ((short*)Cv)[idx] = f2b(acc[mf][n][j]);
          else ((float*)Cv)[idx] = acc[mf][n][j];
        }
  }
}

// ---------------- causal flash attention, 256 q-rows/block, 16 waves x 16 rows ----------------
// 1024-thread blocks: with HW pinning this kernel at ~1 block/CU, block size sets
// waves/CU. K double-buffered (global_load_lds); V single buffer, T14 reg-staged.
// LDS = 32K(K) + 16K(V) + 32K(Ps) = 80 KB.
__global__ __launch_bounds__(1024, 4) void attn_kernel(
    const short* __restrict__ qb, const short* __restrict__ kb, const short* __restrict__ vt,
    short* __restrict__ ab) {
  __shared__ short Ks[2][64 * 128];
  __shared__ short Vs[128 * 64];
  __shared__ short Ps[16][16 * 64];
  const int tid = threadIdx.x;
  const int wave = tid >> 6, lane = tid & 63;
  const int lr = lane & 15, lg = lane >> 4;
  const int qt = (int)gridDim.x - 1 - (int)blockIdx.x;  // heavy blocks first
  const int bh = blockIdx.y;
  const int b = bh >> 5, h = bh & 31;

  bf16x8 aq[4];
  {
    const short* qrow = qb + ((size_t)(b * S_ + qt * 256 + wave * 16 + lr) * H_ + h) * HD_;
#pragma unroll
    for (int kk = 0; kk < 4; ++kk)
      aq[kk] = *reinterpret_cast<const bf16x8*>(qrow + kk * 32 + lg * 8);
  }

  float m = -1e30f, l = 0.f;
  f32x4 o[8] = {};

  const short* kb_bh = kb + ((size_t)b * S_ * H_ + h) * HD_;
  const short* vt_bh = vt + ((size_t)(b * H_ + h)) * HD_ * S_;

  auto stageK = [&](int t, int buf) {
    int row = tid >> 4;                       // tok 0..63
    int col = ((tid & 15) ^ (row & 7)) * 8;   // inverse-swizzled source granule
    gload16(kb_bh + (size_t)(t * 64 + row) * (H_ * HD_) + col,
            &Ks[buf][(tid & 960) * 8]);
  };
  auto loadV = [&](int t, bf16x8& vr) {
    int row = tid >> 3;                       // d 0..127
    vr = *reinterpret_cast<const bf16x8*>(vt_bh + (size_t)row * S_ + t * 64 + (tid & 7) * 8);
  };
  auto writeV = [&](const bf16x8& vr) {
    int row = tid >> 3;
    int gran = (tid & 7) ^ (row & 7);
    *reinterpret_cast<bf16x8*>(&Vs[row * 64 + gran * 8]) = vr;
  };

  auto process = [&](int t, bool diag) {
    const int buf = t & 1;
    f32x4 sc[4] = {};
    __builtin_amdgcn_s_setprio(1);
#pragma unroll
    for (int cb = 0; cb < 4; ++cb) {
      int tok = cb * 16 + lr;
#pragma unroll
      for (int kk = 0; kk < 4; ++kk) {
        int addr = tok * 128 + (((kk * 4 + lg) ^ (tok & 7)) * 8);
        bf16x8 bk = *reinterpret_cast<const bf16x8*>(&Ks[buf][addr]);
        sc[cb] = __builtin_amdgcn_mfma_f32_16x16x32_bf16(bk, aq[kk], sc[cb], 0, 0, 0);
      }
    }
    __builtin_amdgcn_s_setprio(0);
    const float scale = 0.08838834764831845f;
    const int rowg = qt * 256 + wave * 16 + lr;
#pragma unroll
    for (int cb = 0; cb < 4; ++cb)
#pragma unroll
      for (int j = 0; j < 4; ++j) {
        int colg = t * 64 + cb * 16 + lg * 4 + j;
        float v = sc[cb][j] * scale;
        sc[cb][j] = (!diag || colg <= rowg) ? v : -1e30f;
      }
    float mx = sc[0][0];
#pragma unroll
    for (int cb = 0; cb < 4; ++cb)
#pragma unroll
      for (int j = 0; j < 4; ++j) mx = fmaxf(mx, sc[cb][j]);
    mx = fmaxf(mx, __shfl_xor(mx, 16));
    mx = fmaxf(mx, __shfl_xor(mx, 32));
    float mn = fmaxf(m, mx);
    float alpha = __expf(m - mn);
    m = mn;
    float rs = 0.f;
#pragma unroll
    for (int cb = 0; cb < 4; ++cb) {
      short4 pk;
      float p0 = __expf(sc[cb][0] - mn);
      float p1 = __expf(sc[cb][1] - mn);
      float p2 = __expf(sc[cb][2] - mn);
      float p3 = __expf(sc[cb][3] - mn);
      rs += (p0 + p1) + (p2 + p3);
      pk.x = f2b(p0); pk.y = f2b(p1); pk.z = f2b(p2); pk.w = f2b(p3);
      int gran = (cb * 2 + (lg >> 1)) ^ (lr & 7);
      *reinterpret_cast<short4*>(&Ps[wave][lr * 64 + gran * 8 + (lg & 1) * 4]) = pk;
    }
    rs += __shfl_xor(rs, 16);
    rs += __shfl_xor(rs, 32);
    l = l * alpha + rs;
    f32x4 av;
#pragma unroll
    for (int j = 0; j < 4; ++j) av[j] = __shfl(alpha, lg * 4 + j);
#pragma unroll
    for (int nb = 0; nb < 8; ++nb)
#pragma unroll
      for (int j = 0; j < 4; ++j) o[nb][j] *= av[j];
#pragma unroll
    for (int kk = 0; kk < 2; ++kk) {
      bf16x8 ap = *reinterpret_cast<const bf16x8*>(
          &Ps[wave][lr * 64 + (((kk * 4 + lg) ^ (lr & 7)) * 8)]);
      __builtin_amdgcn_s_setprio(1);
#pragma unroll
      for (int nb = 0; nb < 8; ++nb) {
        int d = nb * 16 + lr;
        bf16x8 bv = *reinterpret_cast<const bf16x8*>(
            &Vs[d * 64 + (((kk * 4 + lg) ^ (lr & 7)) * 8)]);
        o[nb] = __builtin_amdgcn_mfma_f32_16x16x32_bf16(ap, bv, o[nb], 0, 0, 0);
      }
      __builtin_amdgcn_s_setprio(0);
    }
  };

  const int nt = 4 * (qt + 1);
  bf16x8 vr;
  stageK(0, 0);
  loadV(0, vr);
  __syncthreads();
  writeV(vr);
  __syncthreads();
  for (int t = 0; t < nt; ++t) {
    const bool more = (t + 1 < nt);
    if (more) {
      loadV(t + 1, vr);
      stageK(t + 1, (t + 1) & 1);
    }
    process(t, t >= 4 * qt);
    __syncthreads();
    if (more) writeV(vr);
    __syncthreads();
  }

  {
    f32x4 lv;
#pragma unroll
    for (int j = 0; j < 4; ++j) lv[j] = __shfl(l, lg * 4 + j);
#pragma unroll
    for (int j = 0; j < 4; ++j) {
      int q = qt * 256 + wave * 16 + lg * 4 + j;
      float inv = 1.f / lv[j];
      size_t base = ((size_t)(b * S_ + q) * H_ + h) * HD_;
#pragma unroll
      for (int nb = 0; nb < 8; ++nb)
        ab[base + nb * 16 + lr] = f2b(o[nb][j] * inv);
    }
  }
}

// ---------------- gated prefix attention (adds into ab) ----------------
__global__ __launch_bounds__(256) void prefix_kernel(
    const short* __restrict__ qb, const short* __restrict__ pkb, const short* __restrict__ pvb,
    const float* __restrict__ gate, short* __restrict__ ab) {
  __shared__ short pkl[P_ * 128];
  __shared__ short pvl[P_ * 128];
  const int tid = threadIdx.x;
  const int qt = blockIdx.x, bh = blockIdx.y;
  const int b = bh >> 5, h = bh & 31;
  for (int i = tid; i < P_ * 16; i += 256) {
    int row = i >> 4, c = (i & 15) * 8;
    *(bf16x8*)&pkl[row * 128 + c] = *(const bf16x8*)&pkb[(size_t)row * 4096 + h * 128 + c];
    *(bf16x8*)&pvl[row * 128 + c] = *(const bf16x8*)&pvb[(size_t)row * 4096 + h * 128 + c];
  }
  __syncthreads();
  const int r = tid >> 2, p = tid & 3;
  const int q = qt * 64 + r;
  const short* qrow = qb + ((size_t)(b * S_ + q) * H_ + h) * HD_ + p * 32;
  float qv[32];
#pragma unroll
  for (int i = 0; i < 4; ++i) {
    bf16x8 v = *(const bf16x8*)(qrow + i * 8);
#pragma unroll
    for (int e = 0; e < 8; ++e) qv[i * 8 + e] = b2f(v[e]);
  }
  const float scale = 0.08838834764831845f;
  float s[P_];
  float mx = -1e30f;
#pragma unroll
  for (int j = 0; j < P_; ++j) {
    float dot = 0.f;
#pragma unroll
    for (int i = 0; i < 4; ++i) {
      bf16x8 kv = *(const bf16x8*)&pkl[j * 128 + p * 32 + i * 8];
#pragma unroll
      for (int e = 0; e < 8; ++e) dot += qv[i * 8 + e] * b2f(kv[e]);
    }
    dot += __shfl_xor(dot, 1);
    dot += __shfl_xor(dot, 2);
    s[j] = dot * scale;
    mx = fmaxf(mx, s[j]);
  }
  float sum = 0.f;
#pragma unroll
  for (int j = 0; j < P_; ++j) { s[j] = __expf(s[j] - mx); sum += s[j]; }
  float o[32] = {};
#pragma unroll
  for (int j = 0; j < P_; ++j) {
#pragma unroll
    for (int i = 0; i < 4; ++i) {
      bf16x8 vv = *(const bf16x8*)&pvl[j * 128 + p * 32 + i * 8];
#pragma unroll
      for (int e = 0; e < 8; ++e) o[i * 8 + e] += s[j] * b2f(vv[e]);
    }
  }
  float g = tanhf(gate[h]) / sum;
  short* arow = ab + ((size_t)(b * S_ + q) * H_ + h) * HD_ + p * 32;
#pragma unroll
  for (int i = 0; i < 4; ++i) {
    bf16x8 av = *(bf16x8*)(arow + i * 8);
#pragma unroll
    for (int e = 0; e < 8; ++e) av[e] = f2b(b2f(av[e]) + g * o[i * 8 + e]);
    *(bf16x8*)(arow + i * 8) = av;
  }
}

// ---------------- launcher ----------------
extern "C" void kernel_launch(void* const* d_in, const int* in_sizes, int n_in,
                              void* d_out, int out_size, void* d_ws, size_t ws_size,
                              hipStream_t stream) {
  const float* x = (const float*)d_in[0];
  const float* fc = (const float*)d_in[1];
  const float* fs = (const float*)d_in[2];
  const float* prefix = (const float*)d_in[3];
  const float* gate = (const float*)d_in[4];
  const float* wq = (const float*)d_in[5];
  const float* wk = (const float*)d_in[6];
  const float* wv = (const float*)d_in[7];
  const float* wo = (const float*)d_in[8];
  float* out = (float*)d_out;

  char* ws = (char*)d_ws;
  const size_t SZ = (size_t)4096 * 4096 * 2;
  short* xb = (short*)(ws);
  short* wT = (short*)(ws + SZ);
  short* qbuf = (short*)(ws + 2 * SZ);
  short* kbuf = (short*)(ws + 3 * SZ);
  short* vT = (short*)(ws + 4 * SZ);
  short* pb = (short*)(ws + 5 * SZ);
  short* pkb = (short*)(ws + 5 * SZ + (1 << 20));
  short* pvb = (short*)(ws + 5 * SZ + (2 << 20));
  short* abuf = xb;  // alias: x_bf16 dead after V projection

  dim3 tcg(128, 128), tcb(32, 8);
  dim3 gg(16, 16), gp(32, 1);

  convert_f32_bf16<<<16384, 256, 0, stream>>>(x, xb);
  pad_prefix<<<2048, 256, 0, stream>>>(prefix, pb);

  transpose_convert<<<tcg, tcb, 0, stream>>>(wq, wT, 4096, 4096);
  gemm256<1><<<gg, 512, 0, stream>>>(xb, wT, qbuf, 4096, 4096, 4096);

  transpose_convert<<<tcg, tcb, 0, stream>>>(wk, wT, 4096, 4096);
  gemm256<1><<<gg, 512, 0, stream>>>(xb, wT, kbuf, 4096, 4096, 4096);
  gemm_bt<1><<<gp, 256, 0, stream>>>(pb, wT, pkb, 128, 4096, 4096);

  transpose_convert<<<tcg, tcb, 0, stream>>>(wv, wT, 4096, 4096);
  gemm256<2><<<gg, 512, 0, stream>>>(xb, wT, vT, 4096, 4096, 4096);
  gemm_bt<1><<<gp, 256, 0, stream>>>(pb, wT, pvb, 128, 4096, 4096);

  rope_kernel<<<8192, 256, 0, stream>>>(qbuf, fc, fs);
  rope_kernel<<<8192, 256, 0, stream>>>(kbuf, fc, fs);

  attn_kernel<<<dim3(8, 64), 1024, 0, stream>>>(qbuf, kbuf, vT, abuf);
  prefix_kernel<<<dim3(32, 64), 256, 0, stream>>>(qbuf, pkb, pvb, gate, abuf);

  transpose_convert<<<tcg, tcb, 0, stream>>>(wo, wT, 4096, 4096);
  gemm256<0><<<gg, 512, 0, stream>>>(abuf, wT, out, 4096, 4096, 4096);
}

// Round 9
// 1020.178 us; speedup vs baseline: 1.9132x; 1.0761x over previous
//
#include <hip/hip_runtime.h>
#include <hip/hip_bf16.h>

#define AS1 __attribute__((address_space(1)))
#define AS3 __attribute__((address_space(3)))

typedef __attribute__((ext_vector_type(8))) short bf16x8;
typedef __attribute__((ext_vector_type(4))) float f32x4;

#define B_ 2
#define S_ 2048
#define D_ 4096
#define H_ 32
#define HD_ 128
#define P_ 30

__device__ __forceinline__ short f2b(float f) {
  union { __hip_bfloat16 h; short s; } u;
  u.h = __float2bfloat16(f);
  return u.s;
}
__device__ __forceinline__ float b2f(short s) {
  union { short s; __hip_bfloat16 h; } u;
  u.s = s;
  return __bfloat162float(u.h);
}
__device__ __forceinline__ void gload16(const void* g, void* l) {
  __builtin_amdgcn_global_load_lds((const AS1 void*)g, (AS3 void*)l, 16, 0, 0);
}

// ---------------- elementwise conversion ----------------
__global__ __launch_bounds__(256) void convert_f32_bf16(const float* __restrict__ in,
                                                        short* __restrict__ out) {
  size_t i = ((size_t)blockIdx.x * 256 + threadIdx.x) * 4;
  float4 v = *reinterpret_cast<const float4*>(in + i);
  short4 o;
  o.x = f2b(v.x); o.y = f2b(v.y); o.z = f2b(v.z); o.w = f2b(v.w);
  *reinterpret_cast<short4*>(out + i) = o;
}

// prefix (30 x 4096 f32) -> padded 128 x 4096 bf16 (zeros beyond row 29)
__global__ __launch_bounds__(256) void pad_prefix(const float* __restrict__ p,
                                                  short* __restrict__ pb) {
  int i = blockIdx.x * 256 + threadIdx.x;
  int row = i >> 12, col = i & 4095;
  pb[i] = (row < P_) ? f2b(p[row * D_ + col]) : (short)0;
}

// W (K x N) f32 -> Wt (N x K) bf16, 32x32 LDS tiles
__global__ void transpose_convert(const float* __restrict__ W, short* __restrict__ Wt,
                                  int K, int N) {
  __shared__ float t[32][33];
  int bx = blockIdx.x, by = blockIdx.y;
  int tx = threadIdx.x, ty = threadIdx.y;
#pragma unroll
  for (int i = 0; i < 4; ++i) {
    int r = ty * 4 + i;
    t[r][tx] = W[(size_t)(by * 32 + r) * N + bx * 32 + tx];
  }
  __syncthreads();
#pragma unroll
  for (int i = 0; i < 4; ++i) {
    int r = ty * 4 + i;
    Wt[(size_t)(bx * 32 + r) * K + by * 32 + tx] = f2b(t[tx][r]);
  }
}

// in-place RoPE on (B,S,H,HD) bf16
__global__ __launch_bounds__(256) void rope_kernel(short* __restrict__ t,
                                                   const float* __restrict__ fc,
                                                   const float* __restrict__ fs) {
  size_t g = ((size_t)blockIdx.x * 256 + threadIdx.x) * 8;
  int d = (int)(g & 127);
  int s = (int)((g >> 12) & 2047);
  bf16x8 v = *reinterpret_cast<bf16x8*>(t + g);
  int i0 = d >> 1;
  float4 c = *reinterpret_cast<const float4*>(fc + (size_t)s * 64 + i0);
  float4 sn = *reinterpret_cast<const float4*>(fs + (size_t)s * 64 + i0);
  float cc[4] = {c.x, c.y, c.z, c.w};
  float ss[4] = {sn.x, sn.y, sn.z, sn.w};
  bf16x8 o;
#pragma unroll
  for (int p = 0; p < 4; ++p) {
    float t0 = b2f(v[2 * p]), t1 = b2f(v[2 * p + 1]);
    o[2 * p] = f2b(t0 * cc[p] - t1 * ss[p]);
    o[2 * p + 1] = f2b(t0 * ss[p] + t1 * cc[p]);
  }
  *reinterpret_cast<bf16x8*>(t + g) = o;
}

// ---------------- small GEMM (m97 structure) for prefix projections ----------------
template <int OM>
__global__ __launch_bounds__(256) void gemm_bt(const short* __restrict__ A,
                                               const short* __restrict__ Bt,
                                               void* __restrict__ Cv,
                                               int M, int N, int K) {
  __shared__ short As[128 * 32];
  __shared__ short Bs[128 * 32];
  const int tid = threadIdx.x;
  const int lane = tid & 63;
  const int wbase = tid & 192;
  const int wr = ((tid >> 7) & 1) * 64;
  const int wc = ((tid >> 6) & 1) * 64;
  const int lr = lane & 15;
  const int lk = (lane >> 4) * 8;
  int lin = blockIdx.y * gridDim.x + blockIdx.x;
  int nwg = gridDim.x * gridDim.y;
  int cpx = nwg >> 3;
  int swz = (lin & 7) * cpx + (lin >> 3);
  const int bm = swz / gridDim.x, bn = swz % gridDim.x;
  f32x4 acc[4][4] = {};
  const short* Ab = A + (size_t)bm * 128 * K;
  const short* Bb = Bt + (size_t)bn * 128 * K;
  for (int kt = 0; kt < K; kt += 32) {
    __syncthreads();
#pragma unroll
    for (int i = 0; i < 2; ++i) {
      int f = i * 256 + tid;
      int row = f >> 2, col = (f & 3) * 8;
      gload16(Ab + (size_t)row * K + kt + col, &As[(i * 256 + wbase) * 8]);
      gload16(Bb + (size_t)row * K + kt + col, &Bs[(i * 256 + wbase) * 8]);
    }
    __syncthreads();
    bf16x8 af[4], bfr[4];
#pragma unroll
    for (int m = 0; m < 4; ++m)
      af[m] = *reinterpret_cast<const bf16x8*>(&As[(wr + m * 16 + lr) * 32 + lk]);
#pragma unroll
    for (int n = 0; n < 4; ++n)
      bfr[n] = *reinterpret_cast<const bf16x8*>(&Bs[(wc + n * 16 + lr) * 32 + lk]);
#pragma unroll
    for (int m = 0; m < 4; ++m)
#pragma unroll
      for (int n = 0; n < 4; ++n)
        acc[m][n] = __builtin_amdgcn_mfma_f32_16x16x32_bf16(af[m], bfr[n], acc[m][n], 0, 0, 0);
  }
  const int row0 = bm * 128 + wr + (lane >> 4) * 4;
  const int col0 = bn * 128 + wc + lr;
#pragma unroll
  for (int m = 0; m < 4; ++m)
#pragma unroll
    for (int n = 0; n < 4; ++n)
#pragma unroll
      for (int j = 0; j < 4; ++j) {
        size_t idx = (size_t)(row0 + m * 16 + j) * N + col0 + n * 16;
        if constexpr (OM == 1) ((short*)Cv)[idx] = f2b(acc[m][n][j]);
        else ((float*)Cv)[idx] = acc[m][n][j];
      }
}

// ---------------- 256x256 8-wave GEMM, 4-phase counted-vmcnt pipeline ----------------
#define PHASE(mh, kh, STAGE, TAIL)                                              \
  {                                                                             \
    bf16x8 af[4], bfr[4];                                                       \
    const int pg = (((kh)*4 + lg) ^ (lr & 7)) * 8;                              \
    _Pragma("unroll") for (int mm = 0; mm < 4; ++mm)                            \
      af[mm] = *(const bf16x8*)&As[slot][(wr + (mh)*64 + mm*16 + lr)*64 + pg];  \
    _Pragma("unroll") for (int nn = 0; nn < 4; ++nn)                            \
      bfr[nn] = *(const bf16x8*)&Bs[slot][(wc + nn*16 + lr)*64 + pg];           \
    STAGE;                                                                      \
    __builtin_amdgcn_s_barrier();                                               \
    asm volatile("s_waitcnt lgkmcnt(0)" ::: "memory");                          \
    __builtin_amdgcn_sched_barrier(0);                                          \
    __builtin_amdgcn_s_setprio(1);                                              \
    _Pragma("unroll") for (int mm = 0; mm < 4; ++mm)                            \
      _Pragma("unroll") for (int nn = 0; nn < 4; ++nn)                          \
        acc[(mh)*4 + mm][nn] = __builtin_amdgcn_mfma_f32_16x16x32_bf16(         \
            af[mm], bfr[nn], acc[(mh)*4 + mm][nn], 0, 0, 0);                    \
    __builtin_amdgcn_s_setprio(0);                                              \
    TAIL;                                                                       \
    __builtin_amdgcn_s_barrier();                                               \
  }

template <int OM>
__global__ __launch_bounds__(512, 2) void gemm256(const short* __restrict__ A,
                                                  const short* __restrict__ Bt,
                                                  void* __restrict__ Cv,
                                                  int M, int N, int K) {
  __shared__ short As[2][256 * 64];
  __shared__ short Bs[2][256 * 64];
  const int tid = threadIdx.x;
  const int w = tid >> 6;
  const int lane = tid & 63;
  const int lr = lane & 15, lg = lane >> 4;
  const int wr = (w >> 2) * 128;
  const int wc = (w & 3) * 64;
  int lin = blockIdx.y * gridDim.x + blockIdx.x;
  int nwg = gridDim.x * gridDim.y;
  int cpx = nwg >> 3;
  int swz = (lin & 7) * cpx + (lin >> 3);
  const int bm = swz / gridDim.x, bn = swz % gridDim.x;

  const short* Ab = A + (size_t)bm * 256 * K;
  const short* Bb = Bt + (size_t)bn * 256 * K;
  const int NT = K >> 6;

  f32x4 acc[8][4] = {};

  auto stA = [&](int slot_, int r0, int kt) {
    int row = r0 + (lane >> 3);
    int gsrc = (lane & 7) ^ ((lane >> 3) & 7);
    gload16(Ab + (size_t)row * K + kt + gsrc * 8, &As[slot_][r0 * 64]);
  };
  auto stB = [&](int slot_, int r0, int kt) {
    int row = r0 + (lane >> 3);
    int gsrc = (lane & 7) ^ ((lane >> 3) & 7);
    gload16(Bb + (size_t)row * K + kt + gsrc * 8, &Bs[slot_][r0 * 64]);
  };

  const int q2 = w * 2, q4 = w * 4;
  const int rt0 = (q2 < 8 ? 0 : 64) + q2 * 8;
  const int rt1 = (q2 + 1 < 8 ? 0 : 64) + (q2 + 1) * 8;

  {
#pragma unroll
    for (int i = 0; i < 4; ++i) stB(0, (q4 + i) * 8, 0);
    stA(0, rt0, 0); stA(0, 64 + rt0, 0);
    stA(0, rt1, 0); stA(0, 64 + rt1, 0);
#pragma unroll
    for (int i = 0; i < 4; ++i) stB(1, (q4 + i) * 8, 64);
    stA(1, rt0, 64); stA(1, 64 + rt0, 64);
    stA(1, rt1, 64); stA(1, 64 + rt1, 64);
  }
  asm volatile("s_waitcnt vmcnt(8)" ::: "memory");
  __builtin_amdgcn_s_barrier();

  for (int t = 0; t < NT; ++t) {
    const int slot = t & 1;
    const int ns = slot ^ 1;
    const int kt1 = (t + 1) << 6, kt2 = (t + 2) << 6;
    const bool s6 = (t >= 1) && (t + 1 < NT);
    const bool s2 = (t + 2 < NT);

    PHASE(0, 0,
          { if (s6) { stB(ns, (q4 + 0) * 8, kt1); stB(ns, (q4 + 1) * 8, kt1); } },
          {});
    PHASE(0, 1,
          { if (s6) { stB(ns, (q4 + 2) * 8, kt1); stB(ns, (q4 + 3) * 8, kt1);
                      stA(ns, 64 + rt0, kt1);     stA(ns, 64 + rt1, kt1); } },
          {});
    PHASE(1, 0,
          { if (s2) stA(slot, rt0, kt2); },
          {});
    PHASE(1, 1,
          { if (s2) stA(slot, rt1, kt2); },
          { if (s2) asm volatile("s_waitcnt vmcnt(2)" ::: "memory");
            else    asm volatile("s_waitcnt vmcnt(0)" ::: "memory"); });
  }

  const int row0 = bm * 256 + wr + lg * 4;
  const int col0 = bn * 256 + wc + lr;
  if constexpr (OM == 2) {
    short* C = (short*)Cv;
#pragma unroll
    for (int mf = 0; mf < 8; ++mf)
#pragma unroll
      for (int n = 0; n < 4; ++n) {
        int r0 = row0 + mf * 16;
        int bb = r0 >> 11, s0 = r0 & 2047;
        short4 pk;
        pk.x = f2b(acc[mf][n][0]); pk.y = f2b(acc[mf][n][1]);
        pk.z = f2b(acc[mf][n][2]); pk.w = f2b(acc[mf][n][3]);
        size_t idx = ((size_t)(bb * 4096 + col0 + n * 16)) * 2048 + s0;
        *reinterpret_cast<short4*>(&C[idx]) = pk;
      }
  } else {
#pragma unroll
    for (int mf = 0; mf < 8; ++mf)
#pragma unroll
      for (int n = 0; n < 4; ++n)
#pragma unroll
        for (int j = 0; j < 4; ++j) {
          size_t idx = (size_t)(row0 + mf * 16 + j) * N + col0 + n * 16;
          if constexpr (OM == 1) ((short*)Cv)[idx] = f2b(acc[mf][n][j]);
          else ((float*)Cv)[idx] = acc[mf][n][j];
        }
  }
}

// ---------------- causal flash attention, 256 q-rows/block, 16 waves x 16 rows ----------------
// 1-D grid of 512, LPT-ordered: qt = 7 - (lin>>6) so all heavy (qt=7) blocks
// dispatch first; FIFO pickup pairs heavy with light -> uniform ~36 tile-rounds/CU.
__global__ __launch_bounds__(1024, 4) void attn_kernel(
    const short* __restrict__ qb, const short* __restrict__ kb, const short* __restrict__ vt,
    short* __restrict__ ab) {
  __shared__ short Ks[2][64 * 128];
  __shared__ short Vs[128 * 64];
  __shared__ short Ps[16][16 * 64];
  const int tid = threadIdx.x;
  const int wave = tid >> 6, lane = tid & 63;
  const int lr = lane & 15, lg = lane >> 4;
  const int lin = blockIdx.x;
  const int qt = 7 - (lin >> 6);     // heavy blocks dispatch first (LPT)
  const int bh = lin & 63;
  const int b = bh >> 5, h = bh & 31;

  bf16x8 aq[4];
  {
    const short* qrow = qb + ((size_t)(b * S_ + qt * 256 + wave * 16 + lr) * H_ + h) * HD_;
#pragma unroll
    for (int kk = 0; kk < 4; ++kk)
      aq[kk] = *reinterpret_cast<const bf16x8*>(qrow + kk * 32 + lg * 8);
  }

  float m = -1e30f, l = 0.f;
  f32x4 o[8] = {};

  const short* kb_bh = kb + ((size_t)b * S_ * H_ + h) * HD_;
  const short* vt_bh = vt + ((size_t)(b * H_ + h)) * HD_ * S_;

  auto stageK = [&](int t, int buf) {
    int row = tid >> 4;
    int col = ((tid & 15) ^ (row & 7)) * 8;
    gload16(kb_bh + (size_t)(t * 64 + row) * (H_ * HD_) + col,
            &Ks[buf][(tid & 960) * 8]);
  };
  auto loadV = [&](int t, bf16x8& vr) {
    int row = tid >> 3;
    vr = *reinterpret_cast<const bf16x8*>(vt_bh + (size_t)row * S_ + t * 64 + (tid & 7) * 8);
  };
  auto writeV = [&](const bf16x8& vr) {
    int row = tid >> 3;
    int gran = (tid & 7) ^ (row & 7);
    *reinterpret_cast<bf16x8*>(&Vs[row * 64 + gran * 8]) = vr;
  };

  auto process = [&](int t, bool diag) {
    const int buf = t & 1;
    f32x4 sc[4] = {};
    __builtin_amdgcn_s_setprio(1);
#pragma unroll
    for (int cb = 0; cb < 4; ++cb) {
      int tok = cb * 16 + lr;
#pragma unroll
      for (int kk = 0; kk < 4; ++kk) {
        int addr = tok * 128 + (((kk * 4 + lg) ^ (tok & 7)) * 8);
        bf16x8 bk = *reinterpret_cast<const bf16x8*>(&Ks[buf][addr]);
        sc[cb] = __builtin_amdgcn_mfma_f32_16x16x32_bf16(bk, aq[kk], sc[cb], 0, 0, 0);
      }
    }
    __builtin_amdgcn_s_setprio(0);
    const float scale = 0.08838834764831845f;
    const int rowg = qt * 256 + wave * 16 + lr;
#pragma unroll
    for (int cb = 0; cb < 4; ++cb)
#pragma unroll
      for (int j = 0; j < 4; ++j) {
        int colg = t * 64 + cb * 16 + lg * 4 + j;
        float v = sc[cb][j] * scale;
        sc[cb][j] = (!diag || colg <= rowg) ? v : -1e30f;
      }
    float mx = sc[0][0];
#pragma unroll
    for (int cb = 0; cb < 4; ++cb)
#pragma unroll
      for (int j = 0; j < 4; ++j) mx = fmaxf(mx, sc[cb][j]);
    mx = fmaxf(mx, __shfl_xor(mx, 16));
    mx = fmaxf(mx, __shfl_xor(mx, 32));
    float mn = fmaxf(m, mx);
    float alpha = __expf(m - mn);
    m = mn;
    float rs = 0.f;
#pragma unroll
    for (int cb = 0; cb < 4; ++cb) {
      short4 pk;
      float p0 = __expf(sc[cb][0] - mn);
      float p1 = __expf(sc[cb][1] - mn);
      float p2 = __expf(sc[cb][2] - mn);
      float p3 = __expf(sc[cb][3] - mn);
      rs += (p0 + p1) + (p2 + p3);
      pk.x = f2b(p0); pk.y = f2b(p1); pk.z = f2b(p2); pk.w = f2b(p3);
      int gran = (cb * 2 + (lg >> 1)) ^ (lr & 7);
      *reinterpret_cast<short4*>(&Ps[wave][lr * 64 + gran * 8 + (lg & 1) * 4]) = pk;
    }
    rs += __shfl_xor(rs, 16);
    rs += __shfl_xor(rs, 32);
    l = l * alpha + rs;
    f32x4 av;
#pragma unroll
    for (int j = 0; j < 4; ++j) av[j] = __shfl(alpha, lg * 4 + j);
#pragma unroll
    for (int nb = 0; nb < 8; ++nb)
#pragma unroll
      for (int j = 0; j < 4; ++j) o[nb][j] *= av[j];
#pragma unroll
    for (int kk = 0; kk < 2; ++kk) {
      bf16x8 ap = *reinterpret_cast<const bf16x8*>(
          &Ps[wave][lr * 64 + (((kk * 4 + lg) ^ (lr & 7)) * 8)]);
      __builtin_amdgcn_s_setprio(1);
#pragma unroll
      for (int nb = 0; nb < 8; ++nb) {
        int d = nb * 16 + lr;
        bf16x8 bv = *reinterpret_cast<const bf16x8*>(
            &Vs[d * 64 + (((kk * 4 + lg) ^ (lr & 7)) * 8)]);
        o[nb] = __builtin_amdgcn_mfma_f32_16x16x32_bf16(ap, bv, o[nb], 0, 0, 0);
      }
      __builtin_amdgcn_s_setprio(0);
    }
  };

  const int nt = 4 * (qt + 1);
  bf16x8 vr;
  stageK(0, 0);
  loadV(0, vr);
  __syncthreads();
  writeV(vr);
  __syncthreads();
  for (int t = 0; t < nt; ++t) {
    const bool more = (t + 1 < nt);
    if (more) {
      loadV(t + 1, vr);
      stageK(t + 1, (t + 1) & 1);
    }
    process(t, t >= 4 * qt);
    __syncthreads();
    if (more) writeV(vr);
    __syncthreads();
  }

  {
    f32x4 lv;
#pragma unroll
    for (int j = 0; j < 4; ++j) lv[j] = __shfl(l, lg * 4 + j);
#pragma unroll
    for (int j = 0; j < 4; ++j) {
      int q = qt * 256 + wave * 16 + lg * 4 + j;
      float inv = 1.f / lv[j];
      size_t base = ((size_t)(b * S_ + q) * H_ + h) * HD_;
#pragma unroll
      for (int nb = 0; nb < 8; ++nb)
        ab[base + nb * 16 + lr] = f2b(o[nb][j] * inv);
    }
  }
}

// ---------------- gated prefix attention (adds into ab) ----------------
__global__ __launch_bounds__(256) void prefix_kernel(
    const short* __restrict__ qb, const short* __restrict__ pkb, const short* __restrict__ pvb,
    const float* __restrict__ gate, short* __restrict__ ab) {
  __shared__ short pkl[P_ * 128];
  __shared__ short pvl[P_ * 128];
  const int tid = threadIdx.x;
  const int qt = blockIdx.x, bh = blockIdx.y;
  const int b = bh >> 5, h = bh & 31;
  for (int i = tid; i < P_ * 16; i += 256) {
    int row = i >> 4, c = (i & 15) * 8;
    *(bf16x8*)&pkl[row * 128 + c] = *(const bf16x8*)&pkb[(size_t)row * 4096 + h * 128 + c];
    *(bf16x8*)&pvl[row * 128 + c] = *(const bf16x8*)&pvb[(size_t)row * 4096 + h * 128 + c];
  }
  __syncthreads();
  const int r = tid >> 2, p = tid & 3;
  const int q = qt * 64 + r;
  const short* qrow = qb + ((size_t)(b * S_ + q) * H_ + h) * HD_ + p * 32;
  float qv[32];
#pragma unroll
  for (int i = 0; i < 4; ++i) {
    bf16x8 v = *(const bf16x8*)(qrow + i * 8);
#pragma unroll
    for (int e = 0; e < 8; ++e) qv[i * 8 + e] = b2f(v[e]);
  }
  const float scale = 0.08838834764831845f;
  float s[P_];
  float mx = -1e30f;
#pragma unroll
  for (int j = 0; j < P_; ++j) {
    float dot = 0.f;
#pragma unroll
    for (int i = 0; i < 4; ++i) {
      bf16x8 kv = *(const bf16x8*)&pkl[j * 128 + p * 32 + i * 8];
#pragma unroll
      for (int e = 0; e < 8; ++e) dot += qv[i * 8 + e] * b2f(kv[e]);
    }
    dot += __shfl_xor(dot, 1);
    dot += __shfl_xor(dot, 2);
    s[j] = dot * scale;
    mx = fmaxf(mx, s[j]);
  }
  float sum = 0.f;
#pragma unroll
  for (int j = 0; j < P_; ++j) { s[j] = __expf(s[j] - mx); sum += s[j]; }
  float o[32] = {};
#pragma unroll
  for (int j = 0; j < P_; ++j) {
#pragma unroll
    for (int i = 0; i < 4; ++i) {
      bf16x8 vv = *(const bf16x8*)&pvl[j * 128 + p * 32 + i * 8];
#pragma unroll
      for (int e = 0; e < 8; ++e) o[i * 8 + e] += s[j] * b2f(vv[e]);
    }
  }
  float g = tanhf(gate[h]) / sum;
  short* arow = ab + ((size_t)(b * S_ + q) * H_ + h) * HD_ + p * 32;
#pragma unroll
  for (int i = 0; i < 4; ++i) {
    bf16x8 av = *(bf16x8*)(arow + i * 8);
#pragma unroll
    for (int e = 0; e < 8; ++e) av[e] = f2b(b2f(av[e]) + g * o[i * 8 + e]);
    *(bf16x8*)(arow + i * 8) = av;
  }
}

// ---------------- launcher ----------------
extern "C" void kernel_launch(void* const* d_in, const int* in_sizes, int n_in,
                              void* d_out, int out_size, void* d_ws, size_t ws_size,
                              hipStream_t stream) {
  const float* x = (const float*)d_in[0];
  const float* fc = (const float*)d_in[1];
  const float* fs = (const float*)d_in[2];
  const float* prefix = (const float*)d_in[3];
  const float* gate = (const float*)d_in[4];
  const float* wq = (const float*)d_in[5];
  const float* wk = (const float*)d_in[6];
  const float* wv = (const float*)d_in[7];
  const float* wo = (const float*)d_in[8];
  float* out = (float*)d_out;

  char* ws = (char*)d_ws;
  const size_t SZ = (size_t)4096 * 4096 * 2;
  short* xb = (short*)(ws);
  short* wT = (short*)(ws + SZ);
  short* qbuf = (short*)(ws + 2 * SZ);
  short* kbuf = (short*)(ws + 3 * SZ);
  short* vT = (short*)(ws + 4 * SZ);
  short* pb = (short*)(ws + 5 * SZ);
  short* pkb = (short*)(ws + 5 * SZ + (1 << 20));
  short* pvb = (short*)(ws + 5 * SZ + (2 << 20));
  short* abuf = xb;  // alias: x_bf16 dead after V projection

  dim3 tcg(128, 128), tcb(32, 8);
  dim3 gg(16, 16), gp(32, 1);

  convert_f32_bf16<<<16384, 256, 0, stream>>>(x, xb);
  pad_prefix<<<2048, 256, 0, stream>>>(prefix, pb);

  transpose_convert<<<tcg, tcb, 0, stream>>>(wq, wT, 4096, 4096);
  gemm256<1><<<gg, 512, 0, stream>>>(xb, wT, qbuf, 4096, 4096, 4096);

  transpose_convert<<<tcg, tcb, 0, stream>>>(wk, wT, 4096, 4096);
  gemm256<1><<<gg, 512, 0, stream>>>(xb, wT, kbuf, 4096, 4096, 4096);
  gemm_bt<1><<<gp, 256, 0, stream>>>(pb, wT, pkb, 128, 4096, 4096);

  transpose_convert<<<tcg, tcb, 0, stream>>>(wv, wT, 4096, 4096);
  gemm256<2><<<gg, 512, 0, stream>>>(xb, wT, vT, 4096, 4096, 4096);
  gemm_bt<1><<<gp, 256, 0, stream>>>(pb, wT, pvb, 128, 4096, 4096);

  rope_kernel<<<8192, 256, 0, stream>>>(qbuf, fc, fs);
  rope_kernel<<<8192, 256, 0, stream>>>(kbuf, fc, fs);

  attn_kernel<<<512, 1024, 0, stream>>>(qbuf, kbuf, vT, abuf);
  prefix_kernel<<<dim3(32, 64), 256, 0, stream>>>(qbuf, pkb, pvb, gate, abuf);

  transpose_convert<<<tcg, tcb, 0, stream>>>(wo, wT, 4096, 4096);
  gemm256<0><<<gg, 512, 0, stream>>>(abuf, wT, out, 4096, 4096, 4096);
}

// Round 10
// 915.905 us; speedup vs baseline: 2.1311x; 1.1138x over previous
//
#include <hip/hip_runtime.h>
#include <hip/hip_bf16.h>

#define AS1 __attribute__((address_space(1)))
#define AS3 __attribute__((address_space(3)))

typedef __attribute__((ext_vector_type(8))) short bf16x8;
typedef __attribute__((ext_vector_type(4))) float f32x4;

#define B_ 2
#define S_ 2048
#define D_ 4096
#define H_ 32
#define HD_ 128
#define P_ 30

__device__ __forceinline__ short f2b(float f) {
  union { __hip_bfloat16 h; short s; } u;
  u.h = __float2bfloat16(f);
  return u.s;
}
__device__ __forceinline__ float b2f(short s) {
  union { short s; __hip_bfloat16 h; } u;
  u.s = s;
  return __bfloat162float(u.h);
}
__device__ __forceinline__ void gload16(const void* g, void* l) {
  __builtin_amdgcn_global_load_lds((const AS1 void*)g, (AS3 void*)l, 16, 0, 0);
}

// ---------------- elementwise conversion ----------------
__global__ __launch_bounds__(256) void convert_f32_bf16(const float* __restrict__ in,
                                                        short* __restrict__ out) {
  size_t i = ((size_t)blockIdx.x * 256 + threadIdx.x) * 4;
  float4 v = *reinterpret_cast<const float4*>(in + i);
  short4 o;
  o.x = f2b(v.x); o.y = f2b(v.y); o.z = f2b(v.z); o.w = f2b(v.w);
  *reinterpret_cast<short4*>(out + i) = o;
}

// prefix (30 x 4096 f32) -> padded 128 x 4096 bf16 (zeros beyond row 29)
__global__ __launch_bounds__(256) void pad_prefix(const float* __restrict__ p,
                                                  short* __restrict__ pb) {
  int i = blockIdx.x * 256 + threadIdx.x;
  int row = i >> 12, col = i & 4095;
  pb[i] = (row < P_) ? f2b(p[row * D_ + col]) : (short)0;
}

// W (K x N) f32 -> Wt (N x K) bf16, 32x32 LDS tiles
__global__ void transpose_convert(const float* __restrict__ W, short* __restrict__ Wt,
                                  int K, int N) {
  __shared__ float t[32][33];
  int bx = blockIdx.x, by = blockIdx.y;
  int tx = threadIdx.x, ty = threadIdx.y;
#pragma unroll
  for (int i = 0; i < 4; ++i) {
    int r = ty * 4 + i;
    t[r][tx] = W[(size_t)(by * 32 + r) * N + bx * 32 + tx];
  }
  __syncthreads();
#pragma unroll
  for (int i = 0; i < 4; ++i) {
    int r = ty * 4 + i;
    Wt[(size_t)(bx * 32 + r) * K + by * 32 + tx] = f2b(t[tx][r]);
  }
}

// in-place RoPE on (B,S,H,HD) bf16
__global__ __launch_bounds__(256) void rope_kernel(short* __restrict__ t,
                                                   const float* __restrict__ fc,
                                                   const float* __restrict__ fs) {
  size_t g = ((size_t)blockIdx.x * 256 + threadIdx.x) * 8;
  int d = (int)(g & 127);
  int s = (int)((g >> 12) & 2047);
  bf16x8 v = *reinterpret_cast<bf16x8*>(t + g);
  int i0 = d >> 1;
  float4 c = *reinterpret_cast<const float4*>(fc + (size_t)s * 64 + i0);
  float4 sn = *reinterpret_cast<const float4*>(fs + (size_t)s * 64 + i0);
  float cc[4] = {c.x, c.y, c.z, c.w};
  float ss[4] = {sn.x, sn.y, sn.z, sn.w};
  bf16x8 o;
#pragma unroll
  for (int p = 0; p < 4; ++p) {
    float t0 = b2f(v[2 * p]), t1 = b2f(v[2 * p + 1]);
    o[2 * p] = f2b(t0 * cc[p] - t1 * ss[p]);
    o[2 * p + 1] = f2b(t0 * ss[p] + t1 * cc[p]);
  }
  *reinterpret_cast<bf16x8*>(t + g) = o;
}

// ---------------- small GEMM (m97 structure) for prefix projections ----------------
// OM: 1 = bf16 out (MxN), 3 = bf16 transposed out (C^T, N x M layout)
template <int OM>
__global__ __launch_bounds__(256) void gemm_bt(const short* __restrict__ A,
                                               const short* __restrict__ Bt,
                                               void* __restrict__ Cv,
                                               int M, int N, int K) {
  __shared__ short As[128 * 32];
  __shared__ short Bs[128 * 32];
  const int tid = threadIdx.x;
  const int lane = tid & 63;
  const int wbase = tid & 192;
  const int wr = ((tid >> 7) & 1) * 64;
  const int wc = ((tid >> 6) & 1) * 64;
  const int lr = lane & 15;
  const int lk = (lane >> 4) * 8;
  int lin = blockIdx.y * gridDim.x + blockIdx.x;
  int nwg = gridDim.x * gridDim.y;
  int cpx = nwg >> 3;
  int swz = (lin & 7) * cpx + (lin >> 3);
  const int bm = swz / gridDim.x, bn = swz % gridDim.x;
  f32x4 acc[4][4] = {};
  const short* Ab = A + (size_t)bm * 128 * K;
  const short* Bb = Bt + (size_t)bn * 128 * K;
  for (int kt = 0; kt < K; kt += 32) {
    __syncthreads();
#pragma unroll
    for (int i = 0; i < 2; ++i) {
      int f = i * 256 + tid;
      int row = f >> 2, col = (f & 3) * 8;
      gload16(Ab + (size_t)row * K + kt + col, &As[(i * 256 + wbase) * 8]);
      gload16(Bb + (size_t)row * K + kt + col, &Bs[(i * 256 + wbase) * 8]);
    }
    __syncthreads();
    bf16x8 af[4], bfr[4];
#pragma unroll
    for (int m = 0; m < 4; ++m)
      af[m] = *reinterpret_cast<const bf16x8*>(&As[(wr + m * 16 + lr) * 32 + lk]);
#pragma unroll
    for (int n = 0; n < 4; ++n)
      bfr[n] = *reinterpret_cast<const bf16x8*>(&Bs[(wc + n * 16 + lr) * 32 + lk]);
#pragma unroll
    for (int m = 0; m < 4; ++m)
#pragma unroll
      for (int n = 0; n < 4; ++n)
        acc[m][n] = __builtin_amdgcn_mfma_f32_16x16x32_bf16(af[m], bfr[n], acc[m][n], 0, 0, 0);
  }
  const int row0 = bm * 128 + wr + (lane >> 4) * 4;
  const int col0 = bn * 128 + wc + lr;
  if constexpr (OM == 3) {
    short* C = (short*)Cv;
#pragma unroll
    for (int m = 0; m < 4; ++m)
#pragma unroll
      for (int n = 0; n < 4; ++n) {
        short4 pk;
        pk.x = f2b(acc[m][n][0]); pk.y = f2b(acc[m][n][1]);
        pk.z = f2b(acc[m][n][2]); pk.w = f2b(acc[m][n][3]);
        size_t idx = (size_t)(col0 + n * 16) * M + row0 + m * 16;
        *reinterpret_cast<short4*>(&C[idx]) = pk;
      }
  } else {
#pragma unroll
    for (int m = 0; m < 4; ++m)
#pragma unroll
      for (int n = 0; n < 4; ++n)
#pragma unroll
        for (int j = 0; j < 4; ++j) {
          size_t idx = (size_t)(row0 + m * 16 + j) * N + col0 + n * 16;
          ((short*)Cv)[idx] = f2b(acc[m][n][j]);
        }
  }
}

// ---------------- 256x256 8-wave GEMM, 4-phase counted-vmcnt pipeline ----------------
#define PHASE(mh, kh, STAGE, TAIL)                                              \
  {                                                                             \
    bf16x8 af[4], bfr[4];                                                       \
    const int pg = (((kh)*4 + lg) ^ (lr & 7)) * 8;                              \
    _Pragma("unroll") for (int mm = 0; mm < 4; ++mm)                            \
      af[mm] = *(const bf16x8*)&As[slot][(wr + (mh)*64 + mm*16 + lr)*64 + pg];  \
    _Pragma("unroll") for (int nn = 0; nn < 4; ++nn)                            \
      bfr[nn] = *(const bf16x8*)&Bs[slot][(wc + nn*16 + lr)*64 + pg];           \
    STAGE;                                                                      \
    __builtin_amdgcn_s_barrier();                                               \
    asm volatile("s_waitcnt lgkmcnt(0)" ::: "memory");                          \
    __builtin_amdgcn_sched_barrier(0);                                          \
    __builtin_amdgcn_s_setprio(1);                                              \
    _Pragma("unroll") for (int mm = 0; mm < 4; ++mm)                            \
      _Pragma("unroll") for (int nn = 0; nn < 4; ++nn)                          \
        acc[(mh)*4 + mm][nn] = __builtin_amdgcn_mfma_f32_16x16x32_bf16(         \
            af[mm], bfr[nn], acc[(mh)*4 + mm][nn], 0, 0, 0);                    \
    __builtin_amdgcn_s_setprio(0);                                              \
    TAIL;                                                                       \
    __builtin_amdgcn_s_barrier();                                               \
  }

template <int OM>
__global__ __launch_bounds__(512, 2) void gemm256(const short* __restrict__ A,
                                                  const short* __restrict__ Bt,
                                                  void* __restrict__ Cv,
                                                  int M, int N, int K) {
  __shared__ short As[2][256 * 64];
  __shared__ short Bs[2][256 * 64];
  const int tid = threadIdx.x;
  const int w = tid >> 6;
  const int lane = tid & 63;
  const int lr = lane & 15, lg = lane >> 4;
  const int wr = (w >> 2) * 128;
  const int wc = (w & 3) * 64;
  int lin = blockIdx.y * gridDim.x + blockIdx.x;
  int nwg = gridDim.x * gridDim.y;
  int cpx = nwg >> 3;
  int swz = (lin & 7) * cpx + (lin >> 3);
  const int bm = swz / gridDim.x, bn = swz % gridDim.x;

  const short* Ab = A + (size_t)bm * 256 * K;
  const short* Bb = Bt + (size_t)bn * 256 * K;
  const int NT = K >> 6;

  f32x4 acc[8][4] = {};

  auto stA = [&](int slot_, int r0, int kt) {
    int row = r0 + (lane >> 3);
    int gsrc = (lane & 7) ^ ((lane >> 3) & 7);
    gload16(Ab + (size_t)row * K + kt + gsrc * 8, &As[slot_][r0 * 64]);
  };
  auto stB = [&](int slot_, int r0, int kt) {
    int row = r0 + (lane >> 3);
    int gsrc = (lane & 7) ^ ((lane >> 3) & 7);
    gload16(Bb + (size_t)row * K + kt + gsrc * 8, &Bs[slot_][r0 * 64]);
  };

  const int q2 = w * 2, q4 = w * 4;
  const int rt0 = (q2 < 8 ? 0 : 64) + q2 * 8;
  const int rt1 = (q2 + 1 < 8 ? 0 : 64) + (q2 + 1) * 8;

  {
#pragma unroll
    for (int i = 0; i < 4; ++i) stB(0, (q4 + i) * 8, 0);
    stA(0, rt0, 0); stA(0, 64 + rt0, 0);
    stA(0, rt1, 0); stA(0, 64 + rt1, 0);
#pragma unroll
    for (int i = 0; i < 4; ++i) stB(1, (q4 + i) * 8, 64);
    stA(1, rt0, 64); stA(1, 64 + rt0, 64);
    stA(1, rt1, 64); stA(1, 64 + rt1, 64);
  }
  asm volatile("s_waitcnt vmcnt(8)" ::: "memory");
  __builtin_amdgcn_s_barrier();

  for (int t = 0; t < NT; ++t) {
    const int slot = t & 1;
    const int ns = slot ^ 1;
    const int kt1 = (t + 1) << 6, kt2 = (t + 2) << 6;
    const bool s6 = (t >= 1) && (t + 1 < NT);
    const bool s2 = (t + 2 < NT);

    PHASE(0, 0,
          { if (s6) { stB(ns, (q4 + 0) * 8, kt1); stB(ns, (q4 + 1) * 8, kt1); } },
          {});
    PHASE(0, 1,
          { if (s6) { stB(ns, (q4 + 2) * 8, kt1); stB(ns, (q4 + 3) * 8, kt1);
                      stA(ns, 64 + rt0, kt1);     stA(ns, 64 + rt1, kt1); } },
          {});
    PHASE(1, 0,
          { if (s2) stA(slot, rt0, kt2); },
          {});
    PHASE(1, 1,
          { if (s2) stA(slot, rt1, kt2); },
          { if (s2) asm volatile("s_waitcnt vmcnt(2)" ::: "memory");
            else    asm volatile("s_waitcnt vmcnt(0)" ::: "memory"); });
  }

  const int row0 = bm * 256 + wr + lg * 4;
  const int col0 = bn * 256 + wc + lr;
  if constexpr (OM == 2) {
    short* C = (short*)Cv;
#pragma unroll
    for (int mf = 0; mf < 8; ++mf)
#pragma unroll
      for (int n = 0; n < 4; ++n) {
        int r0 = row0 + mf * 16;
        int bb = r0 >> 11, s0 = r0 & 2047;
        short4 pk;
        pk.x = f2b(acc[mf][n][0]); pk.y = f2b(acc[mf][n][1]);
        pk.z = f2b(acc[mf][n][2]); pk.w = f2b(acc[mf][n][3]);
        size_t idx = ((size_t)(bb * 4096 + col0 + n * 16)) * 2048 + s0;
        *reinterpret_cast<short4*>(&C[idx]) = pk;
      }
  } else {
#pragma unroll
    for (int mf = 0; mf < 8; ++mf)
#pragma unroll
      for (int n = 0; n < 4; ++n)
#pragma unroll
        for (int j = 0; j < 4; ++j) {
          size_t idx = (size_t)(row0 + mf * 16 + j) * N + col0 + n * 16;
          if constexpr (OM == 1) ((short*)Cv)[idx] = f2b(acc[mf][n][j]);
          else ((float*)Cv)[idx] = acc[mf][n][j];
        }
  }
}

// ---------------- fused flash attention + gated prefix, 256 q-rows/block ----------------
// 16 waves x 16 rows, 1-D LPT grid. Prefix processed first as one extra MFMA tile
// (single-shot softmax into o2/l2); epilogue combines o/l + tanh(gate)*o2/l2.
__global__ __launch_bounds__(1024, 4) void attn_kernel(
    const short* __restrict__ qb, const short* __restrict__ kb, const short* __restrict__ vt,
    const short* __restrict__ pkb, const short* __restrict__ pvt,
    const float* __restrict__ gate, short* __restrict__ ab) {
  __shared__ short Ks[2][64 * 128];
  __shared__ short Vs[128 * 64];
  __shared__ short Ps[16][16 * 64];
  const int tid = threadIdx.x;
  const int wave = tid >> 6, lane = tid & 63;
  const int lr = lane & 15, lg = lane >> 4;
  const int lin = blockIdx.x;
  const int qt = 7 - (lin >> 6);     // heavy blocks dispatch first (LPT)
  const int bh = lin & 63;
  const int b = bh >> 5, h = bh & 31;

  bf16x8 aq[4];
  {
    const short* qrow = qb + ((size_t)(b * S_ + qt * 256 + wave * 16 + lr) * H_ + h) * HD_;
#pragma unroll
    for (int kk = 0; kk < 4; ++kk)
      aq[kk] = *reinterpret_cast<const bf16x8*>(qrow + kk * 32 + lg * 8);
  }

  float m = -1e30f, l = 0.f, l2 = 0.f;
  f32x4 o[8] = {}, o2[8] = {};

  const short* kb_bh = kb + ((size_t)b * S_ * H_ + h) * HD_;
  const short* vt_bh = vt + ((size_t)(b * H_ + h)) * HD_ * S_;

  auto stageK = [&](int t, int buf) {
    int row = tid >> 4;
    int col = ((tid & 15) ^ (row & 7)) * 8;
    gload16(kb_bh + (size_t)(t * 64 + row) * (H_ * HD_) + col,
            &Ks[buf][(tid & 960) * 8]);
  };
  auto stagePK = [&](int buf) {  // prefix K: token stride is also 4096
    int row = tid >> 4;
    int col = ((tid & 15) ^ (row & 7)) * 8;
    gload16(pkb + (size_t)row * 4096 + h * HD_ + col, &Ks[buf][(tid & 960) * 8]);
  };
  auto loadV = [&](int t, bf16x8& vr) {
    int row = tid >> 3;
    vr = *reinterpret_cast<const bf16x8*>(vt_bh + (size_t)row * S_ + t * 64 + (tid & 7) * 8);
  };
  auto loadPV = [&](bf16x8& vr) {  // pvt: (h*128+d) rows x 128 token-cols
    int row = tid >> 3;
    vr = *reinterpret_cast<const bf16x8*>(pvt + ((size_t)h * HD_ + row) * 128 + (tid & 7) * 8);
  };
  auto writeV = [&](const bf16x8& vr) {
    int row = tid >> 3;
    int gran = (tid & 7) ^ (row & 7);
    *reinterpret_cast<bf16x8*>(&Vs[row * 64 + gran * 8]) = vr;
  };

  const float scale = 0.08838834764831845f;

  // QK^T into sc for tile in Ks[buf]
  auto qkt = [&](int buf, f32x4 sc[4]) {
    __builtin_amdgcn_s_setprio(1);
#pragma unroll
    for (int cb = 0; cb < 4; ++cb) {
      int tok = cb * 16 + lr;
#pragma unroll
      for (int kk = 0; kk < 4; ++kk) {
        int addr = tok * 128 + (((kk * 4 + lg) ^ (tok & 7)) * 8);
        bf16x8 bk = *reinterpret_cast<const bf16x8*>(&Ks[buf][addr]);
        sc[cb] = __builtin_amdgcn_mfma_f32_16x16x32_bf16(bk, aq[kk], sc[cb], 0, 0, 0);
      }
    }
    __builtin_amdgcn_s_setprio(0);
  };
  // P (in Ps[wave]) x V (in Vs) -> acc
  auto pv = [&](f32x4* acc_) {
#pragma unroll
    for (int kk = 0; kk < 2; ++kk) {
      bf16x8 ap = *reinterpret_cast<const bf16x8*>(
          &Ps[wave][lr * 64 + (((kk * 4 + lg) ^ (lr & 7)) * 8)]);
      __builtin_amdgcn_s_setprio(1);
#pragma unroll
      for (int nb = 0; nb < 8; ++nb) {
        int d = nb * 16 + lr;
        bf16x8 bv = *reinterpret_cast<const bf16x8*>(
            &Vs[d * 64 + (((kk * 4 + lg) ^ (lr & 7)) * 8)]);
        acc_[nb] = __builtin_amdgcn_mfma_f32_16x16x32_bf16(ap, bv, acc_[nb], 0, 0, 0);
      }
      __builtin_amdgcn_s_setprio(0);
    }
  };

  auto process = [&](int t, bool diag) {
    const int buf = t & 1;
    f32x4 sc[4] = {};
    qkt(buf, sc);
    const int rowg = qt * 256 + wave * 16 + lr;
#pragma unroll
    for (int cb = 0; cb < 4; ++cb)
#pragma unroll
      for (int j = 0; j < 4; ++j) {
        int colg = t * 64 + cb * 16 + lg * 4 + j;
        float v = sc[cb][j] * scale;
        sc[cb][j] = (!diag || colg <= rowg) ? v : -1e30f;
      }
    float mx = sc[0][0];
#pragma unroll
    for (int cb = 0; cb < 4; ++cb)
#pragma unroll
      for (int j = 0; j < 4; ++j) mx = fmaxf(mx, sc[cb][j]);
    mx = fmaxf(mx, __shfl_xor(mx, 16));
    mx = fmaxf(mx, __shfl_xor(mx, 32));
    float mn = fmaxf(m, mx);
    float alpha = __expf(m - mn);
    m = mn;
    float rs = 0.f;
#pragma unroll
    for (int cb = 0; cb < 4; ++cb) {
      short4 pk;
      float p0 = __expf(sc[cb][0] - mn);
      float p1 = __expf(sc[cb][1] - mn);
      float p2 = __expf(sc[cb][2] - mn);
      float p3 = __expf(sc[cb][3] - mn);
      rs += (p0 + p1) + (p2 + p3);
      pk.x = f2b(p0); pk.y = f2b(p1); pk.z = f2b(p2); pk.w = f2b(p3);
      int gran = (cb * 2 + (lg >> 1)) ^ (lr & 7);
      *reinterpret_cast<short4*>(&Ps[wave][lr * 64 + gran * 8 + (lg & 1) * 4]) = pk;
    }
    rs += __shfl_xor(rs, 16);
    rs += __shfl_xor(rs, 32);
    l = l * alpha + rs;
    f32x4 av;
#pragma unroll
    for (int j = 0; j < 4; ++j) av[j] = __shfl(alpha, lg * 4 + j);
#pragma unroll
    for (int nb = 0; nb < 8; ++nb)
#pragma unroll
      for (int j = 0; j < 4; ++j) o[nb][j] *= av[j];
    pv(o);
  };

  // single-shot prefix tile (cols >= P_ masked, no online update)
  auto processPrefix = [&]() {
    f32x4 sc[4] = {};
    qkt(0, sc);
#pragma unroll
    for (int cb = 0; cb < 4; ++cb)
#pragma unroll
      for (int j = 0; j < 4; ++j) {
        int coll = cb * 16 + lg * 4 + j;
        float v = sc[cb][j] * scale;
        sc[cb][j] = (coll < P_) ? v : -1e30f;
      }
    float mx = sc[0][0];
#pragma unroll
    for (int cb = 0; cb < 4; ++cb)
#pragma unroll
      for (int j = 0; j < 4; ++j) mx = fmaxf(mx, sc[cb][j]);
    mx = fmaxf(mx, __shfl_xor(mx, 16));
    mx = fmaxf(mx, __shfl_xor(mx, 32));
    float rs = 0.f;
#pragma unroll
    for (int cb = 0; cb < 4; ++cb) {
      short4 pk;
      float p0 = __expf(sc[cb][0] - mx);
      float p1 = __expf(sc[cb][1] - mx);
      float p2 = __expf(sc[cb][2] - mx);
      float p3 = __expf(sc[cb][3] - mx);
      rs += (p0 + p1) + (p2 + p3);
      pk.x = f2b(p0); pk.y = f2b(p1); pk.z = f2b(p2); pk.w = f2b(p3);
      int gran = (cb * 2 + (lg >> 1)) ^ (lr & 7);
      *reinterpret_cast<short4*>(&Ps[wave][lr * 64 + gran * 8 + (lg & 1) * 4]) = pk;
    }
    rs += __shfl_xor(rs, 16);
    rs += __shfl_xor(rs, 32);
    l2 = rs;
    pv(o2);
  };

  const int nt = 4 * (qt + 1);
  bf16x8 vr;

  // ---- prefix tile first (Ks[0], Vs free) ----
  stagePK(0);
  loadPV(vr);
  __syncthreads();
  writeV(vr);
  __syncthreads();
  processPrefix();
  __syncthreads();   // all waves done reading Ks[0]/Vs before restaging

  // ---- main causal loop ----
  stageK(0, 0);
  loadV(0, vr);
  __syncthreads();
  writeV(vr);
  __syncthreads();
  for (int t = 0; t < nt; ++t) {
    const bool more = (t + 1 < nt);
    if (more) {
      loadV(t + 1, vr);
      stageK(t + 1, (t + 1) & 1);
    }
    process(t, t >= 4 * qt);
    __syncthreads();
    if (more) writeV(vr);
    __syncthreads();
  }

  {
    float g = tanhf(gate[h]);
    f32x4 lv, lv2;
#pragma unroll
    for (int j = 0; j < 4; ++j) {
      lv[j] = __shfl(l, lg * 4 + j);
      lv2[j] = __shfl(l2, lg * 4 + j);
    }
#pragma unroll
    for (int j = 0; j < 4; ++j) {
      int q = qt * 256 + wave * 16 + lg * 4 + j;
      float inv = 1.f / lv[j];
      float inv2 = g / lv2[j];
      size_t base = ((size_t)(b * S_ + q) * H_ + h) * HD_;
#pragma unroll
      for (int nb = 0; nb < 8; ++nb)
        ab[base + nb * 16 + lr] = f2b(o[nb][j] * inv + o2[nb][j] * inv2);
    }
  }
}

// ---------------- launcher ----------------
extern "C" void kernel_launch(void* const* d_in, const int* in_sizes, int n_in,
                              void* d_out, int out_size, void* d_ws, size_t ws_size,
                              hipStream_t stream) {
  const float* x = (const float*)d_in[0];
  const float* fc = (const float*)d_in[1];
  const float* fs = (const float*)d_in[2];
  const float* prefix = (const float*)d_in[3];
  const float* gate = (const float*)d_in[4];
  const float* wq = (const float*)d_in[5];
  const float* wk = (const float*)d_in[6];
  const float* wv = (const float*)d_in[7];
  const float* wo = (const float*)d_in[8];
  float* out = (float*)d_out;

  char* ws = (char*)d_ws;
  const size_t SZ = (size_t)4096 * 4096 * 2;
  short* xb = (short*)(ws);
  short* wT = (short*)(ws + SZ);
  short* qbuf = (short*)(ws + 2 * SZ);
  short* kbuf = (short*)(ws + 3 * SZ);
  short* vT = (short*)(ws + 4 * SZ);
  short* pb = (short*)(ws + 5 * SZ);
  short* pkb = (short*)(ws + 5 * SZ + (1 << 20));
  short* pvt = (short*)(ws + 5 * SZ + (2 << 20));  // pv^T: 4096 x 128 bf16 (1 MB)
  short* abuf = xb;  // alias: x_bf16 dead after V projection

  dim3 tcg(128, 128), tcb(32, 8);
  dim3 gg(16, 16), gp(32, 1);

  convert_f32_bf16<<<16384, 256, 0, stream>>>(x, xb);
  pad_prefix<<<2048, 256, 0, stream>>>(prefix, pb);

  transpose_convert<<<tcg, tcb, 0, stream>>>(wq, wT, 4096, 4096);
  gemm256<1><<<gg, 512, 0, stream>>>(xb, wT, qbuf, 4096, 4096, 4096);

  transpose_convert<<<tcg, tcb, 0, stream>>>(wk, wT, 4096, 4096);
  gemm256<1><<<gg, 512, 0, stream>>>(xb, wT, kbuf, 4096, 4096, 4096);
  gemm_bt<1><<<gp, 256, 0, stream>>>(pb, wT, pkb, 128, 4096, 4096);

  transpose_convert<<<tcg, tcb, 0, stream>>>(wv, wT, 4096, 4096);
  gemm256<2><<<gg, 512, 0, stream>>>(xb, wT, vT, 4096, 4096, 4096);
  gemm_bt<3><<<gp, 256, 0, stream>>>(pb, wT, pvt, 128, 4096, 4096);

  rope_kernel<<<8192, 256, 0, stream>>>(qbuf, fc, fs);
  rope_kernel<<<8192, 256, 0, stream>>>(kbuf, fc, fs);

  attn_kernel<<<512, 1024, 0, stream>>>(qbuf, kbuf, vT, pkb, pvt, gate, abuf);

  transpose_convert<<<tcg, tcb, 0, stream>>>(wo, wT, 4096, 4096);
  gemm256<0><<<gg, 512, 0, stream>>>(abuf, wT, out, 4096, 4096, 4096);
}